// Round 1
// baseline (5401.595 us; speedup 1.0000x reference)
//
#include <hip/hip_runtime.h>

#define B_    2
#define C0_   64
#define C4_   256
#define H_    160
#define W_    320
#define G_    4
#define HW_   (H_*W_)
#define NROWS_ (B_*H_)      // 320
#define EPS_  1e-5f

#define TH_ 8
#define TW_ 32

// workspace layout sizes (in floats)
#define WT_SZ   147456      // 4*64*9*64
#define BQT_SZ  4096        // 4*64*16
#define AB_SZ   1024        // 2 sides * (a[256] + b[256])
#define T1_SZ   ((size_t)B_*C4_*HW_)   // 26214400
#define QK_SZ   ((size_t)B_*C0_*HW_)   // 6553600
#define RS_SZ   ((size_t)NROWS_*W_)    // 102400
#define CSP_SZ  ((size_t)NROWS_*5*W_)  // 512000

// ---------------------------------------------------------------------------
// Weight pre-transpose: wT[g][ic][tap][oc], bqT/bsT[g][ic][o]
__global__ __launch_bounds__(256) void wtrans_kernel(
    const float* __restrict__ w1, const float* __restrict__ w2,
    const float* __restrict__ bq, const float* __restrict__ bs,
    float* __restrict__ wT1, float* __restrict__ wT2,
    float* __restrict__ bqT, float* __restrict__ bsT) {
  int idx = blockIdx.x * 256 + threadIdx.x;
  if (idx < WT_SZ) {
    int oc  = idx & 63;
    int tap = (idx >> 6) % 9;
    int ic  = (idx / 576) & 63;
    int g   = idx / 36864;
    size_t src = ((size_t)(g*64 + oc) * 64 + ic) * 9 + tap;
    wT1[idx] = w1[src];
    wT2[idx] = w2[src];
  }
  if (idx < BQT_SZ) {
    int o  = idx & 15;
    int ic = (idx >> 4) & 63;
    int g  = idx >> 10;
    size_t src = (size_t)(g*16 + o) * 64 + ic;
    bqT[idx] = bq[src];
    bsT[idx] = bs[src];
  }
}

// ---------------------------------------------------------------------------
// BN stats: per (side, channel) mean/var over (B,H,W) -> scale a, shift b
__global__ __launch_bounds__(256) void bnstats_kernel(
    const float* __restrict__ catL, const float* __restrict__ catR,
    const float* __restrict__ gamma, const float* __restrict__ beta,
    float* __restrict__ ab) {
  int sc = blockIdx.x;          // 0..511
  int side = sc >> 8, c = sc & 255;
  const float* base = (side ? catR : catL) + (size_t)c * HW_;
  float s = 0.f, s2 = 0.f;
  for (int i = threadIdx.x; i < HW_; i += 256) {
    float v0 = base[i];
    float v1 = base[(size_t)C4_*HW_ + i];
    s  += v0 + v1;
    s2 += fmaf(v0, v0, v1*v1);
  }
  #pragma unroll
  for (int o = 32; o; o >>= 1) { s += __shfl_down(s, o); s2 += __shfl_down(s2, o); }
  __shared__ float rs[4], rs2[4];
  int wid = threadIdx.x >> 6;
  if ((threadIdx.x & 63) == 0) { rs[wid] = s; rs2[wid] = s2; }
  __syncthreads();
  if (threadIdx.x == 0) {
    float S  = rs[0]+rs[1]+rs[2]+rs[3];
    float S2 = rs2[0]+rs2[1]+rs2[2]+rs2[3];
    float inv_n = 1.f / (float)(2*HW_);
    float mu  = S * inv_n;
    float var = S2 * inv_n - mu*mu;
    float a = gamma[c] * rsqrtf(var + EPS_);
    ab[side*512 + c]       = a;
    ab[side*512 + 256 + c] = beta[c] - mu*a;
  }
}

// ---------------------------------------------------------------------------
// conv1: t1 = leaky_relu( gconv3x3( bn(cat) ) + b1 ), BN fused into loads
__global__ __launch_bounds__(256) void conv1_kernel(
    const float* __restrict__ cat, const float* __restrict__ ab,
    const float* __restrict__ wT, const float* __restrict__ bias,
    float* __restrict__ out) {
  const int b = blockIdx.z >> 2, g = blockIdx.z & 3;
  const int h0 = blockIdx.y * TH_, w0 = blockIdx.x * TW_;
  const int tid = threadIdx.x;
  const int pw = tid & 31, ph = tid >> 5;
  __shared__ float xt[(TH_+2)*(TW_+2)];
  float acc[64];
  #pragma unroll
  for (int i = 0; i < 64; ++i) acc[i] = 0.f;
  const float* wg = wT + (size_t)g * 36864;
  for (int ic = 0; ic < 64; ++ic) {
    const int c = g*64 + ic;
    const float* src = cat + ((size_t)b*C4_ + c) * HW_;
    const float as = ab[c], bsh = ab[256 + c];
    for (int i = tid; i < (TH_+2)*(TW_+2); i += 256) {
      int lh = i / (TW_+2), lw = i - lh*(TW_+2);
      int gh = h0 - 1 + lh, gw = w0 - 1 + lw;
      float v = 0.f;
      if (gh >= 0 && gh < H_ && gw >= 0 && gw < W_) v = fmaf(as, src[gh*W_ + gw], bsh);
      xt[i] = v;
    }
    __syncthreads();
    float x9[9];
    #pragma unroll
    for (int dh = 0; dh < 3; ++dh)
      #pragma unroll
      for (int dw = 0; dw < 3; ++dw)
        x9[dh*3+dw] = xt[(ph+dh)*(TW_+2) + pw + dw];
    const float* wp = wg + ic*576;
    #pragma unroll
    for (int t = 0; t < 9; ++t) {
      const float xv = x9[t];
      #pragma unroll
      for (int oc = 0; oc < 64; ++oc)
        acc[oc] = fmaf(wp[t*64 + oc], xv, acc[oc]);
    }
    __syncthreads();
  }
  const int h = h0 + ph, w = w0 + pw;
  const size_t obase = ((size_t)b*C4_ + g*64) * HW_ + (size_t)h*W_ + w;
  #pragma unroll
  for (int oc = 0; oc < 64; ++oc) {
    float v = acc[oc] + bias[g*64 + oc];
    out[obase + (size_t)oc*HW_] = (v >= 0.f) ? v : 0.1f*v;
  }
}

// ---------------------------------------------------------------------------
// conv2 + residual(bn input) + fused 1x1 projection -> Qraw (16 ch per group)
__global__ __launch_bounds__(256) void conv2q_kernel(
    const float* __restrict__ t1, const float* __restrict__ cat,
    const float* __restrict__ ab, const float* __restrict__ wT,
    const float* __restrict__ b2, const float* __restrict__ bqT,
    const float* __restrict__ bqb, float* __restrict__ qout) {
  const int b = blockIdx.z >> 2, g = blockIdx.z & 3;
  const int h0 = blockIdx.y * TH_, w0 = blockIdx.x * TW_;
  const int tid = threadIdx.x;
  const int pw = tid & 31, ph = tid >> 5;
  __shared__ float xt[(TH_+2)*(TW_+2)];
  float acc[64];
  #pragma unroll
  for (int i = 0; i < 64; ++i) acc[i] = 0.f;
  const float* wg = wT + (size_t)g * 36864;
  for (int ic = 0; ic < 64; ++ic) {
    const int c = g*64 + ic;
    const float* src = t1 + ((size_t)b*C4_ + c) * HW_;
    for (int i = tid; i < (TH_+2)*(TW_+2); i += 256) {
      int lh = i / (TW_+2), lw = i - lh*(TW_+2);
      int gh = h0 - 1 + lh, gw = w0 - 1 + lw;
      float v = 0.f;
      if (gh >= 0 && gh < H_ && gw >= 0 && gw < W_) v = src[gh*W_ + gw];
      xt[i] = v;
    }
    __syncthreads();
    float x9[9];
    #pragma unroll
    for (int dh = 0; dh < 3; ++dh)
      #pragma unroll
      for (int dw = 0; dw < 3; ++dw)
        x9[dh*3+dw] = xt[(ph+dh)*(TW_+2) + pw + dw];
    const float* wp = wg + ic*576;
    #pragma unroll
    for (int t = 0; t < 9; ++t) {
      const float xv = x9[t];
      #pragma unroll
      for (int oc = 0; oc < 64; ++oc)
        acc[oc] = fmaf(wp[t*64 + oc], xv, acc[oc]);
    }
    __syncthreads();
  }
  const int h = h0 + ph, w = w0 + pw;
  float q[16];
  #pragma unroll
  for (int o = 0; o < 16; ++o) q[o] = bqb[g*16 + o];
  for (int oc = 0; oc < 64; ++oc) {
    const int c = g*64 + oc;
    float y = acc[oc] + b2[c]
            + fmaf(ab[c], cat[((size_t)b*C4_ + c)*HW_ + (size_t)h*W_ + w], ab[256 + c]);
    const float* bw = bqT + c*16;
    #pragma unroll
    for (int o = 0; o < 16; ++o) q[o] = fmaf(bw[o], y, q[o]);
  }
  const size_t qbase = ((size_t)b*C0_ + g*16) * HW_ + (size_t)h*W_ + w;
  #pragma unroll
  for (int o = 0; o < 16; ++o) qout[qbase + (size_t)o*HW_] = q[o];
}

// ---------------------------------------------------------------------------
// subtract mean over w per (b,c,h) row; one wave per row
__global__ __launch_bounds__(64) void rowmean_kernel(float* __restrict__ q) {
  float* p = q + (size_t)blockIdx.x * W_;
  const int lane = threadIdx.x;
  float v[5]; float s = 0.f;
  #pragma unroll
  for (int k = 0; k < 5; ++k) { v[k] = p[lane + 64*k]; s += v[k]; }
  #pragma unroll
  for (int o = 32; o; o >>= 1) s += __shfl_xor(s, o);
  const float m = s * (1.f/320.f);
  #pragma unroll
  for (int k = 0; k < 5; ++k) p[lane + 64*k] = v[k] - m;
}

// ---------------------------------------------------------------------------
// rsum/csum of exp(S), S recomputed in 64x64 tiles. grid (5 ublocks, 320 rows)
__global__ __launch_bounds__(256) void stats_kernel(
    const float* __restrict__ Qp, const float* __restrict__ Kp,
    float* __restrict__ rsum, float* __restrict__ cspart) {
  const int ub = blockIdx.x, row = blockIdx.y;
  const int b = row / H_, h = row - b*H_;
  const int tid = threadIdx.x;
  const int ti = tid & 15, tj = tid >> 4;
  __shared__ float Qs[4096], Ks[4096];
  __shared__ float rs[64], cs[W_];
  for (int i = tid; i < W_; i += 256) cs[i] = 0.f;
  if (tid < 64) rs[tid] = 0.f;
  const size_t rowoff = (size_t)b*C0_*HW_ + (size_t)h*W_;
  for (int i = tid; i < 4096; i += 256) {
    int c = i >> 6, u = i & 63;
    Qs[i] = Qp[rowoff + (size_t)c*HW_ + ub*64 + u];
  }
  for (int vb = 0; vb < 5; ++vb) {
    __syncthreads();
    for (int i = tid; i < 4096; i += 256) {
      int c = i >> 6, v = i & 63;
      Ks[i] = Kp[rowoff + (size_t)c*HW_ + vb*64 + v];
    }
    __syncthreads();
    float sacc[4][4] = {};
    #pragma unroll 4
    for (int c = 0; c < 64; ++c) {
      const float4 a4 = *reinterpret_cast<const float4*>(&Qs[c*64 + ti*4]);
      const float4 b4 = *reinterpret_cast<const float4*>(&Ks[c*64 + tj*4]);
      const float av[4] = {a4.x, a4.y, a4.z, a4.w};
      const float bv[4] = {b4.x, b4.y, b4.z, b4.w};
      #pragma unroll
      for (int i = 0; i < 4; ++i)
        #pragma unroll
        for (int j = 0; j < 4; ++j)
          sacc[i][j] = fmaf(av[i], bv[j], sacc[i][j]);
    }
    float rp[4] = {}, cp[4] = {};
    #pragma unroll
    for (int i = 0; i < 4; ++i)
      #pragma unroll
      for (int j = 0; j < 4; ++j) {
        float e = __expf(sacc[i][j]);
        rp[i] += e; cp[j] += e;
      }
    #pragma unroll
    for (int i = 0; i < 4; ++i) unsafeAtomicAdd(&rs[ti*4 + i], rp[i]);
    #pragma unroll
    for (int j = 0; j < 4; ++j) unsafeAtomicAdd(&cs[vb*64 + tj*4 + j], cp[j]);
  }
  __syncthreads();
  if (tid < 64) rsum[(size_t)row*W_ + ub*64 + tid] = rs[tid];
  for (int i = tid; i < W_; i += 256) cspart[((size_t)row*5 + ub)*W_ + i] = cs[i];
}

__global__ __launch_bounds__(256) void csreduce_kernel(
    const float* __restrict__ csp, float* __restrict__ csum) {
  int idx = blockIdx.x*256 + threadIdx.x;
  if (idx >= (int)RS_SZ) return;
  int row = idx / W_, v = idx - row*W_;
  float s = 0.f;
  #pragma unroll
  for (int ub = 0; ub < 5; ++ub) s += csp[((size_t)row*5 + ub)*W_ + v];
  csum[idx] = s;
}

// ---------------------------------------------------------------------------
// Fused output kernel (one side). Computes, per (row, ublock):
//   E = exp(Q.K) tiles (+2-row halo), xT = (E/rsum) . xmul,
//   V[i] = sum_j (sum_d E[i+d,j]/rsum[i+d]) * E[i,j]/csum[j],
//   out = xblend*(1-tanh(5V)) + xT*tanh(5V)
// Called twice with (Q,K,rs,cs,x_r,x_l)->out_l and (K,Q,cs,rs,x_l,x_r)->out_r.
__device__ __forceinline__ int halo_u(int k, int u0) {
  if (k < 64) return u0 + k;
  return (k == 64) ? (u0-2) : (k == 65) ? (u0-1) : (k == 66) ? (u0+64) : (u0+65);
}

__global__ __launch_bounds__(256) void attn_kernel(
    const float* __restrict__ Qp, const float* __restrict__ Kp,
    const float* __restrict__ rsump, const float* __restrict__ csump,
    const float* __restrict__ xmul, const float* __restrict__ xblend,
    float* __restrict__ outp) {
  const int ub = blockIdx.x;        // 0..4
  const int row = blockIdx.y;       // 0..319
  const int b = row / H_, h = row - b*H_;
  const int u0 = ub * 64;
  const int tid = threadIdx.x;
  const int ti = tid & 15, tj = tid >> 4;

  __shared__ float Qs[64*68];   // [c][k], k: 0..63 core, 64..67 halo rows
  __shared__ float KE[68*65];   // phase A: Ks[c][v] stride 64; phase B: E[r][v] stride 65
  __shared__ float Xm[64*68];   // [v][c] stride 68
  __shared__ float rinv[68];
  __shared__ float cinv[64];
  __shared__ float Vacc[64];

  const size_t rowoff = (size_t)b*C0_*HW_ + (size_t)h*W_;
  const float* rsrow = rsump + (size_t)row*W_;
  const float* csrow = csump + (size_t)row*W_;

  for (int i = tid; i < 64*68; i += 256) {
    int c = i / 68, k = i - c*68;
    int u = halo_u(k, u0);
    Qs[i] = (u >= 0 && u < W_) ? Qp[rowoff + (size_t)c*HW_ + u] : 0.f;
  }
  if (tid < 68) {
    int u = halo_u(tid, u0);
    rinv[tid] = (u >= 0 && u < W_) ? 1.f / rsrow[u] : 0.f;
  }
  if (tid < 64) Vacc[tid] = 0.f;

  float acc[4][4] = {};

  for (int vb = 0; vb < 5; ++vb) {
    const int v0 = vb * 64;
    __syncthreads();
    for (int i = tid; i < 4096; i += 256) {
      int c = i >> 6, v = i & 63;
      KE[c*64 + v] = Kp[rowoff + (size_t)c*HW_ + v0 + v];
    }
    for (int i = tid; i < 4096; i += 256) {
      int c = i >> 6, v = i & 63;
      Xm[v*68 + c] = xmul[rowoff + (size_t)c*HW_ + v0 + v];
    }
    if (tid < 64) cinv[tid] = 1.f / csrow[v0 + tid];
    __syncthreads();

    // core 64x64 S tile
    float sacc[4][4] = {};
    #pragma unroll 4
    for (int c = 0; c < 64; ++c) {
      const float4 a4 = *reinterpret_cast<const float4*>(&Qs[c*68 + ti*4]);
      const float4 b4 = *reinterpret_cast<const float4*>(&KE[c*64 + tj*4]);
      const float av[4] = {a4.x, a4.y, a4.z, a4.w};
      const float bv[4] = {b4.x, b4.y, b4.z, b4.w};
      #pragma unroll
      for (int i = 0; i < 4; ++i)
        #pragma unroll
        for (int j = 0; j < 4; ++j)
          sacc[i][j] = fmaf(av[i], bv[j], sacc[i][j]);
    }
    // halo S: 4 rows x 64 v, one value per thread
    const int hi = tid >> 6, hv = tid & 63;
    float sh = 0.f;
    #pragma unroll 8
    for (int c = 0; c < 64; ++c)
      sh = fmaf(Qs[c*68 + 64 + hi], KE[c*64 + hv], sh);
    __syncthreads();

    // overwrite KE with E (stride 65)
    #pragma unroll
    for (int i = 0; i < 4; ++i)
      #pragma unroll
      for (int j = 0; j < 4; ++j)
        KE[(ti*4+i)*65 + tj*4+j] = __expf(sacc[i][j]);
    {
      int u = halo_u(64 + hi, u0);
      KE[(64+hi)*65 + hv] = (u >= 0 && u < W_) ? __expf(sh) : 0.f;
    }
    __syncthreads();

    // xT accumulation: acc[u][c] += E[u][v] * Xm[v][c]
    #pragma unroll 4
    for (int v = 0; v < 64; ++v) {
      const float4 xv = *reinterpret_cast<const float4*>(&Xm[v*68 + tj*4]);
      const float xa[4] = {xv.x, xv.y, xv.z, xv.w};
      float ev[4];
      #pragma unroll
      for (int i = 0; i < 4; ++i) ev[i] = KE[(ti*4+i)*65 + v];
      #pragma unroll
      for (int i = 0; i < 4; ++i)
        #pragma unroll
        for (int j = 0; j < 4; ++j)
          acc[i][j] = fmaf(ev[i], xa[j], acc[i][j]);
    }

    // banded V accumulation
    float vp[4] = {};
    #pragma unroll
    for (int i2 = 0; i2 < 4; ++i2) {
      const int icore = ti*4 + i2;
      #pragma unroll
      for (int j2 = 0; j2 < 4; ++j2) {
        const int jj = tj*4 + j2;
        float pr = 0.f;
        #pragma unroll
        for (int d = -2; d <= 2; ++d) {
          int r = icore + d;
          int rr = (r < 0) ? (66 + r) : (r > 63) ? (r + 2) : r;
          pr = fmaf(KE[rr*65 + jj], rinv[rr], pr);
        }
        vp[i2] = fmaf(KE[icore*65 + jj] * cinv[jj], pr, vp[i2]);
      }
    }
    #pragma unroll
    for (int i2 = 0; i2 < 4; ++i2)
      unsafeAtomicAdd(&Vacc[ti*4 + i2], vp[i2]);
  }
  __syncthreads();

  float tvals[4], rvals[4];
  #pragma unroll
  for (int i2 = 0; i2 < 4; ++i2) {
    tvals[i2] = tanhf(5.f * Vacc[ti*4 + i2]);
    rvals[i2] = rinv[ti*4 + i2];
  }
  #pragma unroll
  for (int j2 = 0; j2 < 4; ++j2) {
    const int c = tj*4 + j2;
    const size_t base = rowoff + (size_t)c*HW_ + u0 + ti*4;
    const float4 xb4 = *reinterpret_cast<const float4*>(&xblend[base]);
    const float xbv[4] = {xb4.x, xb4.y, xb4.z, xb4.w};
    float ov[4];
    #pragma unroll
    for (int i2 = 0; i2 < 4; ++i2) {
      float xT = acc[i2][j2] * rvals[i2];
      ov[i2] = xbv[i2] * (1.f - tvals[i2]) + xT * tvals[i2];
    }
    float4 o4; o4.x = ov[0]; o4.y = ov[1]; o4.z = ov[2]; o4.w = ov[3];
    *reinterpret_cast<float4*>(&outp[base]) = o4;
  }
}

// ---------------------------------------------------------------------------
extern "C" void kernel_launch(void* const* d_in, const int* in_sizes, int n_in,
                              void* d_out, int out_size, void* d_ws, size_t ws_size,
                              hipStream_t stream) {
  const float* x_left  = (const float*)d_in[0];
  const float* x_right = (const float*)d_in[1];
  const float* catL    = (const float*)d_in[2];
  const float* catR    = (const float*)d_in[3];
  const float* bq_w    = (const float*)d_in[4];
  const float* bq_b    = (const float*)d_in[5];
  const float* bs_w    = (const float*)d_in[6];
  const float* bs_b    = (const float*)d_in[7];
  const float* rb_w1   = (const float*)d_in[8];
  const float* rb_b1   = (const float*)d_in[9];
  const float* rb_w2   = (const float*)d_in[10];
  const float* rb_b2   = (const float*)d_in[11];
  const float* gamma   = (const float*)d_in[12];
  const float* beta    = (const float*)d_in[13];

  float* ws = (float*)d_ws;
  size_t off = 0;
  float* wT1 = ws + off; off += WT_SZ;
  float* wT2 = ws + off; off += WT_SZ;
  float* bqT = ws + off; off += BQT_SZ;
  float* bsT = ws + off; off += BQT_SZ;
  float* ab  = ws + off; off += AB_SZ;
  float* t1  = ws + off; off += T1_SZ;
  float* Qb  = ws + off; off += QK_SZ;
  float* Kb  = ws + off; off += QK_SZ;
  float* rsb = ws + off; off += RS_SZ;
  float* csb = ws + off; off += RS_SZ;
  float* csp = ws + off; off += CSP_SZ;

  wtrans_kernel<<<WT_SZ/256, 256, 0, stream>>>(rb_w1, rb_w2, bq_w, bs_w, wT1, wT2, bqT, bsT);
  bnstats_kernel<<<512, 256, 0, stream>>>(catL, catR, gamma, beta, ab);

  dim3 cgrid(W_/TW_, H_/TH_, B_*G_);
  // left side -> Q
  conv1_kernel<<<cgrid, 256, 0, stream>>>(catL, ab, wT1, rb_b1, t1);
  conv2q_kernel<<<cgrid, 256, 0, stream>>>(t1, catL, ab, wT2, rb_b2, bqT, bq_b, Qb);
  // right side -> K
  conv1_kernel<<<cgrid, 256, 0, stream>>>(catR, ab + 512, wT1, rb_b1, t1);
  conv2q_kernel<<<cgrid, 256, 0, stream>>>(t1, catR, ab + 512, wT2, rb_b2, bsT, bs_b, Kb);

  rowmean_kernel<<<B_*C0_*H_, 64, 0, stream>>>(Qb);
  rowmean_kernel<<<B_*C0_*H_, 64, 0, stream>>>(Kb);

  stats_kernel<<<dim3(5, NROWS_), 256, 0, stream>>>(Qb, Kb, rsb, csp);
  csreduce_kernel<<<(int)((RS_SZ + 255)/256), 256, 0, stream>>>(csp, csb);

  float* outL = (float*)d_out;
  float* outR = outL + QK_SZ;
  attn_kernel<<<dim3(5, NROWS_), 256, 0, stream>>>(Qb, Kb, rsb, csb, x_right, x_left, outL);
  attn_kernel<<<dim3(5, NROWS_), 256, 0, stream>>>(Kb, Qb, csb, rsb, x_left, x_right, outR);
}

// Round 2
// 2642.500 us; speedup vs baseline: 2.0441x; 2.0441x over previous
//
#include <hip/hip_runtime.h>

#define B_    2
#define C0_   64
#define C4_   256
#define H_    160
#define W_    320
#define G_    4
#define HW_   (H_*W_)
#define NROWS_ (B_*H_)      // 320
#define EPS_  1e-5f

#define TH_ 8
#define TW_ 32

// workspace layout sizes (in floats)
#define WT_SZ   147456      // 4*64*9*64  (conv1 weights, [g][ic][tap][oc])
#define WF_SZ   36864       // 4*64*9*16  (fused conv2+proj weights)
#define BQA_SZ  4096        // 256*16     (proj weight * BN scale)
#define BF_SZ   64
#define AB_SZ   1024        // 2 sides * (a[256] + b[256])
#define T1_SZ   ((size_t)B_*C4_*HW_)   // 26214400
#define QK_SZ   ((size_t)B_*C0_*HW_)   // 6553600
#define RS_SZ   ((size_t)NROWS_*W_)    // 102400
#define CSP_SZ  ((size_t)NROWS_*5*W_)  // 512000

// ---------------------------------------------------------------------------
// Weight prep: wT1[g][ic][tap][oc]; fused WfQ/WfK[g][ic][tap][o16]
__global__ __launch_bounds__(256) void wtrans_kernel(
    const float* __restrict__ w1, const float* __restrict__ w2,
    const float* __restrict__ bq, const float* __restrict__ bs,
    float* __restrict__ wT1, float* __restrict__ WfQ, float* __restrict__ WfK) {
  int idx = blockIdx.x * 256 + threadIdx.x;
  if (idx < WT_SZ) {
    int oc  = idx & 63;
    int tap = (idx >> 6) % 9;
    int ic  = (idx / 576) & 63;
    int g   = idx / 36864;
    size_t src = ((size_t)(g*64 + oc) * 64 + ic) * 9 + tap;
    wT1[idx] = w1[src];
  }
  if (idx < WF_SZ) {
    int o = idx & 15, tap = (idx >> 4) % 9, ic = (idx / 144) & 63, g = idx / 9216;
    const float* w2p = w2 + ((size_t)(g*64)*64 + ic)*9 + tap;   // +oc*576
    const float* bqp = bq + (size_t)(g*16 + o)*64;
    const float* bsp = bs + (size_t)(g*16 + o)*64;
    float sq = 0.f, sk = 0.f;
    for (int oc = 0; oc < 64; ++oc) {
      float wv = w2p[(size_t)oc*576];
      sq = fmaf(bqp[oc], wv, sq);
      sk = fmaf(bsp[oc], wv, sk);
    }
    WfQ[idx] = sq;
    WfK[idx] = sk;
  }
}

// ---------------------------------------------------------------------------
// BN stats: per (side, channel) mean/var over (B,H,W) -> scale a, shift b
__global__ __launch_bounds__(256) void bnstats_kernel(
    const float* __restrict__ catL, const float* __restrict__ catR,
    const float* __restrict__ gamma, const float* __restrict__ beta,
    float* __restrict__ ab) {
  int sc = blockIdx.x;          // 0..511
  int side = sc >> 8, c = sc & 255;
  const float* base = (side ? catR : catL) + (size_t)c * HW_;
  float s = 0.f, s2 = 0.f;
  for (int i = threadIdx.x; i < HW_; i += 256) {
    float v0 = base[i];
    float v1 = base[(size_t)C4_*HW_ + i];
    s  += v0 + v1;
    s2 += fmaf(v0, v0, v1*v1);
  }
  #pragma unroll
  for (int o = 32; o; o >>= 1) { s += __shfl_down(s, o); s2 += __shfl_down(s2, o); }
  __shared__ float rs[4], rs2[4];
  int wid = threadIdx.x >> 6;
  if ((threadIdx.x & 63) == 0) { rs[wid] = s; rs2[wid] = s2; }
  __syncthreads();
  if (threadIdx.x == 0) {
    float S  = rs[0]+rs[1]+rs[2]+rs[3];
    float S2 = rs2[0]+rs2[1]+rs2[2]+rs2[3];
    float inv_n = 1.f / (float)(2*HW_);
    float mu  = S * inv_n;
    float var = S2 * inv_n - mu*mu;
    float a = gamma[c] * rsqrtf(var + EPS_);
    ab[side*512 + c]       = a;
    ab[side*512 + 256 + c] = beta[c] - mu*a;
  }
}

// ---------------------------------------------------------------------------
// prep2 (needs BN stats): bqaL/bsaR[c256][o16] = projw * BNscale;
// fused bias bfQ/bfK[o] = proj_bias + sum_c projw*(b2_c + BNshift_c)
__global__ __launch_bounds__(256) void prep2_kernel(
    const float* __restrict__ bq, const float* __restrict__ bs,
    const float* __restrict__ bqb, const float* __restrict__ bsb,
    const float* __restrict__ b2, const float* __restrict__ ab,
    float* __restrict__ bqaL, float* __restrict__ bsaR,
    float* __restrict__ bfQ, float* __restrict__ bfK) {
  int idx = blockIdx.x*256 + threadIdx.x;
  if (idx < 8192) {
    int side = idx >> 12, j = idx & 4095;
    int c = j >> 4, o = j & 15, g = c >> 6, ic = c & 63;
    const float* w = side ? bs : bq;
    float val = w[(size_t)(g*16 + o)*64 + ic] * ab[side*512 + c];
    (side ? bsaR : bqaL)[j] = val;
  }
  if (idx < 128) {
    int side = idx >> 6, co = idx & 63, g = co >> 4, o = co & 15;
    const float* w = side ? bs : bq;
    float s = (side ? bsb : bqb)[co];
    for (int c2 = 0; c2 < 64; ++c2) {
      int ch = g*64 + c2;
      s = fmaf(w[(size_t)(g*16 + o)*64 + c2], b2[ch] + ab[side*512 + 256 + ch], s);
    }
    (side ? bfK : bfQ)[co] = s;
  }
}

// ---------------------------------------------------------------------------
// conv1: t1 = leaky_relu( gconv3x3( bn(cat) ) + b1 ), BN fused into loads
__global__ __launch_bounds__(256) void conv1_kernel(
    const float* __restrict__ cat, const float* __restrict__ ab,
    const float* __restrict__ wT, const float* __restrict__ bias,
    float* __restrict__ out) {
  const int b = blockIdx.z >> 2, g = blockIdx.z & 3;
  const int h0 = blockIdx.y * TH_, w0 = blockIdx.x * TW_;
  const int tid = threadIdx.x;
  const int pw = tid & 31, ph = tid >> 5;
  __shared__ float xt[(TH_+2)*(TW_+2)];
  float acc[64];
  #pragma unroll
  for (int i = 0; i < 64; ++i) acc[i] = 0.f;
  const float* wg = wT + (size_t)g * 36864;
  for (int ic = 0; ic < 64; ++ic) {
    const int c = g*64 + ic;
    const float* src = cat + ((size_t)b*C4_ + c) * HW_;
    const float as = ab[c], bsh = ab[256 + c];
    for (int i = tid; i < (TH_+2)*(TW_+2); i += 256) {
      int lh = i / (TW_+2), lw = i - lh*(TW_+2);
      int gh = h0 - 1 + lh, gw = w0 - 1 + lw;
      float v = 0.f;
      if (gh >= 0 && gh < H_ && gw >= 0 && gw < W_) v = fmaf(as, src[gh*W_ + gw], bsh);
      xt[i] = v;
    }
    __syncthreads();
    float x9[9];
    #pragma unroll
    for (int dh = 0; dh < 3; ++dh)
      #pragma unroll
      for (int dw = 0; dw < 3; ++dw)
        x9[dh*3+dw] = xt[(ph+dh)*(TW_+2) + pw + dw];
    const float* wp = wg + ic*576;
    #pragma unroll
    for (int t = 0; t < 9; ++t) {
      const float xv = x9[t];
      #pragma unroll
      for (int oc = 0; oc < 64; ++oc)
        acc[oc] = fmaf(wp[t*64 + oc], xv, acc[oc]);
    }
    __syncthreads();
  }
  const int h = h0 + ph, w = w0 + pw;
  const size_t obase = ((size_t)b*C4_ + g*64) * HW_ + (size_t)h*W_ + w;
  #pragma unroll
  for (int oc = 0; oc < 64; ++oc) {
    float v = acc[oc] + bias[g*64 + oc];
    out[obase + (size_t)oc*HW_] = (v >= 0.f) ? v : 0.1f*v;
  }
}

// ---------------------------------------------------------------------------
// conv2 with folded 1x1 projection: q[16] = Wf * t1 + bqa . cat + bf
__global__ __launch_bounds__(256) void conv2q_kernel(
    const float* __restrict__ t1, const float* __restrict__ cat,
    const float* __restrict__ Wf, const float* __restrict__ bqa,
    const float* __restrict__ bf, float* __restrict__ qout) {
  const int b = blockIdx.z >> 2, g = blockIdx.z & 3;
  const int h0 = blockIdx.y * TH_, w0 = blockIdx.x * TW_;
  const int tid = threadIdx.x;
  const int pw = tid & 31, ph = tid >> 5;
  __shared__ float xt[(TH_+2)*(TW_+2)];
  const int h = h0 + ph, w = w0 + pw;
  float q[16];
  #pragma unroll
  for (int o = 0; o < 16; ++o) q[o] = bf[g*16 + o];
  const float* wg   = Wf  + (size_t)g * 9216;
  const float* bag  = bqa + (size_t)g * 1024;
  const float* catp = cat + ((size_t)b*C4_ + g*64) * HW_ + (size_t)h*W_ + w;
  for (int ic = 0; ic < 64; ++ic) {
    const float* src = t1 + ((size_t)b*C4_ + g*64 + ic) * HW_;
    for (int i = tid; i < (TH_+2)*(TW_+2); i += 256) {
      int lh = i / (TW_+2), lw = i - lh*(TW_+2);
      int gh = h0 - 1 + lh, gw = w0 - 1 + lw;
      float v = 0.f;
      if (gh >= 0 && gh < H_ && gw >= 0 && gw < W_) v = src[gh*W_ + gw];
      xt[i] = v;
    }
    __syncthreads();
    float x9[9];
    #pragma unroll
    for (int dh = 0; dh < 3; ++dh)
      #pragma unroll
      for (int dw = 0; dw < 3; ++dw)
        x9[dh*3+dw] = xt[(ph+dh)*(TW_+2) + pw + dw];
    const float* wp = wg + ic*144;
    #pragma unroll
    for (int t = 0; t < 9; ++t) {
      const float xv = x9[t];
      #pragma unroll
      for (int o = 0; o < 16; ++o)
        q[o] = fmaf(wp[t*16 + o], xv, q[o]);
    }
    const float rc = catp[(size_t)ic*HW_];
    const float* ba = bag + ic*16;
    #pragma unroll
    for (int o = 0; o < 16; ++o) q[o] = fmaf(ba[o], rc, q[o]);
    __syncthreads();
  }
  const size_t qbase = ((size_t)b*C0_ + g*16) * HW_ + (size_t)h*W_ + w;
  #pragma unroll
  for (int o = 0; o < 16; ++o) qout[qbase + (size_t)o*HW_] = q[o];
}

// ---------------------------------------------------------------------------
// subtract mean over w per (b,c,h) row; one wave per row
__global__ __launch_bounds__(64) void rowmean_kernel(float* __restrict__ q) {
  float* p = q + (size_t)blockIdx.x * W_;
  const int lane = threadIdx.x;
  float v[5]; float s = 0.f;
  #pragma unroll
  for (int k = 0; k < 5; ++k) { v[k] = p[lane + 64*k]; s += v[k]; }
  #pragma unroll
  for (int o = 32; o; o >>= 1) s += __shfl_xor(s, o);
  const float m = s * (1.f/320.f);
  #pragma unroll
  for (int k = 0; k < 5; ++k) p[lane + 64*k] = v[k] - m;
}

// ---------------------------------------------------------------------------
// rsum/csum of exp(S), S recomputed in 64x64 tiles. grid (5 ublocks, 320 rows)
__global__ __launch_bounds__(256) void stats_kernel(
    const float* __restrict__ Qp, const float* __restrict__ Kp,
    float* __restrict__ rsum, float* __restrict__ cspart) {
  const int ub = blockIdx.x, row = blockIdx.y;
  const int b = row / H_, h = row - b*H_;
  const int tid = threadIdx.x;
  const int ti = tid & 15, tj = tid >> 4;
  __shared__ float Qs[4096], Ks[4096];
  __shared__ float rs[64], cs[W_];
  for (int i = tid; i < W_; i += 256) cs[i] = 0.f;
  if (tid < 64) rs[tid] = 0.f;
  const size_t rowoff = (size_t)b*C0_*HW_ + (size_t)h*W_;
  for (int i = tid; i < 4096; i += 256) {
    int c = i >> 6, u = i & 63;
    Qs[i] = Qp[rowoff + (size_t)c*HW_ + ub*64 + u];
  }
  for (int vb = 0; vb < 5; ++vb) {
    __syncthreads();
    for (int i = tid; i < 4096; i += 256) {
      int c = i >> 6, v = i & 63;
      Ks[i] = Kp[rowoff + (size_t)c*HW_ + vb*64 + v];
    }
    __syncthreads();
    float sacc[4][4] = {};
    #pragma unroll 4
    for (int c = 0; c < 64; ++c) {
      const float4 a4 = *reinterpret_cast<const float4*>(&Qs[c*64 + ti*4]);
      const float4 b4 = *reinterpret_cast<const float4*>(&Ks[c*64 + tj*4]);
      const float av[4] = {a4.x, a4.y, a4.z, a4.w};
      const float bv[4] = {b4.x, b4.y, b4.z, b4.w};
      #pragma unroll
      for (int i = 0; i < 4; ++i)
        #pragma unroll
        for (int j = 0; j < 4; ++j)
          sacc[i][j] = fmaf(av[i], bv[j], sacc[i][j]);
    }
    float rp[4] = {}, cp[4] = {};
    #pragma unroll
    for (int i = 0; i < 4; ++i)
      #pragma unroll
      for (int j = 0; j < 4; ++j) {
        float e = __expf(sacc[i][j]);
        rp[i] += e; cp[j] += e;
      }
    #pragma unroll
    for (int i = 0; i < 4; ++i) unsafeAtomicAdd(&rs[ti*4 + i], rp[i]);
    #pragma unroll
    for (int j = 0; j < 4; ++j) unsafeAtomicAdd(&cs[vb*64 + tj*4 + j], cp[j]);
  }
  __syncthreads();
  if (tid < 64) rsum[(size_t)row*W_ + ub*64 + tid] = rs[tid];
  for (int i = tid; i < W_; i += 256) cspart[((size_t)row*5 + ub)*W_ + i] = cs[i];
}

__global__ __launch_bounds__(256) void csreduce_kernel(
    const float* __restrict__ csp, float* __restrict__ csum) {
  int idx = blockIdx.x*256 + threadIdx.x;
  if (idx >= (int)RS_SZ) return;
  int row = idx / W_, v = idx - row*W_;
  float s = 0.f;
  #pragma unroll
  for (int ub = 0; ub < 5; ++ub) s += csp[((size_t)row*5 + ub)*W_ + v];
  csum[idx] = s;
}

// ---------------------------------------------------------------------------
// Fused output kernel (one side). See round-1 notes.
__device__ __forceinline__ int halo_u(int k, int u0) {
  if (k < 64) return u0 + k;
  return (k == 64) ? (u0-2) : (k == 65) ? (u0-1) : (k == 66) ? (u0+64) : (u0+65);
}

__global__ __launch_bounds__(256) void attn_kernel(
    const float* __restrict__ Qp, const float* __restrict__ Kp,
    const float* __restrict__ rsump, const float* __restrict__ csump,
    const float* __restrict__ xmul, const float* __restrict__ xblend,
    float* __restrict__ outp) {
  const int ub = blockIdx.x;        // 0..4
  const int row = blockIdx.y;       // 0..319
  const int b = row / H_, h = row - b*H_;
  const int u0 = ub * 64;
  const int tid = threadIdx.x;
  const int ti = tid & 15, tj = tid >> 4;

  __shared__ float Qs[64*68];   // [c][k], k: 0..63 core, 64..67 halo rows
  __shared__ float KE[68*65];   // phase A: Ks[c][v] stride 64; phase B: E[r][v] stride 65
  __shared__ float Xm[64*68];   // [v][c] stride 68
  __shared__ float rinv[68];
  __shared__ float cinv[64];
  __shared__ float Vacc[64];

  const size_t rowoff = (size_t)b*C0_*HW_ + (size_t)h*W_;
  const float* rsrow = rsump + (size_t)row*W_;
  const float* csrow = csump + (size_t)row*W_;

  for (int i = tid; i < 64*68; i += 256) {
    int c = i / 68, k = i - c*68;
    int u = halo_u(k, u0);
    Qs[i] = (u >= 0 && u < W_) ? Qp[rowoff + (size_t)c*HW_ + u] : 0.f;
  }
  if (tid < 68) {
    int u = halo_u(tid, u0);
    rinv[tid] = (u >= 0 && u < W_) ? 1.f / rsrow[u] : 0.f;
  }
  if (tid < 64) Vacc[tid] = 0.f;

  float acc[4][4] = {};

  for (int vb = 0; vb < 5; ++vb) {
    const int v0 = vb * 64;
    __syncthreads();
    for (int i = tid; i < 4096; i += 256) {
      int c = i >> 6, v = i & 63;
      KE[c*64 + v] = Kp[rowoff + (size_t)c*HW_ + v0 + v];
    }
    for (int i = tid; i < 4096; i += 256) {
      int c = i >> 6, v = i & 63;
      Xm[v*68 + c] = xmul[rowoff + (size_t)c*HW_ + v0 + v];
    }
    if (tid < 64) cinv[tid] = 1.f / csrow[v0 + tid];
    __syncthreads();

    // core 64x64 S tile
    float sacc[4][4] = {};
    #pragma unroll 4
    for (int c = 0; c < 64; ++c) {
      const float4 a4 = *reinterpret_cast<const float4*>(&Qs[c*68 + ti*4]);
      const float4 b4 = *reinterpret_cast<const float4*>(&KE[c*64 + tj*4]);
      const float av[4] = {a4.x, a4.y, a4.z, a4.w};
      const float bv[4] = {b4.x, b4.y, b4.z, b4.w};
      #pragma unroll
      for (int i = 0; i < 4; ++i)
        #pragma unroll
        for (int j = 0; j < 4; ++j)
          sacc[i][j] = fmaf(av[i], bv[j], sacc[i][j]);
    }
    // halo S: 4 rows x 64 v, one value per thread
    const int hi = tid >> 6, hv = tid & 63;
    float sh = 0.f;
    #pragma unroll 8
    for (int c = 0; c < 64; ++c)
      sh = fmaf(Qs[c*68 + 64 + hi], KE[c*64 + hv], sh);
    __syncthreads();

    // overwrite KE with E (stride 65)
    #pragma unroll
    for (int i = 0; i < 4; ++i)
      #pragma unroll
      for (int j = 0; j < 4; ++j)
        KE[(ti*4+i)*65 + tj*4+j] = __expf(sacc[i][j]);
    {
      int u = halo_u(64 + hi, u0);
      KE[(64+hi)*65 + hv] = (u >= 0 && u < W_) ? __expf(sh) : 0.f;
    }
    __syncthreads();

    // xT accumulation: acc[u][c] += E[u][v] * Xm[v][c]
    #pragma unroll 4
    for (int v = 0; v < 64; ++v) {
      const float4 xv = *reinterpret_cast<const float4*>(&Xm[v*68 + tj*4]);
      const float xa[4] = {xv.x, xv.y, xv.z, xv.w};
      float ev[4];
      #pragma unroll
      for (int i = 0; i < 4; ++i) ev[i] = KE[(ti*4+i)*65 + v];
      #pragma unroll
      for (int i = 0; i < 4; ++i)
        #pragma unroll
        for (int j = 0; j < 4; ++j)
          acc[i][j] = fmaf(ev[i], xa[j], acc[i][j]);
    }

    // banded V accumulation
    float vp[4] = {};
    #pragma unroll
    for (int i2 = 0; i2 < 4; ++i2) {
      const int icore = ti*4 + i2;
      #pragma unroll
      for (int j2 = 0; j2 < 4; ++j2) {
        const int jj = tj*4 + j2;
        float pr = 0.f;
        #pragma unroll
        for (int d = -2; d <= 2; ++d) {
          int r = icore + d;
          int rr = (r < 0) ? (66 + r) : (r > 63) ? (r + 2) : r;
          pr = fmaf(KE[rr*65 + jj], rinv[rr], pr);
        }
        vp[i2] = fmaf(KE[icore*65 + jj] * cinv[jj], pr, vp[i2]);
      }
    }
    #pragma unroll
    for (int i2 = 0; i2 < 4; ++i2)
      unsafeAtomicAdd(&Vacc[ti*4 + i2], vp[i2]);
  }
  __syncthreads();

  float tvals[4], rvals[4];
  #pragma unroll
  for (int i2 = 0; i2 < 4; ++i2) {
    tvals[i2] = tanhf(5.f * Vacc[ti*4 + i2]);
    rvals[i2] = rinv[ti*4 + i2];
  }
  #pragma unroll
  for (int j2 = 0; j2 < 4; ++j2) {
    const int c = tj*4 + j2;
    const size_t base = rowoff + (size_t)c*HW_ + u0 + ti*4;
    const float4 xb4 = *reinterpret_cast<const float4*>(&xblend[base]);
    const float xbv[4] = {xb4.x, xb4.y, xb4.z, xb4.w};
    float ov[4];
    #pragma unroll
    for (int i2 = 0; i2 < 4; ++i2) {
      float xT = acc[i2][j2] * rvals[i2];
      ov[i2] = xbv[i2] * (1.f - tvals[i2]) + xT * tvals[i2];
    }
    float4 o4; o4.x = ov[0]; o4.y = ov[1]; o4.z = ov[2]; o4.w = ov[3];
    *reinterpret_cast<float4*>(&outp[base]) = o4;
  }
}

// ---------------------------------------------------------------------------
extern "C" void kernel_launch(void* const* d_in, const int* in_sizes, int n_in,
                              void* d_out, int out_size, void* d_ws, size_t ws_size,
                              hipStream_t stream) {
  const float* x_left  = (const float*)d_in[0];
  const float* x_right = (const float*)d_in[1];
  const float* catL    = (const float*)d_in[2];
  const float* catR    = (const float*)d_in[3];
  const float* bq_w    = (const float*)d_in[4];
  const float* bq_b    = (const float*)d_in[5];
  const float* bs_w    = (const float*)d_in[6];
  const float* bs_b    = (const float*)d_in[7];
  const float* rb_w1   = (const float*)d_in[8];
  const float* rb_b1   = (const float*)d_in[9];
  const float* rb_w2   = (const float*)d_in[10];
  const float* rb_b2   = (const float*)d_in[11];
  const float* gamma   = (const float*)d_in[12];
  const float* beta    = (const float*)d_in[13];

  float* ws = (float*)d_ws;
  size_t off = 0;
  float* wT1 = ws + off; off += WT_SZ;
  float* WfQ = ws + off; off += WF_SZ;
  float* WfK = ws + off; off += WF_SZ;
  float* bqaL= ws + off; off += BQA_SZ;
  float* bsaR= ws + off; off += BQA_SZ;
  float* bfQ = ws + off; off += BF_SZ;
  float* bfK = ws + off; off += BF_SZ;
  float* ab  = ws + off; off += AB_SZ;
  float* t1  = ws + off; off += T1_SZ;
  float* Qb  = ws + off; off += QK_SZ;
  float* Kb  = ws + off; off += QK_SZ;
  float* rsb = ws + off; off += RS_SZ;
  float* csb = ws + off; off += RS_SZ;
  float* csp = ws + off; off += CSP_SZ;

  wtrans_kernel<<<WT_SZ/256, 256, 0, stream>>>(rb_w1, rb_w2, bq_w, bs_w, wT1, WfQ, WfK);
  bnstats_kernel<<<512, 256, 0, stream>>>(catL, catR, gamma, beta, ab);
  prep2_kernel<<<32, 256, 0, stream>>>(bq_w, bs_w, bq_b, bs_b, rb_b2, ab, bqaL, bsaR, bfQ, bfK);

  dim3 cgrid(W_/TW_, H_/TH_, B_*G_);
  // left side -> Q
  conv1_kernel<<<cgrid, 256, 0, stream>>>(catL, ab, wT1, rb_b1, t1);
  conv2q_kernel<<<cgrid, 256, 0, stream>>>(t1, catL, WfQ, bqaL, bfQ, Qb);
  // right side -> K
  conv1_kernel<<<cgrid, 256, 0, stream>>>(catR, ab + 512, wT1, rb_b1, t1);
  conv2q_kernel<<<cgrid, 256, 0, stream>>>(t1, catR, WfK, bsaR, bfK, Kb);

  rowmean_kernel<<<B_*C0_*H_, 64, 0, stream>>>(Qb);
  rowmean_kernel<<<B_*C0_*H_, 64, 0, stream>>>(Kb);

  stats_kernel<<<dim3(5, NROWS_), 256, 0, stream>>>(Qb, Kb, rsb, csp);
  csreduce_kernel<<<(int)((RS_SZ + 255)/256), 256, 0, stream>>>(csp, csb);

  float* outL = (float*)d_out;
  float* outR = outL + QK_SZ;
  attn_kernel<<<dim3(5, NROWS_), 256, 0, stream>>>(Qb, Kb, rsb, csb, x_right, x_left, outL);
  attn_kernel<<<dim3(5, NROWS_), 256, 0, stream>>>(Kb, Qb, csb, rsb, x_left, x_right, outR);
}

// Round 3
// 2188.568 us; speedup vs baseline: 2.4681x; 1.2074x over previous
//
#include <hip/hip_runtime.h>

#define B_    2
#define C0_   64
#define C4_   256
#define H_    160
#define W_    320
#define G_    4
#define HW_   (H_*W_)
#define NROWS_ (B_*H_)      // 320
#define EPS_  1e-5f

#define TH_ 8
#define TW_ 32
#define CH_ 8               // ic chunk per staging phase

typedef float f32x4 __attribute__((ext_vector_type(4)));

// workspace layout sizes (in floats)
#define WT_SZ   147456      // 4*64*9*64  (conv1 weights, [g][ic][tap][oc])
#define WF_SZ   36864       // 4*64*9*16  (fused conv2+proj weights)
#define BQA_SZ  4096        // 256*16     (proj weight * BN scale)
#define BF_SZ   64
#define AB_SZ   1024        // 2 sides * (a[256] + b[256])
#define T1_SZ   ((size_t)B_*C4_*HW_)   // 26214400
#define QK_SZ   ((size_t)B_*C0_*HW_)   // 6553600
#define RS_SZ   ((size_t)NROWS_*W_)    // 102400
#define CSP_SZ  ((size_t)NROWS_*5*W_)  // 512000

// ---------------------------------------------------------------------------
// Weight prep: wT1[g][ic][tap][oc]; fused WfQ/WfK[g][ic][tap][o16]
__global__ __launch_bounds__(256) void wtrans_kernel(
    const float* __restrict__ w1, const float* __restrict__ w2,
    const float* __restrict__ bq, const float* __restrict__ bs,
    float* __restrict__ wT1, float* __restrict__ WfQ, float* __restrict__ WfK) {
  int idx = blockIdx.x * 256 + threadIdx.x;
  if (idx < WT_SZ) {
    int oc  = idx & 63;
    int tap = (idx >> 6) % 9;
    int ic  = (idx / 576) & 63;
    int g   = idx / 36864;
    size_t src = ((size_t)(g*64 + oc) * 64 + ic) * 9 + tap;
    wT1[idx] = w1[src];
  }
  if (idx < WF_SZ) {
    int o = idx & 15, tap = (idx >> 4) % 9, ic = (idx / 144) & 63, g = idx / 9216;
    const float* w2p = w2 + ((size_t)(g*64)*64 + ic)*9 + tap;   // +oc*576
    const float* bqp = bq + (size_t)(g*16 + o)*64;
    const float* bsp = bs + (size_t)(g*16 + o)*64;
    float sq = 0.f, sk = 0.f;
    for (int oc = 0; oc < 64; ++oc) {
      float wv = w2p[(size_t)oc*576];
      sq = fmaf(bqp[oc], wv, sq);
      sk = fmaf(bsp[oc], wv, sk);
    }
    WfQ[idx] = sq;
    WfK[idx] = sk;
  }
}

// ---------------------------------------------------------------------------
// BN stats: per (side, channel) mean/var over (B,H,W) -> scale a, shift b
__global__ __launch_bounds__(256) void bnstats_kernel(
    const float* __restrict__ catL, const float* __restrict__ catR,
    const float* __restrict__ gamma, const float* __restrict__ beta,
    float* __restrict__ ab) {
  int sc = blockIdx.x;          // 0..511
  int side = sc >> 8, c = sc & 255;
  const float* base = (side ? catR : catL) + (size_t)c * HW_;
  float s = 0.f, s2 = 0.f;
  for (int i = threadIdx.x; i < HW_; i += 256) {
    float v0 = base[i];
    float v1 = base[(size_t)C4_*HW_ + i];
    s  += v0 + v1;
    s2 += fmaf(v0, v0, v1*v1);
  }
  #pragma unroll
  for (int o = 32; o; o >>= 1) { s += __shfl_down(s, o); s2 += __shfl_down(s2, o); }
  __shared__ float rs[4], rs2[4];
  int wid = threadIdx.x >> 6;
  if ((threadIdx.x & 63) == 0) { rs[wid] = s; rs2[wid] = s2; }
  __syncthreads();
  if (threadIdx.x == 0) {
    float S  = rs[0]+rs[1]+rs[2]+rs[3];
    float S2 = rs2[0]+rs2[1]+rs2[2]+rs2[3];
    float inv_n = 1.f / (float)(2*HW_);
    float mu  = S * inv_n;
    float var = S2 * inv_n - mu*mu;
    float a = gamma[c] * rsqrtf(var + EPS_);
    ab[side*512 + c]       = a;
    ab[side*512 + 256 + c] = beta[c] - mu*a;
  }
}

// ---------------------------------------------------------------------------
// prep2 (needs BN stats): bqaL/bsaR[c256][o16] = projw * BNscale;
// fused bias bfQ/bfK[o] = proj_bias + sum_c projw*(b2_c + BNshift_c)
__global__ __launch_bounds__(256) void prep2_kernel(
    const float* __restrict__ bq, const float* __restrict__ bs,
    const float* __restrict__ bqb, const float* __restrict__ bsb,
    const float* __restrict__ b2, const float* __restrict__ ab,
    float* __restrict__ bqaL, float* __restrict__ bsaR,
    float* __restrict__ bfQ, float* __restrict__ bfK) {
  int idx = blockIdx.x*256 + threadIdx.x;
  if (idx < 8192) {
    int side = idx >> 12, j = idx & 4095;
    int c = j >> 4, o = j & 15, g = c >> 6, ic = c & 63;
    const float* w = side ? bs : bq;
    float val = w[(size_t)(g*16 + o)*64 + ic] * ab[side*512 + c];
    (side ? bsaR : bqaL)[j] = val;
  }
  if (idx < 128) {
    int side = idx >> 6, co = idx & 63, g = co >> 4, o = co & 15;
    const float* w = side ? bs : bq;
    float s = (side ? bsb : bqb)[co];
    for (int c2 = 0; c2 < 64; ++c2) {
      int ch = g*64 + c2;
      s = fmaf(w[(size_t)(g*16 + o)*64 + c2], b2[ch] + ab[side*512 + 256 + ch], s);
    }
    (side ? bfK : bfQ)[co] = s;
  }
}

// ---------------------------------------------------------------------------
// conv1: t1 = leaky_relu( gconv3x3( bn(cat) ) + b1 )
// 16 named f32x4 accumulators (register-guaranteed), 8-ic staged chunks.
__global__ __launch_bounds__(256, 2) void conv1_kernel(
    const float* __restrict__ cat, const float* __restrict__ ab,
    const float* __restrict__ wT, const float* __restrict__ bias,
    float* __restrict__ out) {
  const int b = blockIdx.z >> 2, g = blockIdx.z & 3;
  const int h0 = blockIdx.y * TH_, w0 = blockIdx.x * TW_;
  const int tid = threadIdx.x;
  const int pw = tid & 31, ph = tid >> 5;
  __shared__ float xt[CH_ * 360];    // [ic][10][36]

  f32x4 A0{},A1{},A2{},A3{},A4{},A5{},A6{},A7{},
        A8{},A9{},A10{},A11{},A12{},A13{},A14{},A15{};

  const float* wg = wT + (size_t)g * 36864;
  const float* catg = cat + ((size_t)b*C4_ + g*64) * HW_;

  for (int icc = 0; icc < 64; icc += CH_) {
    __syncthreads();
    for (int i = tid; i < CH_*360; i += 256) {
      int ic = i / 360, r = i - ic*360;
      int lh = r / 36, lw = r - lh*36;
      int gh = h0 - 1 + lh, gw = w0 - 1 + lw;
      int c = g*64 + icc + ic;
      float v = 0.f;
      if (lw < 34 && gh >= 0 && gh < H_ && gw >= 0 && gw < W_)
        v = fmaf(ab[c], catg[(size_t)(icc+ic)*HW_ + gh*W_ + gw], ab[256 + c]);
      xt[i] = v;
    }
    __syncthreads();
    #pragma unroll 2
    for (int ic = 0; ic < CH_; ++ic) {
      float x9[9];
      #pragma unroll
      for (int dh = 0; dh < 3; ++dh)
        #pragma unroll
        for (int dw = 0; dw < 3; ++dw)
          x9[dh*3+dw] = xt[ic*360 + (ph+dh)*36 + pw + dw];
      const f32x4* wp = (const f32x4*)(wg + (size_t)(icc+ic)*576);
      #pragma unroll
      for (int t = 0; t < 9; ++t) {
        const float xv = x9[t];
        A0  += wp[t*16+ 0]*xv;  A1  += wp[t*16+ 1]*xv;
        A2  += wp[t*16+ 2]*xv;  A3  += wp[t*16+ 3]*xv;
        A4  += wp[t*16+ 4]*xv;  A5  += wp[t*16+ 5]*xv;
        A6  += wp[t*16+ 6]*xv;  A7  += wp[t*16+ 7]*xv;
        A8  += wp[t*16+ 8]*xv;  A9  += wp[t*16+ 9]*xv;
        A10 += wp[t*16+10]*xv;  A11 += wp[t*16+11]*xv;
        A12 += wp[t*16+12]*xv;  A13 += wp[t*16+13]*xv;
        A14 += wp[t*16+14]*xv;  A15 += wp[t*16+15]*xv;
      }
    }
  }
  const int h = h0 + ph, w = w0 + pw;
  const size_t obase = ((size_t)b*C4_ + g*64) * HW_ + (size_t)h*W_ + w;
  const f32x4* b4 = (const f32x4*)(bias + g*64);
  f32x4 Aq[16] = {A0,A1,A2,A3,A4,A5,A6,A7,A8,A9,A10,A11,A12,A13,A14,A15};
  #pragma unroll
  for (int q = 0; q < 16; ++q) {
    f32x4 v = Aq[q] + b4[q];
    #pragma unroll
    for (int j = 0; j < 4; ++j) {
      float vv = v[j];
      out[obase + (size_t)(q*4+j)*HW_] = (vv >= 0.f) ? vv : 0.1f*vv;
    }
  }
}

// ---------------------------------------------------------------------------
// conv2 with folded 1x1 projection: q[16] = Wf * t1 + bqa . cat + bf
__global__ __launch_bounds__(256, 2) void conv2q_kernel(
    const float* __restrict__ t1, const float* __restrict__ cat,
    const float* __restrict__ Wf, const float* __restrict__ bqa,
    const float* __restrict__ bf, float* __restrict__ qout) {
  const int b = blockIdx.z >> 2, g = blockIdx.z & 3;
  const int h0 = blockIdx.y * TH_, w0 = blockIdx.x * TW_;
  const int tid = threadIdx.x;
  const int pw = tid & 31, ph = tid >> 5;
  __shared__ float xt[CH_ * 360];
  const int h = h0 + ph, w = w0 + pw;

  const f32x4* bf4 = (const f32x4*)(bf + g*16);
  f32x4 Q0 = bf4[0], Q1 = bf4[1], Q2 = bf4[2], Q3 = bf4[3];

  const float* wg   = Wf  + (size_t)g * 9216;
  const f32x4* bag  = (const f32x4*)(bqa + (size_t)g * 1024);
  const float* t1g  = t1  + ((size_t)b*C4_ + g*64) * HW_;
  const float* catp = cat + ((size_t)b*C4_ + g*64) * HW_ + (size_t)h*W_ + w;

  for (int icc = 0; icc < 64; icc += CH_) {
    __syncthreads();
    for (int i = tid; i < CH_*360; i += 256) {
      int ic = i / 360, r = i - ic*360;
      int lh = r / 36, lw = r - lh*36;
      int gh = h0 - 1 + lh, gw = w0 - 1 + lw;
      float v = 0.f;
      if (lw < 34 && gh >= 0 && gh < H_ && gw >= 0 && gw < W_)
        v = t1g[(size_t)(icc+ic)*HW_ + gh*W_ + gw];
      xt[i] = v;
    }
    __syncthreads();
    #pragma unroll 4
    for (int ic = 0; ic < CH_; ++ic) {
      float x9[9];
      #pragma unroll
      for (int dh = 0; dh < 3; ++dh)
        #pragma unroll
        for (int dw = 0; dw < 3; ++dw)
          x9[dh*3+dw] = xt[ic*360 + (ph+dh)*36 + pw + dw];
      const f32x4* wp = (const f32x4*)(wg + (size_t)(icc+ic)*144);
      #pragma unroll
      for (int t = 0; t < 9; ++t) {
        const float xv = x9[t];
        Q0 += wp[t*4+0]*xv; Q1 += wp[t*4+1]*xv;
        Q2 += wp[t*4+2]*xv; Q3 += wp[t*4+3]*xv;
      }
      const float rc = catp[(size_t)(icc+ic)*HW_];
      Q0 += bag[(icc+ic)*4+0]*rc; Q1 += bag[(icc+ic)*4+1]*rc;
      Q2 += bag[(icc+ic)*4+2]*rc; Q3 += bag[(icc+ic)*4+3]*rc;
    }
  }
  const size_t qbase = ((size_t)b*C0_ + g*16) * HW_ + (size_t)h*W_ + w;
  f32x4 Qq[4] = {Q0,Q1,Q2,Q3};
  #pragma unroll
  for (int q = 0; q < 4; ++q)
    #pragma unroll
    for (int j = 0; j < 4; ++j)
      qout[qbase + (size_t)(q*4+j)*HW_] = Qq[q][j];
}

// ---------------------------------------------------------------------------
// subtract mean over w per (b,c,h) row; one wave per row
__global__ __launch_bounds__(64) void rowmean_kernel(float* __restrict__ q) {
  float* p = q + (size_t)blockIdx.x * W_;
  const int lane = threadIdx.x;
  float v[5]; float s = 0.f;
  #pragma unroll
  for (int k = 0; k < 5; ++k) { v[k] = p[lane + 64*k]; s += v[k]; }
  #pragma unroll
  for (int o = 32; o; o >>= 1) s += __shfl_xor(s, o);
  const float m = s * (1.f/320.f);
  #pragma unroll
  for (int k = 0; k < 5; ++k) p[lane + 64*k] = v[k] - m;
}

// ---------------------------------------------------------------------------
// rsum/csum of exp(S), S recomputed in 64x64 tiles. grid (5 ublocks, 320 rows)
__global__ __launch_bounds__(256) void stats_kernel(
    const float* __restrict__ Qp, const float* __restrict__ Kp,
    float* __restrict__ rsum, float* __restrict__ cspart) {
  const int ub = blockIdx.x, row = blockIdx.y;
  const int b = row / H_, h = row - b*H_;
  const int tid = threadIdx.x;
  const int ti = tid & 15, tj = tid >> 4;
  __shared__ float Qs[4096], Ks[4096];
  __shared__ float rs[64], cs[W_];
  for (int i = tid; i < W_; i += 256) cs[i] = 0.f;
  if (tid < 64) rs[tid] = 0.f;
  const size_t rowoff = (size_t)b*C0_*HW_ + (size_t)h*W_;
  for (int i = tid; i < 4096; i += 256) {
    int c = i >> 6, u = i & 63;
    Qs[i] = Qp[rowoff + (size_t)c*HW_ + ub*64 + u];
  }
  for (int vb = 0; vb < 5; ++vb) {
    __syncthreads();
    for (int i = tid; i < 4096; i += 256) {
      int c = i >> 6, v = i & 63;
      Ks[i] = Kp[rowoff + (size_t)c*HW_ + vb*64 + v];
    }
    __syncthreads();
    float sacc[4][4] = {};
    #pragma unroll 4
    for (int c = 0; c < 64; ++c) {
      const float4 a4 = *reinterpret_cast<const float4*>(&Qs[c*64 + ti*4]);
      const float4 b4 = *reinterpret_cast<const float4*>(&Ks[c*64 + tj*4]);
      const float av[4] = {a4.x, a4.y, a4.z, a4.w};
      const float bv[4] = {b4.x, b4.y, b4.z, b4.w};
      #pragma unroll
      for (int i = 0; i < 4; ++i)
        #pragma unroll
        for (int j = 0; j < 4; ++j)
          sacc[i][j] = fmaf(av[i], bv[j], sacc[i][j]);
    }
    float rp[4] = {}, cp[4] = {};
    #pragma unroll
    for (int i = 0; i < 4; ++i)
      #pragma unroll
      for (int j = 0; j < 4; ++j) {
        float e = __expf(sacc[i][j]);
        rp[i] += e; cp[j] += e;
      }
    #pragma unroll
    for (int i = 0; i < 4; ++i) unsafeAtomicAdd(&rs[ti*4 + i], rp[i]);
    #pragma unroll
    for (int j = 0; j < 4; ++j) unsafeAtomicAdd(&cs[vb*64 + tj*4 + j], cp[j]);
  }
  __syncthreads();
  if (tid < 64) rsum[(size_t)row*W_ + ub*64 + tid] = rs[tid];
  for (int i = tid; i < W_; i += 256) cspart[((size_t)row*5 + ub)*W_ + i] = cs[i];
}

__global__ __launch_bounds__(256) void csreduce_kernel(
    const float* __restrict__ csp, float* __restrict__ csum) {
  int idx = blockIdx.x*256 + threadIdx.x;
  if (idx >= (int)RS_SZ) return;
  int row = idx / W_, v = idx - row*W_;
  float s = 0.f;
  #pragma unroll
  for (int ub = 0; ub < 5; ++ub) s += csp[((size_t)row*5 + ub)*W_ + v];
  csum[idx] = s;
}

// ---------------------------------------------------------------------------
// Fused output kernel (one side). See round-1 notes.
__device__ __forceinline__ int halo_u(int k, int u0) {
  if (k < 64) return u0 + k;
  return (k == 64) ? (u0-2) : (k == 65) ? (u0-1) : (k == 66) ? (u0+64) : (u0+65);
}

__global__ __launch_bounds__(256) void attn_kernel(
    const float* __restrict__ Qp, const float* __restrict__ Kp,
    const float* __restrict__ rsump, const float* __restrict__ csump,
    const float* __restrict__ xmul, const float* __restrict__ xblend,
    float* __restrict__ outp) {
  const int ub = blockIdx.x;        // 0..4
  const int row = blockIdx.y;       // 0..319
  const int b = row / H_, h = row - b*H_;
  const int u0 = ub * 64;
  const int tid = threadIdx.x;
  const int ti = tid & 15, tj = tid >> 4;

  __shared__ float Qs[64*68];   // [c][k], k: 0..63 core, 64..67 halo rows
  __shared__ float KE[68*65];   // phase A: Ks[c][v] stride 64; phase B: E[r][v] stride 65
  __shared__ float Xm[64*68];   // [v][c] stride 68
  __shared__ float rinv[68];
  __shared__ float cinv[64];
  __shared__ float Vacc[64];

  const size_t rowoff = (size_t)b*C0_*HW_ + (size_t)h*W_;
  const float* rsrow = rsump + (size_t)row*W_;
  const float* csrow = csump + (size_t)row*W_;

  for (int i = tid; i < 64*68; i += 256) {
    int c = i / 68, k = i - c*68;
    int u = halo_u(k, u0);
    Qs[i] = (u >= 0 && u < W_) ? Qp[rowoff + (size_t)c*HW_ + u] : 0.f;
  }
  if (tid < 68) {
    int u = halo_u(tid, u0);
    rinv[tid] = (u >= 0 && u < W_) ? 1.f / rsrow[u] : 0.f;
  }
  if (tid < 64) Vacc[tid] = 0.f;

  float acc[4][4] = {};

  for (int vb = 0; vb < 5; ++vb) {
    const int v0 = vb * 64;
    __syncthreads();
    for (int i = tid; i < 4096; i += 256) {
      int c = i >> 6, v = i & 63;
      KE[c*64 + v] = Kp[rowoff + (size_t)c*HW_ + v0 + v];
    }
    for (int i = tid; i < 4096; i += 256) {
      int c = i >> 6, v = i & 63;
      Xm[v*68 + c] = xmul[rowoff + (size_t)c*HW_ + v0 + v];
    }
    if (tid < 64) cinv[tid] = 1.f / csrow[v0 + tid];
    __syncthreads();

    // core 64x64 S tile
    float sacc[4][4] = {};
    #pragma unroll 4
    for (int c = 0; c < 64; ++c) {
      const float4 a4 = *reinterpret_cast<const float4*>(&Qs[c*68 + ti*4]);
      const float4 b4 = *reinterpret_cast<const float4*>(&KE[c*64 + tj*4]);
      const float av[4] = {a4.x, a4.y, a4.z, a4.w};
      const float bv[4] = {b4.x, b4.y, b4.z, b4.w};
      #pragma unroll
      for (int i = 0; i < 4; ++i)
        #pragma unroll
        for (int j = 0; j < 4; ++j)
          sacc[i][j] = fmaf(av[i], bv[j], sacc[i][j]);
    }
    // halo S: 4 rows x 64 v, one value per thread
    const int hi = tid >> 6, hv = tid & 63;
    float sh = 0.f;
    #pragma unroll 8
    for (int c = 0; c < 64; ++c)
      sh = fmaf(Qs[c*68 + 64 + hi], KE[c*64 + hv], sh);
    __syncthreads();

    // overwrite KE with E (stride 65)
    #pragma unroll
    for (int i = 0; i < 4; ++i)
      #pragma unroll
      for (int j = 0; j < 4; ++j)
        KE[(ti*4+i)*65 + tj*4+j] = __expf(sacc[i][j]);
    {
      int u = halo_u(64 + hi, u0);
      KE[(64+hi)*65 + hv] = (u >= 0 && u < W_) ? __expf(sh) : 0.f;
    }
    __syncthreads();

    // xT accumulation: acc[u][c] += E[u][v] * Xm[v][c]
    #pragma unroll 4
    for (int v = 0; v < 64; ++v) {
      const float4 xv = *reinterpret_cast<const float4*>(&Xm[v*68 + tj*4]);
      const float xa[4] = {xv.x, xv.y, xv.z, xv.w};
      float ev[4];
      #pragma unroll
      for (int i = 0; i < 4; ++i) ev[i] = KE[(ti*4+i)*65 + v];
      #pragma unroll
      for (int i = 0; i < 4; ++i)
        #pragma unroll
        for (int j = 0; j < 4; ++j)
          acc[i][j] = fmaf(ev[i], xa[j], acc[i][j]);
    }

    // banded V accumulation
    float vp[4] = {};
    #pragma unroll
    for (int i2 = 0; i2 < 4; ++i2) {
      const int icore = ti*4 + i2;
      #pragma unroll
      for (int j2 = 0; j2 < 4; ++j2) {
        const int jj = tj*4 + j2;
        float pr = 0.f;
        #pragma unroll
        for (int d = -2; d <= 2; ++d) {
          int r = icore + d;
          int rr = (r < 0) ? (66 + r) : (r > 63) ? (r + 2) : r;
          pr = fmaf(KE[rr*65 + jj], rinv[rr], pr);
        }
        vp[i2] = fmaf(KE[icore*65 + jj] * cinv[jj], pr, vp[i2]);
      }
    }
    #pragma unroll
    for (int i2 = 0; i2 < 4; ++i2)
      unsafeAtomicAdd(&Vacc[ti*4 + i2], vp[i2]);
  }
  __syncthreads();

  float tvals[4], rvals[4];
  #pragma unroll
  for (int i2 = 0; i2 < 4; ++i2) {
    tvals[i2] = tanhf(5.f * Vacc[ti*4 + i2]);
    rvals[i2] = rinv[ti*4 + i2];
  }
  #pragma unroll
  for (int j2 = 0; j2 < 4; ++j2) {
    const int c = tj*4 + j2;
    const size_t base = rowoff + (size_t)c*HW_ + u0 + ti*4;
    const float4 xb4 = *reinterpret_cast<const float4*>(&xblend[base]);
    const float xbv[4] = {xb4.x, xb4.y, xb4.z, xb4.w};
    float ov[4];
    #pragma unroll
    for (int i2 = 0; i2 < 4; ++i2) {
      float xT = acc[i2][j2] * rvals[i2];
      ov[i2] = xbv[i2] * (1.f - tvals[i2]) + xT * tvals[i2];
    }
    float4 o4; o4.x = ov[0]; o4.y = ov[1]; o4.z = ov[2]; o4.w = ov[3];
    *reinterpret_cast<float4*>(&outp[base]) = o4;
  }
}

// ---------------------------------------------------------------------------
extern "C" void kernel_launch(void* const* d_in, const int* in_sizes, int n_in,
                              void* d_out, int out_size, void* d_ws, size_t ws_size,
                              hipStream_t stream) {
  const float* x_left  = (const float*)d_in[0];
  const float* x_right = (const float*)d_in[1];
  const float* catL    = (const float*)d_in[2];
  const float* catR    = (const float*)d_in[3];
  const float* bq_w    = (const float*)d_in[4];
  const float* bq_b    = (const float*)d_in[5];
  const float* bs_w    = (const float*)d_in[6];
  const float* bs_b    = (const float*)d_in[7];
  const float* rb_w1   = (const float*)d_in[8];
  const float* rb_b1   = (const float*)d_in[9];
  const float* rb_w2   = (const float*)d_in[10];
  const float* rb_b2   = (const float*)d_in[11];
  const float* gamma   = (const float*)d_in[12];
  const float* beta    = (const float*)d_in[13];

  float* ws = (float*)d_ws;
  size_t off = 0;
  float* wT1 = ws + off; off += WT_SZ;
  float* WfQ = ws + off; off += WF_SZ;
  float* WfK = ws + off; off += WF_SZ;
  float* bqaL= ws + off; off += BQA_SZ;
  float* bsaR= ws + off; off += BQA_SZ;
  float* bfQ = ws + off; off += BF_SZ;
  float* bfK = ws + off; off += BF_SZ;
  float* ab  = ws + off; off += AB_SZ;
  float* t1  = ws + off; off += T1_SZ;
  float* Qb  = ws + off; off += QK_SZ;
  float* Kb  = ws + off; off += QK_SZ;
  float* rsb = ws + off; off += RS_SZ;
  float* csb = ws + off; off += RS_SZ;
  float* csp = ws + off; off += CSP_SZ;

  wtrans_kernel<<<WT_SZ/256, 256, 0, stream>>>(rb_w1, rb_w2, bq_w, bs_w, wT1, WfQ, WfK);
  bnstats_kernel<<<512, 256, 0, stream>>>(catL, catR, gamma, beta, ab);
  prep2_kernel<<<32, 256, 0, stream>>>(bq_w, bs_w, bq_b, bs_b, rb_b2, ab, bqaL, bsaR, bfQ, bfK);

  dim3 cgrid(W_/TW_, H_/TH_, B_*G_);
  // left side -> Q
  conv1_kernel<<<cgrid, 256, 0, stream>>>(catL, ab, wT1, rb_b1, t1);
  conv2q_kernel<<<cgrid, 256, 0, stream>>>(t1, catL, WfQ, bqaL, bfQ, Qb);
  // right side -> K
  conv1_kernel<<<cgrid, 256, 0, stream>>>(catR, ab + 512, wT1, rb_b1, t1);
  conv2q_kernel<<<cgrid, 256, 0, stream>>>(t1, catR, WfK, bsaR, bfK, Kb);

  rowmean_kernel<<<B_*C0_*H_, 64, 0, stream>>>(Qb);
  rowmean_kernel<<<B_*C0_*H_, 64, 0, stream>>>(Kb);

  stats_kernel<<<dim3(5, NROWS_), 256, 0, stream>>>(Qb, Kb, rsb, csp);
  csreduce_kernel<<<(int)((RS_SZ + 255)/256), 256, 0, stream>>>(csp, csb);

  float* outL = (float*)d_out;
  float* outR = outL + QK_SZ;
  attn_kernel<<<dim3(5, NROWS_), 256, 0, stream>>>(Qb, Kb, rsb, csb, x_right, x_left, outL);
  attn_kernel<<<dim3(5, NROWS_), 256, 0, stream>>>(Kb, Qb, csb, rsb, x_left, x_right, outR);
}

// Round 4
// 1278.305 us; speedup vs baseline: 4.2256x; 1.7121x over previous
//
#include <hip/hip_runtime.h>

#define B_    2
#define C0_   64
#define C4_   256
#define H_    160
#define W_    320
#define G_    4
#define HW_   (H_*W_)
#define NROWS_ (B_*H_)      // 320
#define EPS_  1e-5f

typedef float f32x4 __attribute__((ext_vector_type(4)));
typedef short s16x8 __attribute__((ext_vector_type(8)));

// workspace sizes (in floats)
#define WFQ_SZ  36864       // f32 [g][tap9][o16][ic64]
#define WB_SZ   73728       // bf16 conv1 weights [g][tap9][oc64][ic64] (147456 shorts)
#define W2B_SZ  20480       // bf16 fused conv2 weights [g][tap10][o16][ic64] (40960 shorts)
#define AB_SZ   1024
#define BF_SZ   64
#define T1_SZ   13107200    // bf16 t1 [b][g][h][w][ic64] (26214400 shorts)
#define QK_SZ   ((size_t)B_*C0_*HW_)   // 6553600
#define RS_SZ   ((size_t)NROWS_*W_)    // 102400
#define CSP_SZ  ((size_t)NROWS_*5*W_)  // 512000

__device__ __forceinline__ unsigned f2bf1(float x) {
  unsigned u = __float_as_uint(x);
  return (u + 0x7FFFu + ((u >> 16) & 1u)) >> 16;
}
__device__ __forceinline__ unsigned packbf(float lo, float hi) {
  return f2bf1(lo) | (f2bf1(hi) << 16);
}

// ---------------------------------------------------------------------------
// wtrans: Wb bf16 [g][tap][oc][ic]; WfQ/WfK f32 [g][tap][o16][ic] (proj-folded)
__global__ __launch_bounds__(256) void wtrans_kernel(
    const float* __restrict__ w1, const float* __restrict__ w2,
    const float* __restrict__ bq, const float* __restrict__ bs,
    unsigned short* __restrict__ Wb, float* __restrict__ WfQ, float* __restrict__ WfK) {
  int idx = blockIdx.x * 256 + threadIdx.x;
  if (idx < 147456) {
    int ic = idx & 63, oc = (idx >> 6) & 63, tap = (idx >> 12) % 9, g = idx / 36864;
    float v = w1[((size_t)(g*64 + oc) * 64 + ic) * 9 + tap];
    Wb[idx] = (unsigned short)f2bf1(v);
  }
  if (idx < 36864) {
    int ic = idx & 63, o = (idx >> 6) & 15, tap = (idx >> 10) % 9, g = idx / 9216;
    const float* w2p = w2 + ((size_t)(g*64) * 64 + ic) * 9 + tap;   // + oc*576
    const float* bqp = bq + (size_t)(g*16 + o) * 64;
    const float* bsp = bs + (size_t)(g*16 + o) * 64;
    float sq = 0.f, sk = 0.f;
    for (int oc = 0; oc < 64; ++oc) {
      float wv = w2p[(size_t)oc * 576];
      sq = fmaf(bqp[oc], wv, sq);
      sk = fmaf(bsp[oc], wv, sk);
    }
    WfQ[idx] = sq;
    WfK[idx] = sk;
  }
}

// ---------------------------------------------------------------------------
__global__ __launch_bounds__(256) void bnstats_kernel(
    const float* __restrict__ catL, const float* __restrict__ catR,
    const float* __restrict__ gamma, const float* __restrict__ beta,
    float* __restrict__ ab) {
  int sc = blockIdx.x;          // 0..511
  int side = sc >> 8, c = sc & 255;
  const float* base = (side ? catR : catL) + (size_t)c * HW_;
  float s = 0.f, s2 = 0.f;
  for (int i = threadIdx.x; i < HW_; i += 256) {
    float v0 = base[i];
    float v1 = base[(size_t)C4_*HW_ + i];
    s  += v0 + v1;
    s2 += fmaf(v0, v0, v1*v1);
  }
  #pragma unroll
  for (int o = 32; o; o >>= 1) { s += __shfl_down(s, o); s2 += __shfl_down(s2, o); }
  __shared__ float rs[4], rs2[4];
  int wid = threadIdx.x >> 6;
  if ((threadIdx.x & 63) == 0) { rs[wid] = s; rs2[wid] = s2; }
  __syncthreads();
  if (threadIdx.x == 0) {
    float S  = rs[0]+rs[1]+rs[2]+rs[3];
    float S2 = rs2[0]+rs2[1]+rs2[2]+rs2[3];
    float inv_n = 1.f / (float)(2*HW_);
    float mu  = S * inv_n;
    float var = S2 * inv_n - mu*mu;
    float a = gamma[c] * rsqrtf(var + EPS_);
    ab[side*512 + c]       = a;
    ab[side*512 + 256 + c] = beta[c] - mu*a;
  }
}

// ---------------------------------------------------------------------------
// prep2: W2bQ/K bf16 [g][tap10][o][ic] (tap9 = residual bqa = projw*BNscale);
// bfQ/bfK[o] = proj_bias + sum_c projw*(b2_c + BNshift_c)
__global__ __launch_bounds__(256) void prep2_kernel(
    const float* __restrict__ bq, const float* __restrict__ bs,
    const float* __restrict__ bqb, const float* __restrict__ bsb,
    const float* __restrict__ b2, const float* __restrict__ ab,
    const float* __restrict__ WfQ, const float* __restrict__ WfK,
    unsigned short* __restrict__ W2bQ, unsigned short* __restrict__ W2bK,
    float* __restrict__ bfQ, float* __restrict__ bfK) {
  int idx = blockIdx.x*256 + threadIdx.x;
  if (idx < 40960) {
    int ic = idx & 63, o = (idx >> 6) & 15, tap = (idx >> 10) % 10, g = idx / 10240;
    float vq, vk;
    if (tap < 9) {
      int src = ((g*9 + tap)*16 + o)*64 + ic;
      vq = WfQ[src]; vk = WfK[src];
    } else {
      vq = bq[(size_t)(g*16 + o)*64 + ic] * ab[g*64 + ic];
      vk = bs[(size_t)(g*16 + o)*64 + ic] * ab[512 + g*64 + ic];
    }
    W2bQ[idx] = (unsigned short)f2bf1(vq);
    W2bK[idx] = (unsigned short)f2bf1(vk);
  }
  if (idx < 128) {
    int side = idx >> 6, co = idx & 63, g = co >> 4, o = co & 15;
    const float* w = side ? bs : bq;
    float s = (side ? bsb : bqb)[co];
    for (int c2 = 0; c2 < 64; ++c2) {
      int ch = g*64 + c2;
      s = fmaf(w[(size_t)(g*16 + o)*64 + c2], b2[ch] + ab[side*512 + 256 + ch], s);
    }
    (side ? bfK : bfQ)[co] = s;
  }
}

// ---------------------------------------------------------------------------
// conv1 MFMA: t1[b][g][h][w][oc64](bf16) = leaky(gconv3x3(bn(cat)) + b1)
// tile: 64 oc x 128 px (2 rows x 64 w). 4 waves split oc. K = tap*64+ic.
__global__ __launch_bounds__(256) void conv1_mfma(
    const float* __restrict__ cat, const float* __restrict__ ab,
    const unsigned short* __restrict__ Wb, const float* __restrict__ bias,
    unsigned short* __restrict__ t1) {
  const int b = blockIdx.z >> 2, g = blockIdx.z & 3;
  const int h0 = blockIdx.y * 2, w0 = blockIdx.x * 64;
  const int tid = threadIdx.x;
  const int lane = tid & 63, wv = tid >> 6;
  const int m0 = wv * 16;
  const int m = lane & 15, kg = lane >> 4;
  __shared__ short Xs[4*66*72];   // [r4][c66][icpad72] bf16, BN applied

  // ---- stage: 4 rows x 66 cols x 64 ic, (c,c+1)x(ic,ic+1) micro-tiles
  const float* catg = cat + ((size_t)b*C4_ + g*64) * HW_;
  for (int u = tid; u < 32*132; u += 256) {
    int icp = u / 132;            // ic pair
    int rc  = u - icp*132;
    int r   = rc / 33, cp = rc - r*33;
    int c   = cp * 2;
    int gh  = h0 - 1 + r;
    int gw  = w0 - 1 + c;
    float vA0 = 0.f, vA1 = 0.f, vB0 = 0.f, vB1 = 0.f;
    if (gh >= 0 && gh < H_) {
      const float* srcA = catg + (size_t)(2*icp)*HW_ + gh*W_;
      const float* srcB = srcA + HW_;
      const float2 a2 = *(const float2*)&ab[g*64 + 2*icp];
      const float2 s2 = *(const float2*)&ab[256 + g*64 + 2*icp];
      if (gw >= 0)       { vA0 = fmaf(a2.x, srcA[gw],   s2.x); vB0 = fmaf(a2.y, srcB[gw],   s2.y); }
      if (gw + 1 < W_)   { vA1 = fmaf(a2.x, srcA[gw+1], s2.x); vB1 = fmaf(a2.y, srcB[gw+1], s2.y); }
    }
    int base = (r*66 + c)*72 + 2*icp;
    *(unsigned*)&Xs[base]      = packbf(vA0, vB0);
    *(unsigned*)&Xs[base + 72] = packbf(vA1, vB1);
  }

  // ---- A prefetch (weights, registers)
  s16x8 afrag[18];
  #pragma unroll
  for (int s = 0; s < 18; ++s) {
    const int tap = s >> 1, ic0 = (s & 1)*32 + kg*8;
    afrag[s] = *(const s16x8*)&Wb[(((size_t)g*9 + tap)*64 + m0 + m)*64 + ic0];
  }
  __syncthreads();

  // ---- K loop
  f32x4 acc[8] = {};
  #pragma unroll
  for (int s = 0; s < 18; ++s) {
    const int tap = s >> 1, dh = tap / 3, dw = tap - dh*3;
    const int ic0 = (s & 1)*32 + kg*8;
    #pragma unroll
    for (int t = 0; t < 8; ++t) {
      const int px = t*16 + m;
      const int r = px >> 6, wl = px & 63;
      const s16x8 bfrag = *(const s16x8*)&Xs[((r + dh)*66 + wl + dw)*72 + ic0];
      acc[t] = __builtin_amdgcn_mfma_f32_16x16x32_bf16(afrag[s], bfrag, acc[t], 0, 0, 0);
    }
  }

  // ---- epilogue: bias + leaky + bf16 pack, t1[px][oc]
  const int ocq = m0 + kg*4;
  const float4 b4 = *(const float4*)&bias[g*64 + ocq];
  const float bb[4] = {b4.x, b4.y, b4.z, b4.w};
  #pragma unroll
  for (int t = 0; t < 8; ++t) {
    const int px = t*16 + m;
    const int h = h0 + (px >> 6), w = w0 + (px & 63);
    float v[4];
    #pragma unroll
    for (int r = 0; r < 4; ++r) {
      float x = acc[t][r] + bb[r];
      v[r] = (x >= 0.f) ? x : 0.1f * x;
    }
    const size_t base = ((((size_t)(b*4 + g)*H_ + h)*W_ + w) << 6) + ocq;
    uint2 pk; pk.x = packbf(v[0], v[1]); pk.y = packbf(v[2], v[3]);
    *(uint2*)&t1[base] = pk;
  }
}

// ---------------------------------------------------------------------------
// conv2 MFMA + folded 1x1 proj + residual-as-K: Q[b][c16g][h][w] f32
// tile: 16 oc x 128 px. 4 waves split px (2 n-tiles each). K = 576 + 64.
__global__ __launch_bounds__(256) void conv2_mfma(
    const unsigned short* __restrict__ t1, const float* __restrict__ cat,
    const float* __restrict__ ab, const unsigned short* __restrict__ W2b,
    const float* __restrict__ bf, float* __restrict__ qout) {
  const int b = blockIdx.z >> 2, g = blockIdx.z & 3;
  const int h0 = blockIdx.y * 2, w0 = blockIdx.x * 64;
  const int tid = threadIdx.x;
  const int lane = tid & 63, wv = tid >> 6;
  const int m = lane & 15, kg = lane >> 4;
  __shared__ short Ys[4*66*72];    // t1 tile [r][c][icpad]
  __shared__ short Rs[128*72];     // residual [px][icpad] = BNscale*cat

  // ---- stage Ys: 16B chunks from ic-contiguous t1
  const unsigned short* t1g = t1 + (((size_t)(b*4 + g)*H_) << 6) * W_;
  for (int u = tid; u < 264*8; u += 256) {
    int rc = u >> 3, j = u & 7;
    int r = rc / 66, c = rc - r*66;
    int gh = h0 - 1 + r, gw = w0 - 1 + c;
    s16x8 v = {};
    if (gh >= 0 && gh < H_ && gw >= 0 && gw < W_)
      v = *(const s16x8*)&t1g[(((size_t)gh*W_ + gw) << 6) + j*8];
    *(s16x8*)&Ys[(rc*72) + j*8] = v;
  }
  // ---- stage Rs: scale*cat, (ic,ic+1) pairs
  const float* catg = cat + ((size_t)b*C4_ + g*64) * HW_;
  for (int u = tid; u < 32*128; u += 256) {
    int icp = u >> 7, px = u & 127;
    int gh = h0 + (px >> 6), gw = w0 + (px & 63);
    const float2 a2 = *(const float2*)&ab[g*64 + 2*icp];
    float vA = a2.x * catg[(size_t)(2*icp)*HW_ + gh*W_ + gw];
    float vB = a2.y * catg[(size_t)(2*icp + 1)*HW_ + gh*W_ + gw];
    *(unsigned*)&Rs[px*72 + 2*icp] = packbf(vA, vB);
  }

  // ---- A prefetch: 20 k-steps (18 conv + 2 residual)
  s16x8 afrag[20];
  #pragma unroll
  for (int s = 0; s < 20; ++s) {
    const int tap = (s < 18) ? (s >> 1) : 9;
    const int ic0 = (s < 18) ? ((s & 1)*32 + kg*8) : ((s - 18)*32 + kg*8);
    afrag[s] = *(const s16x8*)&W2b[(((size_t)g*10 + tap)*16 + m)*64 + ic0];
  }
  __syncthreads();

  // ---- K loop: this wave owns n-tiles {2wv, 2wv+1}
  f32x4 acc[2] = {};
  #pragma unroll
  for (int s = 0; s < 18; ++s) {
    const int tap = s >> 1, dh = tap / 3, dw = tap - dh*3;
    const int ic0 = (s & 1)*32 + kg*8;
    #pragma unroll
    for (int t = 0; t < 2; ++t) {
      const int px = (wv*2 + t)*16 + m;
      const int r = px >> 6, wl = px & 63;
      const s16x8 bfrag = *(const s16x8*)&Ys[((r + dh)*66 + wl + dw)*72 + ic0];
      acc[t] = __builtin_amdgcn_mfma_f32_16x16x32_bf16(afrag[s], bfrag, acc[t], 0, 0, 0);
    }
  }
  #pragma unroll
  for (int s = 18; s < 20; ++s) {
    const int ic0 = (s - 18)*32 + kg*8;
    #pragma unroll
    for (int t = 0; t < 2; ++t) {
      const int px = (wv*2 + t)*16 + m;
      const s16x8 bfrag = *(const s16x8*)&Rs[px*72 + ic0];
      acc[t] = __builtin_amdgcn_mfma_f32_16x16x32_bf16(afrag[s], bfrag, acc[t], 0, 0, 0);
    }
  }

  // ---- epilogue: + bf, write Q f32 [b][g*16+oc][h][w]
  const int ocq = kg*4;
  const float4 q4 = *(const float4*)&bf[g*16 + ocq];
  const float qb[4] = {q4.x, q4.y, q4.z, q4.w};
  #pragma unroll
  for (int t = 0; t < 2; ++t) {
    const int px = (wv*2 + t)*16 + m;
    const int h = h0 + (px >> 6), w = w0 + (px & 63);
    #pragma unroll
    for (int r = 0; r < 4; ++r) {
      const int oc = g*16 + ocq + r;
      qout[((size_t)(b*64 + oc)*H_ + h)*W_ + w] = acc[t][r] + qb[r];
    }
  }
}

// ---------------------------------------------------------------------------
__global__ __launch_bounds__(64) void rowmean_kernel(float* __restrict__ q) {
  float* p = q + (size_t)blockIdx.x * W_;
  const int lane = threadIdx.x;
  float v[5]; float s = 0.f;
  #pragma unroll
  for (int k = 0; k < 5; ++k) { v[k] = p[lane + 64*k]; s += v[k]; }
  #pragma unroll
  for (int o = 32; o; o >>= 1) s += __shfl_xor(s, o);
  const float m = s * (1.f/320.f);
  #pragma unroll
  for (int k = 0; k < 5; ++k) p[lane + 64*k] = v[k] - m;
}

// ---------------------------------------------------------------------------
__global__ __launch_bounds__(256) void stats_kernel(
    const float* __restrict__ Qp, const float* __restrict__ Kp,
    float* __restrict__ rsum, float* __restrict__ cspart) {
  const int ub = blockIdx.x, row = blockIdx.y;
  const int b = row / H_, h = row - b*H_;
  const int tid = threadIdx.x;
  const int ti = tid & 15, tj = tid >> 4;
  __shared__ float Qs[4096], Ks[4096];
  __shared__ float rs[64], cs[W_];
  for (int i = tid; i < W_; i += 256) cs[i] = 0.f;
  if (tid < 64) rs[tid] = 0.f;
  const size_t rowoff = (size_t)b*C0_*HW_ + (size_t)h*W_;
  for (int i = tid; i < 4096; i += 256) {
    int c = i >> 6, u = i & 63;
    Qs[i] = Qp[rowoff + (size_t)c*HW_ + ub*64 + u];
  }
  for (int vb = 0; vb < 5; ++vb) {
    __syncthreads();
    for (int i = tid; i < 4096; i += 256) {
      int c = i >> 6, v = i & 63;
      Ks[i] = Kp[rowoff + (size_t)c*HW_ + vb*64 + v];
    }
    __syncthreads();
    float sacc[4][4] = {};
    #pragma unroll 4
    for (int c = 0; c < 64; ++c) {
      const float4 a4 = *reinterpret_cast<const float4*>(&Qs[c*64 + ti*4]);
      const float4 b4 = *reinterpret_cast<const float4*>(&Ks[c*64 + tj*4]);
      const float av[4] = {a4.x, a4.y, a4.z, a4.w};
      const float bv[4] = {b4.x, b4.y, b4.z, b4.w};
      #pragma unroll
      for (int i = 0; i < 4; ++i)
        #pragma unroll
        for (int j = 0; j < 4; ++j)
          sacc[i][j] = fmaf(av[i], bv[j], sacc[i][j]);
    }
    float rp[4] = {}, cp[4] = {};
    #pragma unroll
    for (int i = 0; i < 4; ++i)
      #pragma unroll
      for (int j = 0; j < 4; ++j) {
        float e = __expf(sacc[i][j]);
        rp[i] += e; cp[j] += e;
      }
    #pragma unroll
    for (int i = 0; i < 4; ++i) unsafeAtomicAdd(&rs[ti*4 + i], rp[i]);
    #pragma unroll
    for (int j = 0; j < 4; ++j) unsafeAtomicAdd(&cs[vb*64 + tj*4 + j], cp[j]);
  }
  __syncthreads();
  if (tid < 64) rsum[(size_t)row*W_ + ub*64 + tid] = rs[tid];
  for (int i = tid; i < W_; i += 256) cspart[((size_t)row*5 + ub)*W_ + i] = cs[i];
}

__global__ __launch_bounds__(256) void csreduce_kernel(
    const float* __restrict__ csp, float* __restrict__ csum) {
  int idx = blockIdx.x*256 + threadIdx.x;
  if (idx >= (int)RS_SZ) return;
  int row = idx / W_, v = idx - row*W_;
  float s = 0.f;
  #pragma unroll
  for (int ub = 0; ub < 5; ++ub) s += csp[((size_t)row*5 + ub)*W_ + v];
  csum[idx] = s;
}

// ---------------------------------------------------------------------------
__device__ __forceinline__ int halo_u(int k, int u0) {
  if (k < 64) return u0 + k;
  return (k == 64) ? (u0-2) : (k == 65) ? (u0-1) : (k == 66) ? (u0+64) : (u0+65);
}

__global__ __launch_bounds__(256) void attn_kernel(
    const float* __restrict__ Qp, const float* __restrict__ Kp,
    const float* __restrict__ rsump, const float* __restrict__ csump,
    const float* __restrict__ xmul, const float* __restrict__ xblend,
    float* __restrict__ outp) {
  const int ub = blockIdx.x;        // 0..4
  const int row = blockIdx.y;       // 0..319
  const int b = row / H_, h = row - b*H_;
  const int u0 = ub * 64;
  const int tid = threadIdx.x;
  const int ti = tid & 15, tj = tid >> 4;

  __shared__ float Qs[64*68];
  __shared__ float KE[68*65];
  __shared__ float Xm[64*68];
  __shared__ float rinv[68];
  __shared__ float cinv[64];
  __shared__ float Vacc[64];

  const size_t rowoff = (size_t)b*C0_*HW_ + (size_t)h*W_;
  const float* rsrow = rsump + (size_t)row*W_;
  const float* csrow = csump + (size_t)row*W_;

  for (int i = tid; i < 64*68; i += 256) {
    int c = i / 68, k = i - c*68;
    int u = halo_u(k, u0);
    Qs[i] = (u >= 0 && u < W_) ? Qp[rowoff + (size_t)c*HW_ + u] : 0.f;
  }
  if (tid < 68) {
    int u = halo_u(tid, u0);
    rinv[tid] = (u >= 0 && u < W_) ? 1.f / rsrow[u] : 0.f;
  }
  if (tid < 64) Vacc[tid] = 0.f;

  float acc[4][4] = {};

  for (int vb = 0; vb < 5; ++vb) {
    const int v0 = vb * 64;
    __syncthreads();
    for (int i = tid; i < 4096; i += 256) {
      int c = i >> 6, v = i & 63;
      KE[c*64 + v] = Kp[rowoff + (size_t)c*HW_ + v0 + v];
    }
    for (int i = tid; i < 4096; i += 256) {
      int c = i >> 6, v = i & 63;
      Xm[v*68 + c] = xmul[rowoff + (size_t)c*HW_ + v0 + v];
    }
    if (tid < 64) cinv[tid] = 1.f / csrow[v0 + tid];
    __syncthreads();

    float sacc[4][4] = {};
    #pragma unroll 4
    for (int c = 0; c < 64; ++c) {
      const float4 a4 = *reinterpret_cast<const float4*>(&Qs[c*68 + ti*4]);
      const float4 b4 = *reinterpret_cast<const float4*>(&KE[c*64 + tj*4]);
      const float av[4] = {a4.x, a4.y, a4.z, a4.w};
      const float bv[4] = {b4.x, b4.y, b4.z, b4.w};
      #pragma unroll
      for (int i = 0; i < 4; ++i)
        #pragma unroll
        for (int j = 0; j < 4; ++j)
          sacc[i][j] = fmaf(av[i], bv[j], sacc[i][j]);
    }
    const int hi = tid >> 6, hv = tid & 63;
    float sh = 0.f;
    #pragma unroll 8
    for (int c = 0; c < 64; ++c)
      sh = fmaf(Qs[c*68 + 64 + hi], KE[c*64 + hv], sh);
    __syncthreads();

    #pragma unroll
    for (int i = 0; i < 4; ++i)
      #pragma unroll
      for (int j = 0; j < 4; ++j)
        KE[(ti*4+i)*65 + tj*4+j] = __expf(sacc[i][j]);
    {
      int u = halo_u(64 + hi, u0);
      KE[(64+hi)*65 + hv] = (u >= 0 && u < W_) ? __expf(sh) : 0.f;
    }
    __syncthreads();

    #pragma unroll 4
    for (int v = 0; v < 64; ++v) {
      const float4 xv = *reinterpret_cast<const float4*>(&Xm[v*68 + tj*4]);
      const float xa[4] = {xv.x, xv.y, xv.z, xv.w};
      float ev[4];
      #pragma unroll
      for (int i = 0; i < 4; ++i) ev[i] = KE[(ti*4+i)*65 + v];
      #pragma unroll
      for (int i = 0; i < 4; ++i)
        #pragma unroll
        for (int j = 0; j < 4; ++j)
          acc[i][j] = fmaf(ev[i], xa[j], acc[i][j]);
    }

    float vp[4] = {};
    #pragma unroll
    for (int i2 = 0; i2 < 4; ++i2) {
      const int icore = ti*4 + i2;
      #pragma unroll
      for (int j2 = 0; j2 < 4; ++j2) {
        const int jj = tj*4 + j2;
        float pr = 0.f;
        #pragma unroll
        for (int d = -2; d <= 2; ++d) {
          int r = icore + d;
          int rr = (r < 0) ? (66 + r) : (r > 63) ? (r + 2) : r;
          pr = fmaf(KE[rr*65 + jj], rinv[rr], pr);
        }
        vp[i2] = fmaf(KE[icore*65 + jj] * cinv[jj], pr, vp[i2]);
      }
    }
    #pragma unroll
    for (int i2 = 0; i2 < 4; ++i2)
      unsafeAtomicAdd(&Vacc[ti*4 + i2], vp[i2]);
  }
  __syncthreads();

  float tvals[4], rvals[4];
  #pragma unroll
  for (int i2 = 0; i2 < 4; ++i2) {
    tvals[i2] = tanhf(5.f * Vacc[ti*4 + i2]);
    rvals[i2] = rinv[ti*4 + i2];
  }
  #pragma unroll
  for (int j2 = 0; j2 < 4; ++j2) {
    const int c = tj*4 + j2;
    const size_t base = rowoff + (size_t)c*HW_ + u0 + ti*4;
    const float4 xb4 = *reinterpret_cast<const float4*>(&xblend[base]);
    const float xbv[4] = {xb4.x, xb4.y, xb4.z, xb4.w};
    float ov[4];
    #pragma unroll
    for (int i2 = 0; i2 < 4; ++i2) {
      float xT = acc[i2][j2] * rvals[i2];
      ov[i2] = xbv[i2] * (1.f - tvals[i2]) + xT * tvals[i2];
    }
    float4 o4; o4.x = ov[0]; o4.y = ov[1]; o4.z = ov[2]; o4.w = ov[3];
    *reinterpret_cast<float4*>(&outp[base]) = o4;
  }
}

// ---------------------------------------------------------------------------
extern "C" void kernel_launch(void* const* d_in, const int* in_sizes, int n_in,
                              void* d_out, int out_size, void* d_ws, size_t ws_size,
                              hipStream_t stream) {
  const float* x_left  = (const float*)d_in[0];
  const float* x_right = (const float*)d_in[1];
  const float* catL    = (const float*)d_in[2];
  const float* catR    = (const float*)d_in[3];
  const float* bq_w    = (const float*)d_in[4];
  const float* bq_b    = (const float*)d_in[5];
  const float* bs_w    = (const float*)d_in[6];
  const float* bs_b    = (const float*)d_in[7];
  const float* rb_w1   = (const float*)d_in[8];
  const float* rb_b1   = (const float*)d_in[9];
  const float* rb_w2   = (const float*)d_in[10];
  const float* rb_b2   = (const float*)d_in[11];
  const float* gamma   = (const float*)d_in[12];
  const float* beta    = (const float*)d_in[13];

  float* ws = (float*)d_ws;
  size_t off = 0;
  float* WfQ = ws + off; off += WFQ_SZ;
  float* WfK = ws + off; off += WFQ_SZ;
  unsigned short* Wb   = (unsigned short*)(ws + off); off += WB_SZ;
  unsigned short* W2bQ = (unsigned short*)(ws + off); off += W2B_SZ;
  unsigned short* W2bK = (unsigned short*)(ws + off); off += W2B_SZ;
  float* ab  = ws + off; off += AB_SZ;
  float* bfQ = ws + off; off += BF_SZ;
  float* bfK = ws + off; off += BF_SZ;
  unsigned short* t1 = (unsigned short*)(ws + off); off += T1_SZ;
  float* Qb  = ws + off; off += QK_SZ;
  float* Kb  = ws + off; off += QK_SZ;
  float* rsb = ws + off; off += RS_SZ;
  float* csb = ws + off; off += RS_SZ;
  float* csp = ws + off; off += CSP_SZ;

  wtrans_kernel<<<576, 256, 0, stream>>>(rb_w1, rb_w2, bq_w, bs_w, Wb, WfQ, WfK);
  bnstats_kernel<<<512, 256, 0, stream>>>(catL, catR, gamma, beta, ab);
  prep2_kernel<<<160, 256, 0, stream>>>(bq_w, bs_w, bq_b, bs_b, rb_b2, ab,
                                        WfQ, WfK, W2bQ, W2bK, bfQ, bfK);

  dim3 cgrid(5, 80, 8);
  // left -> Q
  conv1_mfma<<<cgrid, 256, 0, stream>>>(catL, ab, Wb, rb_b1, t1);
  conv2_mfma<<<cgrid, 256, 0, stream>>>(t1, catL, ab, W2bQ, bfQ, Qb);
  // right -> K
  conv1_mfma<<<cgrid, 256, 0, stream>>>(catR, ab + 512, Wb, rb_b1, t1);
  conv2_mfma<<<cgrid, 256, 0, stream>>>(t1, catR, ab + 512, W2bK, bfK, Kb);

  rowmean_kernel<<<B_*C0_*H_, 64, 0, stream>>>(Qb);
  rowmean_kernel<<<B_*C0_*H_, 64, 0, stream>>>(Kb);

  stats_kernel<<<dim3(5, NROWS_), 256, 0, stream>>>(Qb, Kb, rsb, csp);
  csreduce_kernel<<<(int)((RS_SZ + 255)/256), 256, 0, stream>>>(csp, csb);

  float* outL = (float*)d_out;
  float* outR = outL + QK_SZ;
  attn_kernel<<<dim3(5, NROWS_), 256, 0, stream>>>(Qb, Kb, rsb, csb, x_right, x_left, outL);
  attn_kernel<<<dim3(5, NROWS_), 256, 0, stream>>>(Kb, Qb, csb, rsb, x_left, x_right, outR);
}

// Round 5
// 993.112 us; speedup vs baseline: 5.4391x; 1.2872x over previous
//
#include <hip/hip_runtime.h>

#define B_    2
#define C0_   64
#define C4_   256
#define H_    160
#define W_    320
#define G_    4
#define HW_   (H_*W_)
#define NROWS_ (B_*H_)      // 320
#define EPS_  1e-5f

typedef float f32x4 __attribute__((ext_vector_type(4)));
typedef short s16x8 __attribute__((ext_vector_type(8)));

// workspace sizes (in floats)
#define WFQ_SZ  36864       // f32 [g][tap9][o16][ic64]
#define WB_SZ   73728       // bf16 conv1 weights [g][tap9][oc64][ic64] (147456 shorts)
#define W2B_SZ  20480       // bf16 fused conv2 weights [g][tap10][o16][ic64] (40960 shorts)
#define AB_SZ   1024
#define BF_SZ   64
#define T1_SZ   13107200    // bf16 t1 [b][g][h][w][ic64] (26214400 shorts)
#define QK_SZ   ((size_t)B_*C0_*HW_)   // 6553600
#define RS_SZ   ((size_t)NROWS_*W_)    // 102400
#define CSP_SZ  ((size_t)NROWS_*5*W_)  // 512000

// E-tile swizzled address: row r (0..67), 16B chunk v4 (0..15).
// key = (r>>2)&15 gives full 16-value entropy across a quarter-wave's rows.
#define EADDR(r, v4) (((r) << 6) + ((((v4) ^ (((r) >> 2) & 15))) << 2))

__device__ __forceinline__ unsigned f2bf1(float x) {
  unsigned u = __float_as_uint(x);
  return (u + 0x7FFFu + ((u >> 16) & 1u)) >> 16;
}
__device__ __forceinline__ unsigned packbf(float lo, float hi) {
  return f2bf1(lo) | (f2bf1(hi) << 16);
}

// ---------------------------------------------------------------------------
// wtrans: Wb bf16 [g][tap][oc][ic]; WfQ/WfK f32 [g][tap][o16][ic] (proj-folded)
__global__ __launch_bounds__(256) void wtrans_kernel(
    const float* __restrict__ w1, const float* __restrict__ w2,
    const float* __restrict__ bq, const float* __restrict__ bs,
    unsigned short* __restrict__ Wb, float* __restrict__ WfQ, float* __restrict__ WfK) {
  int idx = blockIdx.x * 256 + threadIdx.x;
  if (idx < 147456) {
    int ic = idx & 63, oc = (idx >> 6) & 63, tap = (idx >> 12) % 9, g = idx / 36864;
    float v = w1[((size_t)(g*64 + oc) * 64 + ic) * 9 + tap];
    Wb[idx] = (unsigned short)f2bf1(v);
  }
  if (idx < 36864) {
    int ic = idx & 63, o = (idx >> 6) & 15, tap = (idx >> 10) % 9, g = idx / 9216;
    const float* w2p = w2 + ((size_t)(g*64) * 64 + ic) * 9 + tap;   // + oc*576
    const float* bqp = bq + (size_t)(g*16 + o) * 64;
    const float* bsp = bs + (size_t)(g*16 + o) * 64;
    float sq = 0.f, sk = 0.f;
    for (int oc = 0; oc < 64; ++oc) {
      float wv = w2p[(size_t)oc * 576];
      sq = fmaf(bqp[oc], wv, sq);
      sk = fmaf(bsp[oc], wv, sk);
    }
    WfQ[idx] = sq;
    WfK[idx] = sk;
  }
}

// ---------------------------------------------------------------------------
__global__ __launch_bounds__(256) void bnstats_kernel(
    const float* __restrict__ catL, const float* __restrict__ catR,
    const float* __restrict__ gamma, const float* __restrict__ beta,
    float* __restrict__ ab) {
  int sc = blockIdx.x;          // 0..511
  int side = sc >> 8, c = sc & 255;
  const float* base = (side ? catR : catL) + (size_t)c * HW_;
  float s = 0.f, s2 = 0.f;
  for (int i = threadIdx.x; i < HW_; i += 256) {
    float v0 = base[i];
    float v1 = base[(size_t)C4_*HW_ + i];
    s  += v0 + v1;
    s2 += fmaf(v0, v0, v1*v1);
  }
  #pragma unroll
  for (int o = 32; o; o >>= 1) { s += __shfl_down(s, o); s2 += __shfl_down(s2, o); }
  __shared__ float rs[4], rs2[4];
  int wid = threadIdx.x >> 6;
  if ((threadIdx.x & 63) == 0) { rs[wid] = s; rs2[wid] = s2; }
  __syncthreads();
  if (threadIdx.x == 0) {
    float S  = rs[0]+rs[1]+rs[2]+rs[3];
    float S2 = rs2[0]+rs2[1]+rs2[2]+rs2[3];
    float inv_n = 1.f / (float)(2*HW_);
    float mu  = S * inv_n;
    float var = S2 * inv_n - mu*mu;
    float a = gamma[c] * rsqrtf(var + EPS_);
    ab[side*512 + c]       = a;
    ab[side*512 + 256 + c] = beta[c] - mu*a;
  }
}

// ---------------------------------------------------------------------------
// prep2: W2bQ/K bf16 [g][tap10][o][ic] (tap9 = residual bqa = projw*BNscale);
// bfQ/bfK[o] = proj_bias + sum_c projw*(b2_c + BNshift_c)
__global__ __launch_bounds__(256) void prep2_kernel(
    const float* __restrict__ bq, const float* __restrict__ bs,
    const float* __restrict__ bqb, const float* __restrict__ bsb,
    const float* __restrict__ b2, const float* __restrict__ ab,
    const float* __restrict__ WfQ, const float* __restrict__ WfK,
    unsigned short* __restrict__ W2bQ, unsigned short* __restrict__ W2bK,
    float* __restrict__ bfQ, float* __restrict__ bfK) {
  int idx = blockIdx.x*256 + threadIdx.x;
  if (idx < 40960) {
    int ic = idx & 63, o = (idx >> 6) & 15, tap = (idx >> 10) % 10, g = idx / 10240;
    float vq, vk;
    if (tap < 9) {
      int src = ((g*9 + tap)*16 + o)*64 + ic;
      vq = WfQ[src]; vk = WfK[src];
    } else {
      vq = bq[(size_t)(g*16 + o)*64 + ic] * ab[g*64 + ic];
      vk = bs[(size_t)(g*16 + o)*64 + ic] * ab[512 + g*64 + ic];
    }
    W2bQ[idx] = (unsigned short)f2bf1(vq);
    W2bK[idx] = (unsigned short)f2bf1(vk);
  }
  if (idx < 128) {
    int side = idx >> 6, co = idx & 63, g = co >> 4, o = co & 15;
    const float* w = side ? bs : bq;
    float s = (side ? bsb : bqb)[co];
    for (int c2 = 0; c2 < 64; ++c2) {
      int ch = g*64 + c2;
      s = fmaf(w[(size_t)(g*16 + o)*64 + c2], b2[ch] + ab[side*512 + 256 + ch], s);
    }
    (side ? bfK : bfQ)[co] = s;
  }
}

// ---------------------------------------------------------------------------
// conv1 MFMA: t1[b][g][h][w][oc64](bf16) = leaky(gconv3x3(bn(cat)) + b1)
__global__ __launch_bounds__(256) void conv1_mfma(
    const float* __restrict__ cat, const float* __restrict__ ab,
    const unsigned short* __restrict__ Wb, const float* __restrict__ bias,
    unsigned short* __restrict__ t1) {
  const int b = blockIdx.z >> 2, g = blockIdx.z & 3;
  const int h0 = blockIdx.y * 2, w0 = blockIdx.x * 64;
  const int tid = threadIdx.x;
  const int lane = tid & 63, wv = tid >> 6;
  const int m0 = wv * 16;
  const int m = lane & 15, kg = lane >> 4;
  __shared__ short Xs[4*66*72];   // [r4][c66][icpad72] bf16, BN applied

  const float* catg = cat + ((size_t)b*C4_ + g*64) * HW_;
  for (int u = tid; u < 32*132; u += 256) {
    int icp = u / 132;            // ic pair
    int rc  = u - icp*132;
    int r   = rc / 33, cp = rc - r*33;
    int c   = cp * 2;
    int gh  = h0 - 1 + r;
    int gw  = w0 - 1 + c;
    float vA0 = 0.f, vA1 = 0.f, vB0 = 0.f, vB1 = 0.f;
    if (gh >= 0 && gh < H_) {
      const float* srcA = catg + (size_t)(2*icp)*HW_ + gh*W_;
      const float* srcB = srcA + HW_;
      const float2 a2 = *(const float2*)&ab[g*64 + 2*icp];
      const float2 s2 = *(const float2*)&ab[256 + g*64 + 2*icp];
      if (gw >= 0)       { vA0 = fmaf(a2.x, srcA[gw],   s2.x); vB0 = fmaf(a2.y, srcB[gw],   s2.y); }
      if (gw + 1 < W_)   { vA1 = fmaf(a2.x, srcA[gw+1], s2.x); vB1 = fmaf(a2.y, srcB[gw+1], s2.y); }
    }
    int base = (r*66 + c)*72 + 2*icp;
    *(unsigned*)&Xs[base]      = packbf(vA0, vB0);
    *(unsigned*)&Xs[base + 72] = packbf(vA1, vB1);
  }

  s16x8 afrag[18];
  #pragma unroll
  for (int s = 0; s < 18; ++s) {
    const int tap = s >> 1, ic0 = (s & 1)*32 + kg*8;
    afrag[s] = *(const s16x8*)&Wb[(((size_t)g*9 + tap)*64 + m0 + m)*64 + ic0];
  }
  __syncthreads();

  f32x4 acc[8] = {};
  #pragma unroll
  for (int s = 0; s < 18; ++s) {
    const int tap = s >> 1, dh = tap / 3, dw = tap - dh*3;
    const int ic0 = (s & 1)*32 + kg*8;
    #pragma unroll
    for (int t = 0; t < 8; ++t) {
      const int px = t*16 + m;
      const int r = px >> 6, wl = px & 63;
      const s16x8 bfrag = *(const s16x8*)&Xs[((r + dh)*66 + wl + dw)*72 + ic0];
      acc[t] = __builtin_amdgcn_mfma_f32_16x16x32_bf16(afrag[s], bfrag, acc[t], 0, 0, 0);
    }
  }

  const int ocq = m0 + kg*4;
  const float4 b4 = *(const float4*)&bias[g*64 + ocq];
  const float bb[4] = {b4.x, b4.y, b4.z, b4.w};
  #pragma unroll
  for (int t = 0; t < 8; ++t) {
    const int px = t*16 + m;
    const int h = h0 + (px >> 6), w = w0 + (px & 63);
    float v[4];
    #pragma unroll
    for (int r = 0; r < 4; ++r) {
      float x = acc[t][r] + bb[r];
      v[r] = (x >= 0.f) ? x : 0.1f * x;
    }
    const size_t base = ((((size_t)(b*4 + g)*H_ + h)*W_ + w) << 6) + ocq;
    uint2 pk; pk.x = packbf(v[0], v[1]); pk.y = packbf(v[2], v[3]);
    *(uint2*)&t1[base] = pk;
  }
}

// ---------------------------------------------------------------------------
// conv2 MFMA + folded 1x1 proj + residual-as-K: Q[b][c16g][h][w] f32
__global__ __launch_bounds__(256) void conv2_mfma(
    const unsigned short* __restrict__ t1, const float* __restrict__ cat,
    const float* __restrict__ ab, const unsigned short* __restrict__ W2b,
    const float* __restrict__ bf, float* __restrict__ qout) {
  const int b = blockIdx.z >> 2, g = blockIdx.z & 3;
  const int h0 = blockIdx.y * 2, w0 = blockIdx.x * 64;
  const int tid = threadIdx.x;
  const int lane = tid & 63, wv = tid >> 6;
  const int m = lane & 15, kg = lane >> 4;
  __shared__ short Ys[4*66*72];    // t1 tile [r][c][icpad]
  __shared__ short Rs[128*72];     // residual [px][icpad] = BNscale*cat

  const unsigned short* t1g = t1 + (((size_t)(b*4 + g)*H_) << 6) * W_;
  for (int u = tid; u < 264*8; u += 256) {
    int rc = u >> 3, j = u & 7;
    int r = rc / 66, c = rc - r*66;
    int gh = h0 - 1 + r, gw = w0 - 1 + c;
    s16x8 v = {};
    if (gh >= 0 && gh < H_ && gw >= 0 && gw < W_)
      v = *(const s16x8*)&t1g[(((size_t)gh*W_ + gw) << 6) + j*8];
    *(s16x8*)&Ys[(rc*72) + j*8] = v;
  }
  const float* catg = cat + ((size_t)b*C4_ + g*64) * HW_;
  for (int u = tid; u < 32*128; u += 256) {
    int icp = u >> 7, px = u & 127;
    int gh = h0 + (px >> 6), gw = w0 + (px & 63);
    const float2 a2 = *(const float2*)&ab[g*64 + 2*icp];
    float vA = a2.x * catg[(size_t)(2*icp)*HW_ + gh*W_ + gw];
    float vB = a2.y * catg[(size_t)(2*icp + 1)*HW_ + gh*W_ + gw];
    *(unsigned*)&Rs[px*72 + 2*icp] = packbf(vA, vB);
  }

  s16x8 afrag[20];
  #pragma unroll
  for (int s = 0; s < 20; ++s) {
    const int tap = (s < 18) ? (s >> 1) : 9;
    const int ic0 = (s < 18) ? ((s & 1)*32 + kg*8) : ((s - 18)*32 + kg*8);
    afrag[s] = *(const s16x8*)&W2b[(((size_t)g*10 + tap)*16 + m)*64 + ic0];
  }
  __syncthreads();

  f32x4 acc[2] = {};
  #pragma unroll
  for (int s = 0; s < 18; ++s) {
    const int tap = s >> 1, dh = tap / 3, dw = tap - dh*3;
    const int ic0 = (s & 1)*32 + kg*8;
    #pragma unroll
    for (int t = 0; t < 2; ++t) {
      const int px = (wv*2 + t)*16 + m;
      const int r = px >> 6, wl = px & 63;
      const s16x8 bfrag = *(const s16x8*)&Ys[((r + dh)*66 + wl + dw)*72 + ic0];
      acc[t] = __builtin_amdgcn_mfma_f32_16x16x32_bf16(afrag[s], bfrag, acc[t], 0, 0, 0);
    }
  }
  #pragma unroll
  for (int s = 18; s < 20; ++s) {
    const int ic0 = (s - 18)*32 + kg*8;
    #pragma unroll
    for (int t = 0; t < 2; ++t) {
      const int px = (wv*2 + t)*16 + m;
      const s16x8 bfrag = *(const s16x8*)&Rs[px*72 + ic0];
      acc[t] = __builtin_amdgcn_mfma_f32_16x16x32_bf16(afrag[s], bfrag, acc[t], 0, 0, 0);
    }
  }

  const int ocq = kg*4;
  const float4 q4 = *(const float4*)&bf[g*16 + ocq];
  const float qb[4] = {q4.x, q4.y, q4.z, q4.w};
  #pragma unroll
  for (int t = 0; t < 2; ++t) {
    const int px = (wv*2 + t)*16 + m;
    const int h = h0 + (px >> 6), w = w0 + (px & 63);
    #pragma unroll
    for (int r = 0; r < 4; ++r) {
      const int oc = g*16 + ocq + r;
      qout[((size_t)(b*64 + oc)*H_ + h)*W_ + w] = acc[t][r] + qb[r];
    }
  }
}

// ---------------------------------------------------------------------------
__global__ __launch_bounds__(64) void rowmean_kernel(float* __restrict__ q) {
  float* p = q + (size_t)blockIdx.x * W_;
  const int lane = threadIdx.x;
  float v[5]; float s = 0.f;
  #pragma unroll
  for (int k = 0; k < 5; ++k) { v[k] = p[lane + 64*k]; s += v[k]; }
  #pragma unroll
  for (int o = 32; o; o >>= 1) s += __shfl_xor(s, o);
  const float m = s * (1.f/320.f);
  #pragma unroll
  for (int k = 0; k < 5; ++k) p[lane + 64*k] = v[k] - m;
}

// ---------------------------------------------------------------------------
// stats: rsum/cspart of exp(S). No LDS atomics: shfl reductions + direct writes.
__global__ __launch_bounds__(256, 4) void stats_kernel(
    const float* __restrict__ Qp, const float* __restrict__ Kp,
    float* __restrict__ rsum, float* __restrict__ cspart) {
  const int ub = blockIdx.x, row = blockIdx.y;
  const int b = row / H_, h = row - b*H_;
  const int u0 = ub * 64;
  const int tid = threadIdx.x;
  const int ti = tid & 15, tj = tid >> 4;
  const int wv = tid >> 6, tjw = (tid >> 4) & 3;
  __shared__ float Qs[4096];     // [c][u] stride 64
  __shared__ float Ks[4352];     // [c][v] stride 68
  __shared__ float rsw[256];
  const size_t rowoff = (size_t)b*C0_*HW_ + (size_t)h*W_;

  for (int i = tid; i < 1024; i += 256) {
    const int c = i >> 4, k = i & 15;
    *(float4*)&Qs[(c << 6) + 4*k] = *(const float4*)&Qp[rowoff + (size_t)c*HW_ + u0 + 4*k];
  }
  float rp[4] = {};
  for (int vb = 0; vb < 5; ++vb) {
    __syncthreads();
    for (int i = tid; i < 1024; i += 256) {
      const int c = i >> 4, v4 = i & 15;
      *(float4*)&Ks[c*68 + 4*v4] = *(const float4*)&Kp[rowoff + (size_t)c*HW_ + vb*64 + 4*v4];
    }
    __syncthreads();
    float sacc[4][4] = {};
    #pragma unroll 4
    for (int c = 0; c < 64; ++c) {
      const float4 a4 = *(const float4*)&Qs[(c << 6) + 4*ti];
      const float4 b4 = *(const float4*)&Ks[c*68 + 4*tj];
      const float av[4] = {a4.x, a4.y, a4.z, a4.w};
      const float bv[4] = {b4.x, b4.y, b4.z, b4.w};
      #pragma unroll
      for (int i = 0; i < 4; ++i)
        #pragma unroll
        for (int j = 0; j < 4; ++j)
          sacc[i][j] = fmaf(av[i], bv[j], sacc[i][j]);
    }
    float cpj[4] = {};
    #pragma unroll
    for (int i = 0; i < 4; ++i)
      #pragma unroll
      for (int j = 0; j < 4; ++j) {
        float e = __expf(sacc[i][j]);
        rp[i] += e; cpj[j] += e;
      }
    // reduce cpj over ti (16 lanes, bits 0..3 of lane)
    #pragma unroll
    for (int j = 0; j < 4; ++j) {
      float v = cpj[j];
      v += __shfl_xor(v, 1); v += __shfl_xor(v, 2);
      v += __shfl_xor(v, 4); v += __shfl_xor(v, 8);
      cpj[j] = v;
    }
    if (ti == 0) {
      float4 c4; c4.x = cpj[0]; c4.y = cpj[1]; c4.z = cpj[2]; c4.w = cpj[3];
      *(float4*)&cspart[((size_t)row*5 + ub)*W_ + vb*64 + 4*tj] = c4;
    }
  }
  // reduce rp over tj: in-wave (tjw bits: lane bits 4,5), then cross-wave
  #pragma unroll
  for (int i = 0; i < 4; ++i) {
    float v = rp[i];
    v += __shfl_xor(v, 16); v += __shfl_xor(v, 32);
    rp[i] = v;
  }
  if (tjw == 0) {
    #pragma unroll
    for (int i = 0; i < 4; ++i) rsw[(wv << 6) + 4*ti + i] = rp[i];
  }
  __syncthreads();
  if (tid < 64)
    rsum[(size_t)row*W_ + u0 + tid] = rsw[tid] + rsw[64+tid] + rsw[128+tid] + rsw[192+tid];
}

__global__ __launch_bounds__(256) void csreduce_kernel(
    const float* __restrict__ csp, float* __restrict__ csum) {
  int idx = blockIdx.x*256 + threadIdx.x;
  if (idx >= (int)RS_SZ) return;
  int row = idx / W_, v = idx - row*W_;
  float s = 0.f;
  #pragma unroll
  for (int ub = 0; ub < 5; ++ub) s += csp[((size_t)row*5 + ub)*W_ + v];
  csum[idx] = s;
}

// ---------------------------------------------------------------------------
__device__ __forceinline__ int halo_u(int k, int u0) {
  if (k < 64) return u0 + k;
  return (k == 64) ? (u0-2) : (k == 65) ? (u0-1) : (k == 66) ? (u0+64) : (u0+65);
}

// Fused output kernel (one side). E stored swizzled (EADDR), no LDS atomics.
__global__ __launch_bounds__(256, 3) void attn_kernel(
    const float* __restrict__ Qp, const float* __restrict__ Kp,
    const float* __restrict__ rsump, const float* __restrict__ csump,
    const float* __restrict__ xmul, const float* __restrict__ xblend,
    float* __restrict__ outp) {
  const int ub = blockIdx.x;        // 0..4
  const int row = blockIdx.y;       // 0..319
  const int b = row / H_, h = row - b*H_;
  const int u0 = ub * 64;
  const int tid = threadIdx.x;
  const int ti = tid & 15, tj = tid >> 4;
  const int wv = tid >> 6, tjw = (tid >> 4) & 3;

  __shared__ float Qs[4096];    // Q core [c][u] stride 64
  __shared__ float KE[4352];    // phase A: Ks[c][v] stride 68; phase B: E swizzled
  __shared__ float Xs2[4096];   // x [c][v] stride 64 (broadcast reads only)
  __shared__ float rinv[68];
  __shared__ float Qh[256];     // halo Q rows [hi][c]
  __shared__ float Vw[256];
  __shared__ float Vt[64];

  const size_t rowoff = (size_t)b*C0_*HW_ + (size_t)h*W_;
  const float* rsrow = rsump + (size_t)row*W_;
  const float* csrow = csump + (size_t)row*W_;

  if (tid < 68) {
    const int u = halo_u(tid, u0);
    rinv[tid] = (u >= 0 && u < W_) ? (1.f / rsrow[u]) : 0.f;
  }
  {
    const int hi = tid >> 6, c = tid & 63;
    const int u = halo_u(64 + hi, u0);
    Qh[(hi << 6) + c] = (u >= 0 && u < W_) ? Qp[rowoff + (size_t)c*HW_ + u] : 0.f;
  }
  for (int i = tid; i < 1024; i += 256) {
    const int c = i >> 4, k = i & 15;
    *(float4*)&Qs[(c << 6) + 4*k] = *(const float4*)&Qp[rowoff + (size_t)c*HW_ + u0 + 4*k];
  }

  float acc[4][4] = {};
  float vp[4] = {};

  for (int vb = 0; vb < 5; ++vb) {
    const int v0 = vb * 64;
    __syncthreads();
    for (int i = tid; i < 1024; i += 256) {
      const int c = i >> 4, v4 = i & 15;
      *(float4*)&KE[c*68 + 4*v4] = *(const float4*)&Kp[rowoff + (size_t)c*HW_ + v0 + 4*v4];
    }
    for (int i = tid; i < 1024; i += 256) {
      const int c = i >> 4, v4 = i & 15;
      *(float4*)&Xs2[(c << 6) + 4*v4] = *(const float4*)&xmul[rowoff + (size_t)c*HW_ + v0 + 4*v4];
    }
    __syncthreads();

    // S core: u = u0+4ti+i, v = v0+4tj+j
    float sacc[4][4] = {};
    #pragma unroll 4
    for (int c = 0; c < 64; ++c) {
      const float4 a4 = *(const float4*)&Qs[(c << 6) + 4*ti];
      const float4 b4 = *(const float4*)&KE[c*68 + 4*tj];
      const float av[4] = {a4.x, a4.y, a4.z, a4.w};
      const float bv[4] = {b4.x, b4.y, b4.z, b4.w};
      #pragma unroll
      for (int i = 0; i < 4; ++i)
        #pragma unroll
        for (int j = 0; j < 4; ++j)
          sacc[i][j] = fmaf(av[i], bv[j], sacc[i][j]);
    }
    // halo S: wave wv handles halo row wv, lane = v
    float sh = 0.f;
    const int hv = tid & 63;
    #pragma unroll 8
    for (int c = 0; c < 64; ++c)
      sh = fmaf(Qh[(wv << 6) + c], KE[c*68 + hv], sh);
    __syncthreads();

    // E writes (swizzled, vectorized core + scalar halo)
    #pragma unroll
    for (int i = 0; i < 4; ++i) {
      float4 e4;
      e4.x = __expf(sacc[i][0]); e4.y = __expf(sacc[i][1]);
      e4.z = __expf(sacc[i][2]); e4.w = __expf(sacc[i][3]);
      *(float4*)&KE[EADDR(4*ti + i, tj)] = e4;
    }
    {
      const int r = 64 + wv;
      const int u = halo_u(r, u0);
      const float ev = (u >= 0 && u < W_) ? __expf(sh) : 0.f;
      KE[(r << 6) + (((hv >> 2) ^ ((r >> 2) & 15)) << 2) + (hv & 3)] = ev;
    }
    __syncthreads();

    // xT: acc[i][j] += sum_v E[u_i][v] * x[c_j][v]
    #pragma unroll 2
    for (int v4 = 0; v4 < 16; ++v4) {
      float4 e4[4], xr[4];
      #pragma unroll
      for (int i = 0; i < 4; ++i) e4[i] = *(const float4*)&KE[EADDR(4*ti + i, v4)];
      #pragma unroll
      for (int j = 0; j < 4; ++j) xr[j] = *(const float4*)&Xs2[((4*tj + j) << 6) + 4*v4];
      #pragma unroll
      for (int i = 0; i < 4; ++i)
        #pragma unroll
        for (int j = 0; j < 4; ++j) {
          acc[i][j] = fmaf(e4[i].x, xr[j].x, acc[i][j]);
          acc[i][j] = fmaf(e4[i].y, xr[j].y, acc[i][j]);
          acc[i][j] = fmaf(e4[i].z, xr[j].z, acc[i][j]);
          acc[i][j] = fmaf(e4[i].w, xr[j].w, acc[i][j]);
        }
    }

    // banded V (register accumulation, float4 along v)
    const float4 cs4 = *(const float4*)&csrow[v0 + 4*tj];
    const float ci[4] = {1.f/cs4.x, 1.f/cs4.y, 1.f/cs4.z, 1.f/cs4.w};
    #pragma unroll
    for (int i2 = 0; i2 < 4; ++i2) {
      const int icore = 4*ti + i2;
      float4 pr = {0.f, 0.f, 0.f, 0.f};
      #pragma unroll
      for (int d = -2; d <= 2; ++d) {
        const int r = icore + d;
        const int rr = (r < 0) ? (66 + r) : ((r > 63) ? (r + 2) : r);
        const float4 ed = *(const float4*)&KE[EADDR(rr, tj)];
        const float rv = rinv[rr];
        pr.x = fmaf(ed.x, rv, pr.x);
        pr.y = fmaf(ed.y, rv, pr.y);
        pr.z = fmaf(ed.z, rv, pr.z);
        pr.w = fmaf(ed.w, rv, pr.w);
      }
      const float4 ei = *(const float4*)&KE[EADDR(icore, tj)];
      vp[i2] = fmaf(ei.x * ci[0], pr.x, vp[i2]);
      vp[i2] = fmaf(ei.y * ci[1], pr.y, vp[i2]);
      vp[i2] = fmaf(ei.z * ci[2], pr.z, vp[i2]);
      vp[i2] = fmaf(ei.w * ci[3], pr.w, vp[i2]);
    }
  }

  // V reduce: sum over tj (in-wave shfl over lane bits 4,5; cross-wave via Vw)
  #pragma unroll
  for (int i2 = 0; i2 < 4; ++i2) {
    float v = vp[i2];
    v += __shfl_xor(v, 16); v += __shfl_xor(v, 32);
    vp[i2] = v;
  }
  if (tjw == 0) {
    #pragma unroll
    for (int i2 = 0; i2 < 4; ++i2) Vw[(wv << 6) + 4*ti + i2] = vp[i2];
  }
  __syncthreads();
  if (tid < 64)
    Vt[tid] = tanhf(5.f * (Vw[tid] + Vw[64+tid] + Vw[128+tid] + Vw[192+tid]));
  __syncthreads();

  float tv[4], rv[4];
  #pragma unroll
  for (int i = 0; i < 4; ++i) { tv[i] = Vt[4*ti + i]; rv[i] = rinv[4*ti + i]; }
  #pragma unroll
  for (int j = 0; j < 4; ++j) {
    const int c = 4*tj + j;
    const size_t base = rowoff + (size_t)c*HW_ + u0 + 4*ti;
    const float4 xb4 = *(const float4*)&xblend[base];
    float4 o4;
    o4.x = xb4.x * (1.f - tv[0]) + acc[0][j]*rv[0]*tv[0];
    o4.y = xb4.y * (1.f - tv[1]) + acc[1][j]*rv[1]*tv[1];
    o4.z = xb4.z * (1.f - tv[2]) + acc[2][j]*rv[2]*tv[2];
    o4.w = xb4.w * (1.f - tv[3]) + acc[3][j]*rv[3]*tv[3];
    *(float4*)&outp[base] = o4;
  }
}

// ---------------------------------------------------------------------------
extern "C" void kernel_launch(void* const* d_in, const int* in_sizes, int n_in,
                              void* d_out, int out_size, void* d_ws, size_t ws_size,
                              hipStream_t stream) {
  const float* x_left  = (const float*)d_in[0];
  const float* x_right = (const float*)d_in[1];
  const float* catL    = (const float*)d_in[2];
  const float* catR    = (const float*)d_in[3];
  const float* bq_w    = (const float*)d_in[4];
  const float* bq_b    = (const float*)d_in[5];
  const float* bs_w    = (const float*)d_in[6];
  const float* bs_b    = (const float*)d_in[7];
  const float* rb_w1   = (const float*)d_in[8];
  const float* rb_b1   = (const float*)d_in[9];
  const float* rb_w2   = (const float*)d_in[10];
  const float* rb_b2   = (const float*)d_in[11];
  const float* gamma   = (const float*)d_in[12];
  const float* beta    = (const float*)d_in[13];

  float* ws = (float*)d_ws;
  size_t off = 0;
  float* WfQ = ws + off; off += WFQ_SZ;
  float* WfK = ws + off; off += WFQ_SZ;
  unsigned short* Wb   = (unsigned short*)(ws + off); off += WB_SZ;
  unsigned short* W2bQ = (unsigned short*)(ws + off); off += W2B_SZ;
  unsigned short* W2bK = (unsigned short*)(ws + off); off += W2B_SZ;
  float* ab  = ws + off; off += AB_SZ;
  float* bfQ = ws + off; off += BF_SZ;
  float* bfK = ws + off; off += BF_SZ;
  unsigned short* t1 = (unsigned short*)(ws + off); off += T1_SZ;
  float* Qb  = ws + off; off += QK_SZ;
  float* Kb  = ws + off; off += QK_SZ;
  float* rsb = ws + off; off += RS_SZ;
  float* csb = ws + off; off += RS_SZ;
  float* csp = ws + off; off += CSP_SZ;

  wtrans_kernel<<<576, 256, 0, stream>>>(rb_w1, rb_w2, bq_w, bs_w, Wb, WfQ, WfK);
  bnstats_kernel<<<512, 256, 0, stream>>>(catL, catR, gamma, beta, ab);
  prep2_kernel<<<160, 256, 0, stream>>>(bq_w, bs_w, bq_b, bs_b, rb_b2, ab,
                                        WfQ, WfK, W2bQ, W2bK, bfQ, bfK);

  dim3 cgrid(5, 80, 8);
  // left -> Q
  conv1_mfma<<<cgrid, 256, 0, stream>>>(catL, ab, Wb, rb_b1, t1);
  conv2_mfma<<<cgrid, 256, 0, stream>>>(t1, catL, ab, W2bQ, bfQ, Qb);
  // right -> K
  conv1_mfma<<<cgrid, 256, 0, stream>>>(catR, ab + 512, Wb, rb_b1, t1);
  conv2_mfma<<<cgrid, 256, 0, stream>>>(t1, catR, ab + 512, W2bK, bfK, Kb);

  rowmean_kernel<<<B_*C0_*H_, 64, 0, stream>>>(Qb);
  rowmean_kernel<<<B_*C0_*H_, 64, 0, stream>>>(Kb);

  stats_kernel<<<dim3(5, NROWS_), 256, 0, stream>>>(Qb, Kb, rsb, csp);
  csreduce_kernel<<<(int)((RS_SZ + 255)/256), 256, 0, stream>>>(csp, csb);

  float* outL = (float*)d_out;
  float* outR = outL + QK_SZ;
  attn_kernel<<<dim3(5, NROWS_), 256, 0, stream>>>(Qb, Kb, rsb, csb, x_right, x_left, outL);
  attn_kernel<<<dim3(5, NROWS_), 256, 0, stream>>>(Kb, Qb, csb, rsb, x_left, x_right, outR);
}

// Round 6
// 813.368 us; speedup vs baseline: 6.6410x; 1.2210x over previous
//
#include <hip/hip_runtime.h>

#define B_    2
#define C0_   64
#define C4_   256
#define H_    160
#define W_    320
#define G_    4
#define HW_   (H_*W_)
#define NROWS_ (B_*H_)      // 320
#define EPS_  1e-5f

typedef float f32x4 __attribute__((ext_vector_type(4)));
typedef short s16x8 __attribute__((ext_vector_type(8)));
typedef _Float16 h16x8 __attribute__((ext_vector_type(8)));
typedef _Float16 h16x4 __attribute__((ext_vector_type(4)));

// workspace sizes (in floats)
#define WFQ_SZ  36864       // f32 [g][tap9][o16][ic64]
#define WB_SZ   73728       // bf16 conv1 weights (147456 shorts)
#define W2B_SZ  20480       // bf16 fused conv2 weights (40960 shorts)
#define AB_SZ   1024
#define BF_SZ   64
#define T1_SZ   13107200    // bf16 t1 [b][g][h][w][ic64]
#define QK_SZ   ((size_t)B_*C0_*HW_)   // 6553600
#define RS_SZ   ((size_t)NROWS_*W_)    // 102400
#define CSP_SZ  ((size_t)NROWS_*5*W_)  // 512000

__device__ __forceinline__ unsigned f2bf1(float x) {
  unsigned u = __float_as_uint(x);
  return (u + 0x7FFFu + ((u >> 16) & 1u)) >> 16;
}
__device__ __forceinline__ unsigned packbf(float lo, float hi) {
  return f2bf1(lo) | (f2bf1(hi) << 16);
}
// swizzled short-index into a [row][64] 2B plane: XOR 16B-chunk by (row&7)
__device__ __forceinline__ int psw(int r, int c) {
  return (r << 6) + (((c >> 3) ^ (r & 7)) << 3) + (c & 7);
}

// ---------------------------------------------------------------------------
// wtrans: Wb bf16 [g][tap][oc][ic]; WfQ/WfK f32 [g][tap][o16][ic] (proj-folded)
__global__ __launch_bounds__(256) void wtrans_kernel(
    const float* __restrict__ w1, const float* __restrict__ w2,
    const float* __restrict__ bq, const float* __restrict__ bs,
    unsigned short* __restrict__ Wb, float* __restrict__ WfQ, float* __restrict__ WfK) {
  int idx = blockIdx.x * 256 + threadIdx.x;
  if (idx < 147456) {
    int ic = idx & 63, oc = (idx >> 6) & 63, tap = (idx >> 12) % 9, g = idx / 36864;
    float v = w1[((size_t)(g*64 + oc) * 64 + ic) * 9 + tap];
    Wb[idx] = (unsigned short)f2bf1(v);
  }
  if (idx < 36864) {
    int ic = idx & 63, o = (idx >> 6) & 15, tap = (idx >> 10) % 9, g = idx / 9216;
    const float* w2p = w2 + ((size_t)(g*64) * 64 + ic) * 9 + tap;   // + oc*576
    const float* bqp = bq + (size_t)(g*16 + o) * 64;
    const float* bsp = bs + (size_t)(g*16 + o) * 64;
    float sq = 0.f, sk = 0.f;
    for (int oc = 0; oc < 64; ++oc) {
      float wv = w2p[(size_t)oc * 576];
      sq = fmaf(bqp[oc], wv, sq);
      sk = fmaf(bsp[oc], wv, sk);
    }
    WfQ[idx] = sq;
    WfK[idx] = sk;
  }
}

// ---------------------------------------------------------------------------
__global__ __launch_bounds__(256) void bnstats_kernel(
    const float* __restrict__ catL, const float* __restrict__ catR,
    const float* __restrict__ gamma, const float* __restrict__ beta,
    float* __restrict__ ab) {
  int sc = blockIdx.x;          // 0..511
  int side = sc >> 8, c = sc & 255;
  const float* base = (side ? catR : catL) + (size_t)c * HW_;
  float s = 0.f, s2 = 0.f;
  for (int i = threadIdx.x; i < HW_; i += 256) {
    float v0 = base[i];
    float v1 = base[(size_t)C4_*HW_ + i];
    s  += v0 + v1;
    s2 += fmaf(v0, v0, v1*v1);
  }
  #pragma unroll
  for (int o = 32; o; o >>= 1) { s += __shfl_down(s, o); s2 += __shfl_down(s2, o); }
  __shared__ float rs[4], rs2[4];
  int wid = threadIdx.x >> 6;
  if ((threadIdx.x & 63) == 0) { rs[wid] = s; rs2[wid] = s2; }
  __syncthreads();
  if (threadIdx.x == 0) {
    float S  = rs[0]+rs[1]+rs[2]+rs[3];
    float S2 = rs2[0]+rs2[1]+rs2[2]+rs2[3];
    float inv_n = 1.f / (float)(2*HW_);
    float mu  = S * inv_n;
    float var = S2 * inv_n - mu*mu;
    float a = gamma[c] * rsqrtf(var + EPS_);
    ab[side*512 + c]       = a;
    ab[side*512 + 256 + c] = beta[c] - mu*a;
  }
}

// ---------------------------------------------------------------------------
__global__ __launch_bounds__(256) void prep2_kernel(
    const float* __restrict__ bq, const float* __restrict__ bs,
    const float* __restrict__ bqb, const float* __restrict__ bsb,
    const float* __restrict__ b2, const float* __restrict__ ab,
    const float* __restrict__ WfQ, const float* __restrict__ WfK,
    unsigned short* __restrict__ W2bQ, unsigned short* __restrict__ W2bK,
    float* __restrict__ bfQ, float* __restrict__ bfK) {
  int idx = blockIdx.x*256 + threadIdx.x;
  if (idx < 40960) {
    int ic = idx & 63, o = (idx >> 6) & 15, tap = (idx >> 10) % 10, g = idx / 10240;
    float vq, vk;
    if (tap < 9) {
      int src = ((g*9 + tap)*16 + o)*64 + ic;
      vq = WfQ[src]; vk = WfK[src];
    } else {
      vq = bq[(size_t)(g*16 + o)*64 + ic] * ab[g*64 + ic];
      vk = bs[(size_t)(g*16 + o)*64 + ic] * ab[512 + g*64 + ic];
    }
    W2bQ[idx] = (unsigned short)f2bf1(vq);
    W2bK[idx] = (unsigned short)f2bf1(vk);
  }
  if (idx < 128) {
    int side = idx >> 6, co = idx & 63, g = co >> 4, o = co & 15;
    const float* w = side ? bs : bq;
    float s = (side ? bsb : bqb)[co];
    for (int c2 = 0; c2 < 64; ++c2) {
      int ch = g*64 + c2;
      s = fmaf(w[(size_t)(g*16 + o)*64 + c2], b2[ch] + ab[side*512 + 256 + ch], s);
    }
    (side ? bfK : bfQ)[co] = s;
  }
}

// ---------------------------------------------------------------------------
// conv1 MFMA: t1[b][g][h][w][oc64](bf16) = leaky(gconv3x3(bn(cat)) + b1)
__global__ __launch_bounds__(256) void conv1_mfma(
    const float* __restrict__ cat, const float* __restrict__ ab,
    const unsigned short* __restrict__ Wb, const float* __restrict__ bias,
    unsigned short* __restrict__ t1) {
  const int b = blockIdx.z >> 2, g = blockIdx.z & 3;
  const int h0 = blockIdx.y * 2, w0 = blockIdx.x * 64;
  const int tid = threadIdx.x;
  const int lane = tid & 63, wv = tid >> 6;
  const int m0 = wv * 16;
  const int m = lane & 15, kg = lane >> 4;
  __shared__ short Xs[4*66*72];   // [r4][c66][icpad72] bf16, BN applied

  const float* catg = cat + ((size_t)b*C4_ + g*64) * HW_;
  for (int u = tid; u < 32*132; u += 256) {
    int icp = u / 132;            // ic pair
    int rc  = u - icp*132;
    int r   = rc / 33, cp = rc - r*33;
    int c   = cp * 2;
    int gh  = h0 - 1 + r;
    int gw  = w0 - 1 + c;
    float vA0 = 0.f, vA1 = 0.f, vB0 = 0.f, vB1 = 0.f;
    if (gh >= 0 && gh < H_) {
      const float* srcA = catg + (size_t)(2*icp)*HW_ + gh*W_;
      const float* srcB = srcA + HW_;
      const float2 a2 = *(const float2*)&ab[g*64 + 2*icp];
      const float2 s2 = *(const float2*)&ab[256 + g*64 + 2*icp];
      if (gw >= 0)       { vA0 = fmaf(a2.x, srcA[gw],   s2.x); vB0 = fmaf(a2.y, srcB[gw],   s2.y); }
      if (gw + 1 < W_)   { vA1 = fmaf(a2.x, srcA[gw+1], s2.x); vB1 = fmaf(a2.y, srcB[gw+1], s2.y); }
    }
    int base = (r*66 + c)*72 + 2*icp;
    *(unsigned*)&Xs[base]      = packbf(vA0, vB0);
    *(unsigned*)&Xs[base + 72] = packbf(vA1, vB1);
  }

  s16x8 afrag[18];
  #pragma unroll
  for (int s = 0; s < 18; ++s) {
    const int tap = s >> 1, ic0 = (s & 1)*32 + kg*8;
    afrag[s] = *(const s16x8*)&Wb[(((size_t)g*9 + tap)*64 + m0 + m)*64 + ic0];
  }
  __syncthreads();

  f32x4 acc[8] = {};
  #pragma unroll
  for (int s = 0; s < 18; ++s) {
    const int tap = s >> 1, dh = tap / 3, dw = tap - dh*3;
    const int ic0 = (s & 1)*32 + kg*8;
    #pragma unroll
    for (int t = 0; t < 8; ++t) {
      const int px = t*16 + m;
      const int r = px >> 6, wl = px & 63;
      const s16x8 bfrag = *(const s16x8*)&Xs[((r + dh)*66 + wl + dw)*72 + ic0];
      acc[t] = __builtin_amdgcn_mfma_f32_16x16x32_bf16(afrag[s], bfrag, acc[t], 0, 0, 0);
    }
  }

  const int ocq = m0 + kg*4;
  const float4 b4 = *(const float4*)&bias[g*64 + ocq];
  const float bb[4] = {b4.x, b4.y, b4.z, b4.w};
  #pragma unroll
  for (int t = 0; t < 8; ++t) {
    const int px = t*16 + m;
    const int h = h0 + (px >> 6), w = w0 + (px & 63);
    float v[4];
    #pragma unroll
    for (int r = 0; r < 4; ++r) {
      float x = acc[t][r] + bb[r];
      v[r] = (x >= 0.f) ? x : 0.1f * x;
    }
    const size_t base = ((((size_t)(b*4 + g)*H_ + h)*W_ + w) << 6) + ocq;
    uint2 pk; pk.x = packbf(v[0], v[1]); pk.y = packbf(v[2], v[3]);
    *(uint2*)&t1[base] = pk;
  }
}

// ---------------------------------------------------------------------------
// conv2 MFMA + folded 1x1 proj + residual-as-K: Q[b][c16g][h][w] f32
__global__ __launch_bounds__(256) void conv2_mfma(
    const unsigned short* __restrict__ t1, const float* __restrict__ cat,
    const float* __restrict__ ab, const unsigned short* __restrict__ W2b,
    const float* __restrict__ bf, float* __restrict__ qout) {
  const int b = blockIdx.z >> 2, g = blockIdx.z & 3;
  const int h0 = blockIdx.y * 2, w0 = blockIdx.x * 64;
  const int tid = threadIdx.x;
  const int lane = tid & 63, wv = tid >> 6;
  const int m = lane & 15, kg = lane >> 4;
  __shared__ short Ys[4*66*72];    // t1 tile [r][c][icpad]
  __shared__ short Rs[128*72];     // residual [px][icpad] = BNscale*cat

  const unsigned short* t1g = t1 + (((size_t)(b*4 + g)*H_) << 6) * W_;
  for (int u = tid; u < 264*8; u += 256) {
    int rc = u >> 3, j = u & 7;
    int r = rc / 66, c = rc - r*66;
    int gh = h0 - 1 + r, gw = w0 - 1 + c;
    s16x8 v = {};
    if (gh >= 0 && gh < H_ && gw >= 0 && gw < W_)
      v = *(const s16x8*)&t1g[(((size_t)gh*W_ + gw) << 6) + j*8];
    *(s16x8*)&Ys[(rc*72) + j*8] = v;
  }
  const float* catg = cat + ((size_t)b*C4_ + g*64) * HW_;
  for (int u = tid; u < 32*128; u += 256) {
    int icp = u >> 7, px = u & 127;
    int gh = h0 + (px >> 6), gw = w0 + (px & 63);
    const float2 a2 = *(const float2*)&ab[g*64 + 2*icp];
    float vA = a2.x * catg[(size_t)(2*icp)*HW_ + gh*W_ + gw];
    float vB = a2.y * catg[(size_t)(2*icp + 1)*HW_ + gh*W_ + gw];
    *(unsigned*)&Rs[px*72 + 2*icp] = packbf(vA, vB);
  }

  s16x8 afrag[20];
  #pragma unroll
  for (int s = 0; s < 20; ++s) {
    const int tap = (s < 18) ? (s >> 1) : 9;
    const int ic0 = (s < 18) ? ((s & 1)*32 + kg*8) : ((s - 18)*32 + kg*8);
    afrag[s] = *(const s16x8*)&W2b[(((size_t)g*10 + tap)*16 + m)*64 + ic0];
  }
  __syncthreads();

  f32x4 acc[2] = {};
  #pragma unroll
  for (int s = 0; s < 18; ++s) {
    const int tap = s >> 1, dh = tap / 3, dw = tap - dh*3;
    const int ic0 = (s & 1)*32 + kg*8;
    #pragma unroll
    for (int t = 0; t < 2; ++t) {
      const int px = (wv*2 + t)*16 + m;
      const int r = px >> 6, wl = px & 63;
      const s16x8 bfrag = *(const s16x8*)&Ys[((r + dh)*66 + wl + dw)*72 + ic0];
      acc[t] = __builtin_amdgcn_mfma_f32_16x16x32_bf16(afrag[s], bfrag, acc[t], 0, 0, 0);
    }
  }
  #pragma unroll
  for (int s = 18; s < 20; ++s) {
    const int ic0 = (s - 18)*32 + kg*8;
    #pragma unroll
    for (int t = 0; t < 2; ++t) {
      const int px = (wv*2 + t)*16 + m;
      const s16x8 bfrag = *(const s16x8*)&Rs[px*72 + ic0];
      acc[t] = __builtin_amdgcn_mfma_f32_16x16x32_bf16(afrag[s], bfrag, acc[t], 0, 0, 0);
    }
  }

  const int ocq = kg*4;
  const float4 q4 = *(const float4*)&bf[g*16 + ocq];
  const float qb[4] = {q4.x, q4.y, q4.z, q4.w};
  #pragma unroll
  for (int t = 0; t < 2; ++t) {
    const int px = (wv*2 + t)*16 + m;
    const int h = h0 + (px >> 6), w = w0 + (px & 63);
    #pragma unroll
    for (int r = 0; r < 4; ++r) {
      const int oc = g*16 + ocq + r;
      qout[((size_t)(b*64 + oc)*H_ + h)*W_ + w] = acc[t][r] + qb[r];
    }
  }
}

// ---------------------------------------------------------------------------
__global__ __launch_bounds__(64) void rowmean_kernel(float* __restrict__ q) {
  float* p = q + (size_t)blockIdx.x * W_;
  const int lane = threadIdx.x;
  float v[5]; float s = 0.f;
  #pragma unroll
  for (int k = 0; k < 5; ++k) { v[k] = p[lane + 64*k]; s += v[k]; }
  #pragma unroll
  for (int o = 32; o; o >>= 1) s += __shfl_xor(s, o);
  const float m = s * (1.f/320.f);
  #pragma unroll
  for (int k = 0; k < 5; ++k) p[lane + 64*k] = v[k] - m;
}

// ---------------------------------------------------------------------------
// stats via split-bf16 MFMA: rsum + cspart of exp(S). S = KhiQhi+KloQhi+KhiQlo.
// D[m=v][n=u]: lane holds S[v = wv*16+l4*4+r][u = t*16+l15].
__global__ __launch_bounds__(256, 4) void stats_kernel(
    const float* __restrict__ Qp, const float* __restrict__ Kp,
    float* __restrict__ rsum, float* __restrict__ cspart) {
  const int ub = blockIdx.x, row = blockIdx.y;
  const int b = row / H_, h = row - b*H_;
  const int u0 = ub * 64;
  const int tid = threadIdx.x;
  const int lane = tid & 63, wv = tid >> 6;
  const int l15 = lane & 15, l4 = lane >> 4;
  __shared__ unsigned short QH[64*64], QL[64*64], KH[64*64], KL[64*64];
  __shared__ float rsw[256];
  const size_t rowoff = (size_t)b*C0_*HW_ + (size_t)h*W_;

  // stage Q transposed+split: [u][c] planes
  for (int i = tid; i < 1024; i += 256) {
    int uq = i >> 6, c = i & 63;
    float4 v4 = *(const float4*)&Qp[rowoff + (size_t)c*HW_ + u0 + 4*uq];
    float q[4] = {v4.x, v4.y, v4.z, v4.w};
    #pragma unroll
    for (int j = 0; j < 4; ++j) {
      int r = 4*uq + j;
      unsigned hh = f2bf1(q[j]);
      QH[psw(r, c)] = (unsigned short)hh;
      QL[psw(r, c)] = (unsigned short)f2bf1(q[j] - __uint_as_float(hh << 16));
    }
  }
  float rp[4] = {};
  for (int vb = 0; vb < 5; ++vb) {
    __syncthreads();
    for (int i = tid; i < 1024; i += 256) {
      int vq = i >> 6, c = i & 63;
      float4 v4 = *(const float4*)&Kp[rowoff + (size_t)c*HW_ + vb*64 + 4*vq];
      float k[4] = {v4.x, v4.y, v4.z, v4.w};
      #pragma unroll
      for (int j = 0; j < 4; ++j) {
        int r = 4*vq + j;
        unsigned hh = f2bf1(k[j]);
        KH[psw(r, c)] = (unsigned short)hh;
        KL[psw(r, c)] = (unsigned short)f2bf1(k[j] - __uint_as_float(hh << 16));
      }
    }
    __syncthreads();
    const int vr = (wv << 4) + l15;
    const s16x8 kh0 = *(const s16x8*)&KH[psw(vr, l4*8)];
    const s16x8 kh1 = *(const s16x8*)&KH[psw(vr, 32 + l4*8)];
    const s16x8 kl0 = *(const s16x8*)&KL[psw(vr, l4*8)];
    const s16x8 kl1 = *(const s16x8*)&KL[psw(vr, 32 + l4*8)];
    float cp[4] = {};
    #pragma unroll
    for (int t = 0; t < 4; ++t) {
      const int qrow = t*16 + l15;
      const s16x8 qh0 = *(const s16x8*)&QH[psw(qrow, l4*8)];
      const s16x8 qh1 = *(const s16x8*)&QH[psw(qrow, 32 + l4*8)];
      const s16x8 ql0 = *(const s16x8*)&QL[psw(qrow, l4*8)];
      const s16x8 ql1 = *(const s16x8*)&QL[psw(qrow, 32 + l4*8)];
      f32x4 s = {};
      s = __builtin_amdgcn_mfma_f32_16x16x32_bf16(kh0, qh0, s, 0, 0, 0);
      s = __builtin_amdgcn_mfma_f32_16x16x32_bf16(kh1, qh1, s, 0, 0, 0);
      s = __builtin_amdgcn_mfma_f32_16x16x32_bf16(kl0, qh0, s, 0, 0, 0);
      s = __builtin_amdgcn_mfma_f32_16x16x32_bf16(kl1, qh1, s, 0, 0, 0);
      s = __builtin_amdgcn_mfma_f32_16x16x32_bf16(kh0, ql0, s, 0, 0, 0);
      s = __builtin_amdgcn_mfma_f32_16x16x32_bf16(kh1, ql1, s, 0, 0, 0);
      float e0 = __expf(s[0]), e1 = __expf(s[1]), e2 = __expf(s[2]), e3 = __expf(s[3]);
      rp[t] += e0 + e1 + e2 + e3;
      cp[0] += e0; cp[1] += e1; cp[2] += e2; cp[3] += e3;
    }
    #pragma unroll
    for (int r = 0; r < 4; ++r) {
      float v = cp[r];
      v += __shfl_xor(v, 1); v += __shfl_xor(v, 2);
      v += __shfl_xor(v, 4); v += __shfl_xor(v, 8);
      cp[r] = v;
    }
    if (l15 == 0) {
      f32x4 cw = {cp[0], cp[1], cp[2], cp[3]};
      *(f32x4*)&cspart[((size_t)row*5 + ub)*W_ + vb*64 + (wv << 4) + (l4 << 2)] = cw;
    }
  }
  #pragma unroll
  for (int t = 0; t < 4; ++t) {
    float v = rp[t];
    v += __shfl_xor(v, 16); v += __shfl_xor(v, 32);
    rp[t] = v;
  }
  if (l4 == 0) {
    #pragma unroll
    for (int t = 0; t < 4; ++t) rsw[(wv << 6) + (t << 4) + l15] = rp[t];
  }
  __syncthreads();
  if (tid < 64)
    rsum[(size_t)row*W_ + u0 + tid] = rsw[tid] + rsw[64+tid] + rsw[128+tid] + rsw[192+tid];
}

__global__ __launch_bounds__(256) void csreduce_kernel(
    const float* __restrict__ csp, float* __restrict__ csum) {
  int idx = blockIdx.x*256 + threadIdx.x;
  if (idx >= (int)RS_SZ) return;
  int row = idx / W_, v = idx - row*W_;
  float s = 0.f;
  #pragma unroll
  for (int ub = 0; ub < 5; ++ub) s += csp[((size_t)row*5 + ub)*W_ + v];
  csum[idx] = s;
}

// ---------------------------------------------------------------------------
__device__ __forceinline__ int halo_u(int k, int u0) {
  if (k < 64) return u0 + k;
  return (k == 64) ? (u0-2) : (k == 65) ? (u0-1) : (k == 66) ? (u0+64) : (u0+65);
}

// attn: split-bf16 MFMA S -> P (fp16 plane + f32 regs) -> fp16 MFMA xT + banded V
__global__ __launch_bounds__(256, 3) void attn_kernel(
    const float* __restrict__ Qp, const float* __restrict__ Kp,
    const float* __restrict__ rsump, const float* __restrict__ csump,
    const float* __restrict__ xmul, const float* __restrict__ xblend,
    float* __restrict__ outp) {
  const int ub = blockIdx.x;        // 0..4
  const int row = blockIdx.y;       // 0..319
  const int b = row / H_, h = row - b*H_;
  const int u0 = ub * 64;
  const int tid = threadIdx.x;
  const int lane = tid & 63, wv = tid >> 6;
  const int l15 = lane & 15, l4 = lane >> 4;

  __shared__ unsigned short QH[68*64], QL[68*64];   // Q split [u 0..67][c]
  __shared__ unsigned short KH[64*64], KL[64*64];   // K split [v][c]
  __shared__ _Float16 Xh[64*64];                    // x fp16 [c][v]
  __shared__ _Float16 Ph[68*64];                    // P fp16 [u 0..67][v]
  __shared__ float rinv[80];                        // 68..79 = 0
  __shared__ float Vw[256], Vt[64];

  const size_t rowoff = (size_t)b*C0_*HW_ + (size_t)h*W_;
  const float* rsrow = rsump + (size_t)row*W_;
  const float* csrow = csump + (size_t)row*W_;

  if (tid < 80) rinv[tid] = 0.f;
  if (tid < 68) {
    const int u = halo_u(tid, u0);
    rinv[tid] = (u >= 0 && u < W_) ? (1.f / rsrow[u]) : 0.f;
  }
  // stage Q transposed+split (rows 0..63 core, 64..67 halo)
  for (int i = tid; i < 17*64; i += 256) {
    int uq = i >> 6, c = i & 63;
    float q[4];
    if (uq < 16) {
      float4 v4 = *(const float4*)&Qp[rowoff + (size_t)c*HW_ + u0 + 4*uq];
      q[0] = v4.x; q[1] = v4.y; q[2] = v4.z; q[3] = v4.w;
    } else {
      #pragma unroll
      for (int j = 0; j < 4; ++j) {
        int u = halo_u(64 + j, u0);
        q[j] = (u >= 0 && u < W_) ? Qp[rowoff + (size_t)c*HW_ + u] : 0.f;
      }
    }
    #pragma unroll
    for (int j = 0; j < 4; ++j) {
      int r = 4*uq + j;
      unsigned hh = f2bf1(q[j]);
      QH[psw(r, c)] = (unsigned short)hh;
      QL[psw(r, c)] = (unsigned short)f2bf1(q[j] - __uint_as_float(hh << 16));
    }
  }

  f32x4 xacc[4] = {};
  float vsum[4] = {};
  const int vq4 = (wv << 4) + (l4 << 2);   // this lane's v base (4 consecutive)

  for (int vb = 0; vb < 5; ++vb) {
    const int v0 = vb * 64;
    __syncthreads();
    // stage K split [v][c]
    for (int i = tid; i < 1024; i += 256) {
      int vq = i >> 6, c = i & 63;
      float4 v4 = *(const float4*)&Kp[rowoff + (size_t)c*HW_ + v0 + 4*vq];
      float k[4] = {v4.x, v4.y, v4.z, v4.w};
      #pragma unroll
      for (int j = 0; j < 4; ++j) {
        int r = 4*vq + j;
        unsigned hh = f2bf1(k[j]);
        KH[psw(r, c)] = (unsigned short)hh;
        KL[psw(r, c)] = (unsigned short)f2bf1(k[j] - __uint_as_float(hh << 16));
      }
    }
    // stage x fp16 [c][v]
    for (int i = tid; i < 1024; i += 256) {
      int c = i >> 4, vq = i & 15;
      float4 v4 = *(const float4*)&xmul[rowoff + (size_t)c*HW_ + v0 + 4*vq];
      h16x4 hx = {(_Float16)v4.x, (_Float16)v4.y, (_Float16)v4.z, (_Float16)v4.w};
      *(h16x4*)&Xh[psw(c, 4*vq)] = hx;
    }
    __syncthreads();

    // ---- S phase: A = K rows (m = v), B = Q rows (n = u)
    const int vr = (wv << 4) + l15;
    const s16x8 kh0 = *(const s16x8*)&KH[psw(vr, l4*8)];
    const s16x8 kh1 = *(const s16x8*)&KH[psw(vr, 32 + l4*8)];
    const s16x8 kl0 = *(const s16x8*)&KL[psw(vr, l4*8)];
    const s16x8 kl1 = *(const s16x8*)&KL[psw(vr, 32 + l4*8)];
    float P[5][4];
    #pragma unroll
    for (int t = 0; t < 5; ++t) {
      const int qrow = (t < 4) ? (t*16 + l15) : (64 + (l15 & 3));
      const s16x8 qh0 = *(const s16x8*)&QH[psw(qrow, l4*8)];
      const s16x8 qh1 = *(const s16x8*)&QH[psw(qrow, 32 + l4*8)];
      const s16x8 ql0 = *(const s16x8*)&QL[psw(qrow, l4*8)];
      const s16x8 ql1 = *(const s16x8*)&QL[psw(qrow, 32 + l4*8)];
      f32x4 s = {};
      s = __builtin_amdgcn_mfma_f32_16x16x32_bf16(kh0, qh0, s, 0, 0, 0);
      s = __builtin_amdgcn_mfma_f32_16x16x32_bf16(kh1, qh1, s, 0, 0, 0);
      s = __builtin_amdgcn_mfma_f32_16x16x32_bf16(kl0, qh0, s, 0, 0, 0);
      s = __builtin_amdgcn_mfma_f32_16x16x32_bf16(kl1, qh1, s, 0, 0, 0);
      s = __builtin_amdgcn_mfma_f32_16x16x32_bf16(kh0, ql0, s, 0, 0, 0);
      s = __builtin_amdgcn_mfma_f32_16x16x32_bf16(kh1, ql1, s, 0, 0, 0);
      const float ri = rinv[(t < 4) ? (t*16 + l15) : (64 + l15)];   // 0 for pad/OOB
      #pragma unroll
      for (int r = 0; r < 4; ++r) P[t][r] = __expf(s[r]) * ri;
    }
    // write P to fp16 plane: core rows + halo rows
    #pragma unroll
    for (int t = 0; t < 4; ++t) {
      h16x4 hp = {(_Float16)P[t][0], (_Float16)P[t][1], (_Float16)P[t][2], (_Float16)P[t][3]};
      *(h16x4*)&Ph[psw(t*16 + l15, vq4)] = hp;
    }
    if (l15 < 4) {
      h16x4 hp = {(_Float16)P[4][0], (_Float16)P[4][1], (_Float16)P[4][2], (_Float16)P[4][3]};
      *(h16x4*)&Ph[psw(64 + l15, vq4)] = hp;
    }
    __syncthreads();

    // ---- xT phase: A = P rows (m = u), B = x rows (n = c)
    {
      const int ur = (wv << 4) + l15;
      const h16x8 pa0 = *(const h16x8*)&Ph[psw(ur, l4*8)];
      const h16x8 pa1 = *(const h16x8*)&Ph[psw(ur, 32 + l4*8)];
      #pragma unroll
      for (int t = 0; t < 4; ++t) {
        const int crow = t*16 + l15;
        const h16x8 xb0 = *(const h16x8*)&Xh[psw(crow, l4*8)];
        const h16x8 xb1 = *(const h16x8*)&Xh[psw(crow, 32 + l4*8)];
        xacc[t] = __builtin_amdgcn_mfma_f32_16x16x32_f16(pa0, xb0, xacc[t], 0, 0, 0);
        xacc[t] = __builtin_amdgcn_mfma_f32_16x16x32_f16(pa1, xb1, xacc[t], 0, 0, 0);
      }
    }

    // ---- banded V: d=0 from f32 regs, d=+-1,+-2 neighbors from fp16 plane
    {
      const float4 cs4 = *(const float4*)&csrow[v0 + vq4];
      const float ci[4] = {1.f/cs4.x, 1.f/cs4.y, 1.f/cs4.z, 1.f/cs4.w};
      #pragma unroll
      for (int t = 0; t < 4; ++t) {
        float w[4] = {P[t][0], P[t][1], P[t][2], P[t][3]};
        #pragma unroll
        for (int d = -2; d <= 2; ++d) {
          if (d == 0) continue;
          const int q = t*16 + l15 + d;
          const int rr = (q < 0) ? (66 + q) : ((q > 63) ? (q + 2) : q);
          const h16x4 pn = *(const h16x4*)&Ph[psw(rr, vq4)];
          w[0] += (float)pn[0]; w[1] += (float)pn[1];
          w[2] += (float)pn[2]; w[3] += (float)pn[3];
        }
        #pragma unroll
        for (int r = 0; r < 4; ++r)
          vsum[t] = fmaf(P[t][r] * ci[r], w[r], vsum[t]);
      }
    }
  }

  // V reduce: over l4 (shfl bits 4,5), then across waves via LDS
  #pragma unroll
  for (int t = 0; t < 4; ++t) {
    float v = vsum[t];
    v += __shfl_xor(v, 16); v += __shfl_xor(v, 32);
    vsum[t] = v;
  }
  if (l4 == 0) {
    #pragma unroll
    for (int t = 0; t < 4; ++t) Vw[(wv << 6) + (t << 4) + l15] = vsum[t];
  }
  __syncthreads();
  if (tid < 64) {
    float v = Vw[tid] + Vw[64+tid] + Vw[128+tid] + Vw[192+tid];
    Vt[tid] = tanhf(5.f * v * rsrow[u0 + tid]);
  }
  __syncthreads();

  // epilogue: lane holds xT[u = wv*16 + l4*4 + r][c = t*16 + l15]
  const int ubu = (wv << 4) + (l4 << 2);
  float tv[4];
  #pragma unroll
  for (int r = 0; r < 4; ++r) tv[r] = Vt[ubu + r];
  #pragma unroll
  for (int t = 0; t < 4; ++t) {
    const int c = (t << 4) + l15;
    const size_t base = rowoff + (size_t)c*HW_ + u0 + ubu;
    const float4 xb4 = *(const float4*)&xblend[base];
    float4 o4;
    o4.x = xb4.x * (1.f - tv[0]) + xacc[t][0] * tv[0];
    o4.y = xb4.y * (1.f - tv[1]) + xacc[t][1] * tv[1];
    o4.z = xb4.z * (1.f - tv[2]) + xacc[t][2] * tv[2];
    o4.w = xb4.w * (1.f - tv[3]) + xacc[t][3] * tv[3];
    *(float4*)&outp[base] = o4;
  }
}

// ---------------------------------------------------------------------------
extern "C" void kernel_launch(void* const* d_in, const int* in_sizes, int n_in,
                              void* d_out, int out_size, void* d_ws, size_t ws_size,
                              hipStream_t stream) {
  const float* x_left  = (const float*)d_in[0];
  const float* x_right = (const float*)d_in[1];
  const float* catL    = (const float*)d_in[2];
  const float* catR    = (const float*)d_in[3];
  const float* bq_w    = (const float*)d_in[4];
  const float* bq_b    = (const float*)d_in[5];
  const float* bs_w    = (const float*)d_in[6];
  const float* bs_b    = (const float*)d_in[7];
  const float* rb_w1   = (const float*)d_in[8];
  const float* rb_b1   = (const float*)d_in[9];
  const float* rb_w2   = (const float*)d_in[10];
  const float* rb_b2   = (const float*)d_in[11];
  const float* gamma   = (const float*)d_in[12];
  const float* beta    = (const float*)d_in[13];

  float* ws = (float*)d_ws;
  size_t off = 0;
  float* WfQ = ws + off; off += WFQ_SZ;
  float* WfK = ws + off; off += WFQ_SZ;
  unsigned short* Wb   = (unsigned short*)(ws + off); off += WB_SZ;
  unsigned short* W2bQ = (unsigned short*)(ws + off); off += W2B_SZ;
  unsigned short* W2bK = (unsigned short*)(ws + off); off += W2B_SZ;
  float* ab  = ws + off; off += AB_SZ;
  float* bfQ = ws + off; off += BF_SZ;
  float* bfK = ws + off; off += BF_SZ;
  unsigned short* t1 = (unsigned short*)(ws + off); off += T1_SZ;
  float* Qb  = ws + off; off += QK_SZ;
  float* Kb  = ws + off; off += QK_SZ;
  float* rsb = ws + off; off += RS_SZ;
  float* csb = ws + off; off += RS_SZ;
  float* csp = ws + off; off += CSP_SZ;

  wtrans_kernel<<<576, 256, 0, stream>>>(rb_w1, rb_w2, bq_w, bs_w, Wb, WfQ, WfK);
  bnstats_kernel<<<512, 256, 0, stream>>>(catL, catR, gamma, beta, ab);
  prep2_kernel<<<160, 256, 0, stream>>>(bq_w, bs_w, bq_b, bs_b, rb_b2, ab,
                                        WfQ, WfK, W2bQ, W2bK, bfQ, bfK);

  dim3 cgrid(5, 80, 8);
  // left -> Q
  conv1_mfma<<<cgrid, 256, 0, stream>>>(catL, ab, Wb, rb_b1, t1);
  conv2_mfma<<<cgrid, 256, 0, stream>>>(t1, catL, ab, W2bQ, bfQ, Qb);
  // right -> K
  conv1_mfma<<<cgrid, 256, 0, stream>>>(catR, ab + 512, Wb, rb_b1, t1);
  conv2_mfma<<<cgrid, 256, 0, stream>>>(t1, catR, ab + 512, W2bK, bfK, Kb);

  rowmean_kernel<<<B_*C0_*H_, 64, 0, stream>>>(Qb);
  rowmean_kernel<<<B_*C0_*H_, 64, 0, stream>>>(Kb);

  stats_kernel<<<dim3(5, NROWS_), 256, 0, stream>>>(Qb, Kb, rsb, csp);
  csreduce_kernel<<<(int)((RS_SZ + 255)/256), 256, 0, stream>>>(csp, csb);

  float* outL = (float*)d_out;
  float* outR = outL + QK_SZ;
  attn_kernel<<<dim3(5, NROWS_), 256, 0, stream>>>(Qb, Kb, rsb, csb, x_right, x_left, outL);
  attn_kernel<<<dim3(5, NROWS_), 256, 0, stream>>>(Kb, Qb, csb, rsb, x_left, x_right, outR);
}

// Round 7
// 705.524 us; speedup vs baseline: 7.6562x; 1.1529x over previous
//
#include <hip/hip_runtime.h>

#define B_    2
#define C0_   64
#define C4_   256
#define H_    160
#define W_    320
#define G_    4
#define HW_   (H_*W_)
#define NROWS_ (B_*H_)      // 320
#define EPS_  1e-5f

typedef float f32x4 __attribute__((ext_vector_type(4)));
typedef short s16x8 __attribute__((ext_vector_type(8)));
typedef _Float16 h16x8 __attribute__((ext_vector_type(8)));
typedef _Float16 h16x4 __attribute__((ext_vector_type(4)));

// workspace sizes (in floats)
#define WFQ_SZ  36864       // f32 [g][tap9][o16][ic64]
#define WB_SZ   73728       // bf16 conv1 weights (147456 shorts)
#define W2B_SZ  20480       // bf16 fused conv2 weights (40960 shorts)
#define AB_SZ   1024
#define BF_SZ   64
#define T1_SZ   13107200    // bf16 t1 [b][g][h][w][ic64]
#define CATB_SZ 13107200    // bf16 catb, same layout (one side at a time)
#define QK_SZ   ((size_t)B_*C0_*HW_)   // 6553600
#define RS_SZ   ((size_t)NROWS_*W_)    // 102400
#define CSP_SZ  ((size_t)NROWS_*5*W_)  // 512000

__device__ __forceinline__ unsigned f2bf1(float x) {
  unsigned u = __float_as_uint(x);
  return (u + 0x7FFFu + ((u >> 16) & 1u)) >> 16;
}
__device__ __forceinline__ unsigned packbf(float lo, float hi) {
  return f2bf1(lo) | (f2bf1(hi) << 16);
}
// swizzled short-index into a [row][64] 2B plane: XOR 16B-chunk by (row&7)
__device__ __forceinline__ int psw(int r, int c) {
  return (r << 6) + (((c >> 3) ^ (r & 7)) << 3) + (c & 7);
}

// ---------------------------------------------------------------------------
// wtrans: Wb bf16 [g][tap][oc][ic]; WfQ/WfK f32 [g][tap][o16][ic] (proj-folded)
__global__ __launch_bounds__(256) void wtrans_kernel(
    const float* __restrict__ w1, const float* __restrict__ w2,
    const float* __restrict__ bq, const float* __restrict__ bs,
    unsigned short* __restrict__ Wb, float* __restrict__ WfQ, float* __restrict__ WfK) {
  int idx = blockIdx.x * 256 + threadIdx.x;
  if (idx < 147456) {
    int ic = idx & 63, oc = (idx >> 6) & 63, tap = (idx >> 12) % 9, g = idx / 36864;
    float v = w1[((size_t)(g*64 + oc) * 64 + ic) * 9 + tap];
    Wb[idx] = (unsigned short)f2bf1(v);
  }
  if (idx < 36864) {
    int ic = idx & 63, o = (idx >> 6) & 15, tap = (idx >> 10) % 9, g = idx / 9216;
    const float* w2p = w2 + ((size_t)(g*64) * 64 + ic) * 9 + tap;   // + oc*576
    const float* bqp = bq + (size_t)(g*16 + o) * 64;
    const float* bsp = bs + (size_t)(g*16 + o) * 64;
    float sq = 0.f, sk = 0.f;
    for (int oc = 0; oc < 64; ++oc) {
      float wv = w2p[(size_t)oc * 576];
      sq = fmaf(bqp[oc], wv, sq);
      sk = fmaf(bsp[oc], wv, sk);
    }
    WfQ[idx] = sq;
    WfK[idx] = sk;
  }
}

// ---------------------------------------------------------------------------
__global__ __launch_bounds__(256) void bnstats_kernel(
    const float* __restrict__ catL, const float* __restrict__ catR,
    const float* __restrict__ gamma, const float* __restrict__ beta,
    float* __restrict__ ab) {
  int sc = blockIdx.x;          // 0..511
  int side = sc >> 8, c = sc & 255;
  const float* base = (side ? catR : catL) + (size_t)c * HW_;
  float s = 0.f, s2 = 0.f;
  for (int i = threadIdx.x; i < HW_; i += 256) {
    float v0 = base[i];
    float v1 = base[(size_t)C4_*HW_ + i];
    s  += v0 + v1;
    s2 += fmaf(v0, v0, v1*v1);
  }
  #pragma unroll
  for (int o = 32; o; o >>= 1) { s += __shfl_down(s, o); s2 += __shfl_down(s2, o); }
  __shared__ float rs[4], rs2[4];
  int wid = threadIdx.x >> 6;
  if ((threadIdx.x & 63) == 0) { rs[wid] = s; rs2[wid] = s2; }
  __syncthreads();
  if (threadIdx.x == 0) {
    float S  = rs[0]+rs[1]+rs[2]+rs[3];
    float S2 = rs2[0]+rs2[1]+rs2[2]+rs2[3];
    float inv_n = 1.f / (float)(2*HW_);
    float mu  = S * inv_n;
    float var = S2 * inv_n - mu*mu;
    float a = gamma[c] * rsqrtf(var + EPS_);
    ab[side*512 + c]       = a;
    ab[side*512 + 256 + c] = beta[c] - mu*a;
  }
}

// ---------------------------------------------------------------------------
// bnapply: catb[b][g][px][ic64] = bf16( a*cat + shift ). One side per launch.
// z = b*4+g; x = px tile of 64. Thread: px = tid&63, ic block = (tid>>6)*16.
__global__ __launch_bounds__(256) void bnapply_kernel(
    const float* __restrict__ cat, const float* __restrict__ abs_,
    unsigned short* __restrict__ catb) {
  const int z = blockIdx.z;
  const int b = z >> 2, g = z & 3;
  const int tid = threadIdx.x;
  const int px = blockIdx.x * 64 + (tid & 63);
  const int ic0 = (tid >> 6) * 16;
  const float* src = cat + ((size_t)b*C4_ + g*64 + ic0) * HW_ + px;
  const float* abp = abs_ + g*64 + ic0;
  unsigned short* dst = catb + (((size_t)(b*4 + g)*HW_ + px) << 6) + ic0;
  unsigned pk[8];
  #pragma unroll
  for (int j = 0; j < 8; ++j) {
    const float2 a2 = *(const float2*)&abp[2*j];
    const float2 s2 = *(const float2*)&abp[256 + 2*j];
    float v0 = fmaf(a2.x, src[(size_t)(2*j)*HW_],   s2.x);
    float v1 = fmaf(a2.y, src[(size_t)(2*j+1)*HW_], s2.y);
    pk[j] = packbf(v0, v1);
  }
  *(uint4*)&dst[0] = *(uint4*)&pk[0];
  *(uint4*)&dst[8] = *(uint4*)&pk[4];
}

// ---------------------------------------------------------------------------
// prep2: W2bQ/K bf16 [g][tap10][o][ic] (tap9 = plain proj weight; residual data
// comes from catb which already carries full BN); bf[o] = proj_bias + sum_c w*b2_c
__global__ __launch_bounds__(256) void prep2_kernel(
    const float* __restrict__ bq, const float* __restrict__ bs,
    const float* __restrict__ bqb, const float* __restrict__ bsb,
    const float* __restrict__ b2,
    const float* __restrict__ WfQ, const float* __restrict__ WfK,
    unsigned short* __restrict__ W2bQ, unsigned short* __restrict__ W2bK,
    float* __restrict__ bfQ, float* __restrict__ bfK) {
  int idx = blockIdx.x*256 + threadIdx.x;
  if (idx < 40960) {
    int ic = idx & 63, o = (idx >> 6) & 15, tap = (idx >> 10) % 10, g = idx / 10240;
    float vq, vk;
    if (tap < 9) {
      int src = ((g*9 + tap)*16 + o)*64 + ic;
      vq = WfQ[src]; vk = WfK[src];
    } else {
      vq = bq[(size_t)(g*16 + o)*64 + ic];
      vk = bs[(size_t)(g*16 + o)*64 + ic];
    }
    W2bQ[idx] = (unsigned short)f2bf1(vq);
    W2bK[idx] = (unsigned short)f2bf1(vk);
  }
  if (idx < 128) {
    int side = idx >> 6, co = idx & 63, g = co >> 4, o = co & 15;
    const float* w = side ? bs : bq;
    float s = (side ? bsb : bqb)[co];
    for (int c2 = 0; c2 < 64; ++c2) {
      int ch = g*64 + c2;
      s = fmaf(w[(size_t)(g*16 + o)*64 + c2], b2[ch], s);
    }
    (side ? bfK : bfQ)[co] = s;
  }
}

// ---------------------------------------------------------------------------
// conv1 MFMA: t1[b][g][h][w][oc64](bf16) = leaky(gconv3x3(catb) + b1)
// staging is pure 16B copies from ic-contiguous catb.
__global__ __launch_bounds__(256) void conv1_mfma(
    const unsigned short* __restrict__ catb,
    const unsigned short* __restrict__ Wb, const float* __restrict__ bias,
    unsigned short* __restrict__ t1) {
  const int b = blockIdx.z >> 2, g = blockIdx.z & 3;
  const int h0 = blockIdx.y * 2, w0 = blockIdx.x * 64;
  const int tid = threadIdx.x;
  const int lane = tid & 63, wv = tid >> 6;
  const int m0 = wv * 16;
  const int m = lane & 15, kg = lane >> 4;
  __shared__ short Xs[4*66*72];   // [r4][c66][icpad72]

  const unsigned short* catbg = catb + (((size_t)(b*4 + g)*H_) << 6) * W_;
  for (int u = tid; u < 264*8; u += 256) {
    int rc = u >> 3, j = u & 7;
    int r = rc / 66, c = rc - r*66;
    int gh = h0 - 1 + r, gw = w0 - 1 + c;
    s16x8 v = {};
    if (gh >= 0 && gh < H_ && gw >= 0 && gw < W_)
      v = *(const s16x8*)&catbg[(((size_t)gh*W_ + gw) << 6) + j*8];
    *(s16x8*)&Xs[rc*72 + j*8] = v;
  }

  s16x8 afrag[18];
  #pragma unroll
  for (int s = 0; s < 18; ++s) {
    const int tap = s >> 1, ic0 = (s & 1)*32 + kg*8;
    afrag[s] = *(const s16x8*)&Wb[(((size_t)g*9 + tap)*64 + m0 + m)*64 + ic0];
  }
  __syncthreads();

  f32x4 acc[8] = {};
  #pragma unroll
  for (int s = 0; s < 18; ++s) {
    const int tap = s >> 1, dh = tap / 3, dw = tap - dh*3;
    const int ic0 = (s & 1)*32 + kg*8;
    #pragma unroll
    for (int t = 0; t < 8; ++t) {
      const int px = t*16 + m;
      const int r = px >> 6, wl = px & 63;
      const s16x8 bfrag = *(const s16x8*)&Xs[((r + dh)*66 + wl + dw)*72 + ic0];
      acc[t] = __builtin_amdgcn_mfma_f32_16x16x32_bf16(afrag[s], bfrag, acc[t], 0, 0, 0);
    }
  }

  const int ocq = m0 + kg*4;
  const float4 b4 = *(const float4*)&bias[g*64 + ocq];
  const float bb[4] = {b4.x, b4.y, b4.z, b4.w};
  #pragma unroll
  for (int t = 0; t < 8; ++t) {
    const int px = t*16 + m;
    const int h = h0 + (px >> 6), w = w0 + (px & 63);
    float v[4];
    #pragma unroll
    for (int r = 0; r < 4; ++r) {
      float x = acc[t][r] + bb[r];
      v[r] = (x >= 0.f) ? x : 0.1f * x;
    }
    const size_t base = ((((size_t)(b*4 + g)*H_ + h)*W_ + w) << 6) + ocq;
    uint2 pk; pk.x = packbf(v[0], v[1]); pk.y = packbf(v[2], v[3]);
    *(uint2*)&t1[base] = pk;
  }
}

// ---------------------------------------------------------------------------
// conv2 MFMA + folded 1x1 proj + residual-as-K (residual data = catb)
__global__ __launch_bounds__(256) void conv2_mfma(
    const unsigned short* __restrict__ t1, const unsigned short* __restrict__ catb,
    const unsigned short* __restrict__ W2b,
    const float* __restrict__ bf, float* __restrict__ qout) {
  const int b = blockIdx.z >> 2, g = blockIdx.z & 3;
  const int h0 = blockIdx.y * 2, w0 = blockIdx.x * 64;
  const int tid = threadIdx.x;
  const int lane = tid & 63, wv = tid >> 6;
  const int m = lane & 15, kg = lane >> 4;
  __shared__ short Ys[4*66*72];    // t1 tile [r][c][icpad]
  __shared__ short Rs[128*72];     // residual [px][icpad] = catb core tile

  const unsigned short* t1g = t1 + (((size_t)(b*4 + g)*H_) << 6) * W_;
  const unsigned short* catbg = catb + (((size_t)(b*4 + g)*H_) << 6) * W_;
  for (int u = tid; u < 264*8; u += 256) {
    int rc = u >> 3, j = u & 7;
    int r = rc / 66, c = rc - r*66;
    int gh = h0 - 1 + r, gw = w0 - 1 + c;
    s16x8 v = {};
    if (gh >= 0 && gh < H_ && gw >= 0 && gw < W_)
      v = *(const s16x8*)&t1g[(((size_t)gh*W_ + gw) << 6) + j*8];
    *(s16x8*)&Ys[(rc*72) + j*8] = v;
  }
  for (int u = tid; u < 128*8; u += 256) {
    int px = u >> 3, j = u & 7;
    int gh = h0 + (px >> 6), gw = w0 + (px & 63);
    *(s16x8*)&Rs[px*72 + j*8] =
        *(const s16x8*)&catbg[(((size_t)gh*W_ + gw) << 6) + j*8];
  }

  s16x8 afrag[20];
  #pragma unroll
  for (int s = 0; s < 20; ++s) {
    const int tap = (s < 18) ? (s >> 1) : 9;
    const int ic0 = (s < 18) ? ((s & 1)*32 + kg*8) : ((s - 18)*32 + kg*8);
    afrag[s] = *(const s16x8*)&W2b[(((size_t)g*10 + tap)*16 + m)*64 + ic0];
  }
  __syncthreads();

  f32x4 acc[2] = {};
  #pragma unroll
  for (int s = 0; s < 18; ++s) {
    const int tap = s >> 1, dh = tap / 3, dw = tap - dh*3;
    const int ic0 = (s & 1)*32 + kg*8;
    #pragma unroll
    for (int t = 0; t < 2; ++t) {
      const int px = (wv*2 + t)*16 + m;
      const int r = px >> 6, wl = px & 63;
      const s16x8 bfrag = *(const s16x8*)&Ys[((r + dh)*66 + wl + dw)*72 + ic0];
      acc[t] = __builtin_amdgcn_mfma_f32_16x16x32_bf16(afrag[s], bfrag, acc[t], 0, 0, 0);
    }
  }
  #pragma unroll
  for (int s = 18; s < 20; ++s) {
    const int ic0 = (s - 18)*32 + kg*8;
    #pragma unroll
    for (int t = 0; t < 2; ++t) {
      const int px = (wv*2 + t)*16 + m;
      const s16x8 bfrag = *(const s16x8*)&Rs[px*72 + ic0];
      acc[t] = __builtin_amdgcn_mfma_f32_16x16x32_bf16(afrag[s], bfrag, acc[t], 0, 0, 0);
    }
  }

  const int ocq = kg*4;
  const float4 q4 = *(const float4*)&bf[g*16 + ocq];
  const float qb[4] = {q4.x, q4.y, q4.z, q4.w};
  #pragma unroll
  for (int t = 0; t < 2; ++t) {
    const int px = (wv*2 + t)*16 + m;
    const int h = h0 + (px >> 6), w = w0 + (px & 63);
    #pragma unroll
    for (int r = 0; r < 4; ++r) {
      const int oc = g*16 + ocq + r;
      qout[((size_t)(b*64 + oc)*H_ + h)*W_ + w] = acc[t][r] + qb[r];
    }
  }
}

// ---------------------------------------------------------------------------
__global__ __launch_bounds__(64) void rowmean_kernel(float* __restrict__ q) {
  float* p = q + (size_t)blockIdx.x * W_;
  const int lane = threadIdx.x;
  float v[5]; float s = 0.f;
  #pragma unroll
  for (int k = 0; k < 5; ++k) { v[k] = p[lane + 64*k]; s += v[k]; }
  #pragma unroll
  for (int o = 32; o; o >>= 1) s += __shfl_xor(s, o);
  const float m = s * (1.f/320.f);
  #pragma unroll
  for (int k = 0; k < 5; ++k) p[lane + 64*k] = v[k] - m;
}

// ---------------------------------------------------------------------------
// stats via split-bf16 MFMA: rsum + cspart of exp(S). S = KhiQhi+KloQhi+KhiQlo.
__global__ __launch_bounds__(256, 4) void stats_kernel(
    const float* __restrict__ Qp, const float* __restrict__ Kp,
    float* __restrict__ rsum, float* __restrict__ cspart) {
  const int ub = blockIdx.x, row = blockIdx.y;
  const int b = row / H_, h = row - b*H_;
  const int u0 = ub * 64;
  const int tid = threadIdx.x;
  const int lane = tid & 63, wv = tid >> 6;
  const int l15 = lane & 15, l4 = lane >> 4;
  __shared__ unsigned short QH[64*64], QL[64*64], KH[64*64], KL[64*64];
  __shared__ float rsw[256];
  const size_t rowoff = (size_t)b*C0_*HW_ + (size_t)h*W_;

  for (int i = tid; i < 1024; i += 256) {
    int uq = i >> 6, c = i & 63;
    float4 v4 = *(const float4*)&Qp[rowoff + (size_t)c*HW_ + u0 + 4*uq];
    float q[4] = {v4.x, v4.y, v4.z, v4.w};
    #pragma unroll
    for (int j = 0; j < 4; ++j) {
      int r = 4*uq + j;
      unsigned hh = f2bf1(q[j]);
      QH[psw(r, c)] = (unsigned short)hh;
      QL[psw(r, c)] = (unsigned short)f2bf1(q[j] - __uint_as_float(hh << 16));
    }
  }
  float rp[4] = {};
  for (int vb = 0; vb < 5; ++vb) {
    __syncthreads();
    for (int i = tid; i < 1024; i += 256) {
      int vq = i >> 6, c = i & 63;
      float4 v4 = *(const float4*)&Kp[rowoff + (size_t)c*HW_ + vb*64 + 4*vq];
      float k[4] = {v4.x, v4.y, v4.z, v4.w};
      #pragma unroll
      for (int j = 0; j < 4; ++j) {
        int r = 4*vq + j;
        unsigned hh = f2bf1(k[j]);
        KH[psw(r, c)] = (unsigned short)hh;
        KL[psw(r, c)] = (unsigned short)f2bf1(k[j] - __uint_as_float(hh << 16));
      }
    }
    __syncthreads();
    const int vr = (wv << 4) + l15;
    const s16x8 kh0 = *(const s16x8*)&KH[psw(vr, l4*8)];
    const s16x8 kh1 = *(const s16x8*)&KH[psw(vr, 32 + l4*8)];
    const s16x8 kl0 = *(const s16x8*)&KL[psw(vr, l4*8)];
    const s16x8 kl1 = *(const s16x8*)&KL[psw(vr, 32 + l4*8)];
    float cp[4] = {};
    #pragma unroll
    for (int t = 0; t < 4; ++t) {
      const int qrow = t*16 + l15;
      const s16x8 qh0 = *(const s16x8*)&QH[psw(qrow, l4*8)];
      const s16x8 qh1 = *(const s16x8*)&QH[psw(qrow, 32 + l4*8)];
      const s16x8 ql0 = *(const s16x8*)&QL[psw(qrow, l4*8)];
      const s16x8 ql1 = *(const s16x8*)&QL[psw(qrow, 32 + l4*8)];
      f32x4 s = {};
      s = __builtin_amdgcn_mfma_f32_16x16x32_bf16(kh0, qh0, s, 0, 0, 0);
      s = __builtin_amdgcn_mfma_f32_16x16x32_bf16(kh1, qh1, s, 0, 0, 0);
      s = __builtin_amdgcn_mfma_f32_16x16x32_bf16(kl0, qh0, s, 0, 0, 0);
      s = __builtin_amdgcn_mfma_f32_16x16x32_bf16(kl1, qh1, s, 0, 0, 0);
      s = __builtin_amdgcn_mfma_f32_16x16x32_bf16(kh0, ql0, s, 0, 0, 0);
      s = __builtin_amdgcn_mfma_f32_16x16x32_bf16(kh1, ql1, s, 0, 0, 0);
      float e0 = __expf(s[0]), e1 = __expf(s[1]), e2 = __expf(s[2]), e3 = __expf(s[3]);
      rp[t] += e0 + e1 + e2 + e3;
      cp[0] += e0; cp[1] += e1; cp[2] += e2; cp[3] += e3;
    }
    #pragma unroll
    for (int r = 0; r < 4; ++r) {
      float v = cp[r];
      v += __shfl_xor(v, 1); v += __shfl_xor(v, 2);
      v += __shfl_xor(v, 4); v += __shfl_xor(v, 8);
      cp[r] = v;
    }
    if (l15 == 0) {
      f32x4 cw = {cp[0], cp[1], cp[2], cp[3]};
      *(f32x4*)&cspart[((size_t)row*5 + ub)*W_ + vb*64 + (wv << 4) + (l4 << 2)] = cw;
    }
  }
  #pragma unroll
  for (int t = 0; t < 4; ++t) {
    float v = rp[t];
    v += __shfl_xor(v, 16); v += __shfl_xor(v, 32);
    rp[t] = v;
  }
  if (l4 == 0) {
    #pragma unroll
    for (int t = 0; t < 4; ++t) rsw[(wv << 6) + (t << 4) + l15] = rp[t];
  }
  __syncthreads();
  if (tid < 64)
    rsum[(size_t)row*W_ + u0 + tid] = rsw[tid] + rsw[64+tid] + rsw[128+tid] + rsw[192+tid];
}

__global__ __launch_bounds__(256) void csreduce_kernel(
    const float* __restrict__ csp, float* __restrict__ csum) {
  int idx = blockIdx.x*256 + threadIdx.x;
  if (idx >= (int)RS_SZ) return;
  int row = idx / W_, v = idx - row*W_;
  float s = 0.f;
  #pragma unroll
  for (int ub = 0; ub < 5; ++ub) s += csp[((size_t)row*5 + ub)*W_ + v];
  csum[idx] = s;
}

// ---------------------------------------------------------------------------
__device__ __forceinline__ int halo_u(int k, int u0) {
  if (k < 64) return u0 + k;
  return (k == 64) ? (u0-2) : (k == 65) ? (u0-1) : (k == 66) ? (u0+64) : (u0+65);
}

// attn: split-bf16 MFMA S -> P (fp16 plane + f32 regs) -> fp16 MFMA xT + banded V
__global__ __launch_bounds__(256, 3) void attn_kernel(
    const float* __restrict__ Qp, const float* __restrict__ Kp,
    const float* __restrict__ rsump, const float* __restrict__ csump,
    const float* __restrict__ xmul, const float* __restrict__ xblend,
    float* __restrict__ outp) {
  const int ub = blockIdx.x;        // 0..4
  const int row = blockIdx.y;       // 0..319
  const int b = row / H_, h = row - b*H_;
  const int u0 = ub * 64;
  const int tid = threadIdx.x;
  const int lane = tid & 63, wv = tid >> 6;
  const int l15 = lane & 15, l4 = lane >> 4;

  __shared__ unsigned short QH[68*64], QL[68*64];   // Q split [u 0..67][c]
  __shared__ unsigned short KH[64*64], KL[64*64];   // K split [v][c]
  __shared__ _Float16 Xh[64*64];                    // x fp16 [c][v]
  __shared__ _Float16 Ph[68*64];                    // P fp16 [u 0..67][v]
  __shared__ float rinv[80];                        // 68..79 = 0
  __shared__ float Vw[256], Vt[64];

  const size_t rowoff = (size_t)b*C0_*HW_ + (size_t)h*W_;
  const float* rsrow = rsump + (size_t)row*W_;
  const float* csrow = csump + (size_t)row*W_;

  if (tid < 80) rinv[tid] = 0.f;
  if (tid < 68) {
    const int u = halo_u(tid, u0);
    rinv[tid] = (u >= 0 && u < W_) ? (1.f / rsrow[u]) : 0.f;
  }
  // stage Q transposed+split (rows 0..63 core, 64..67 halo)
  for (int i = tid; i < 17*64; i += 256) {
    int uq = i >> 6, c = i & 63;
    float q[4];
    if (uq < 16) {
      float4 v4 = *(const float4*)&Qp[rowoff + (size_t)c*HW_ + u0 + 4*uq];
      q[0] = v4.x; q[1] = v4.y; q[2] = v4.z; q[3] = v4.w;
    } else {
      #pragma unroll
      for (int j = 0; j < 4; ++j) {
        int u = halo_u(64 + j, u0);
        q[j] = (u >= 0 && u < W_) ? Qp[rowoff + (size_t)c*HW_ + u] : 0.f;
      }
    }
    #pragma unroll
    for (int j = 0; j < 4; ++j) {
      int r = 4*uq + j;
      unsigned hh = f2bf1(q[j]);
      QH[psw(r, c)] = (unsigned short)hh;
      QL[psw(r, c)] = (unsigned short)f2bf1(q[j] - __uint_as_float(hh << 16));
    }
  }

  f32x4 xacc[4] = {};
  float vsum[4] = {};
  const int vq4 = (wv << 4) + (l4 << 2);   // this lane's v base (4 consecutive)

  for (int vb = 0; vb < 5; ++vb) {
    const int v0 = vb * 64;
    __syncthreads();
    // stage K split [v][c]
    for (int i = tid; i < 1024; i += 256) {
      int vq = i >> 6, c = i & 63;
      float4 v4 = *(const float4*)&Kp[rowoff + (size_t)c*HW_ + v0 + 4*vq];
      float k[4] = {v4.x, v4.y, v4.z, v4.w};
      #pragma unroll
      for (int j = 0; j < 4; ++j) {
        int r = 4*vq + j;
        unsigned hh = f2bf1(k[j]);
        KH[psw(r, c)] = (unsigned short)hh;
        KL[psw(r, c)] = (unsigned short)f2bf1(k[j] - __uint_as_float(hh << 16));
      }
    }
    // stage x fp16 [c][v]
    for (int i = tid; i < 1024; i += 256) {
      int c = i >> 4, vq = i & 15;
      float4 v4 = *(const float4*)&xmul[rowoff + (size_t)c*HW_ + v0 + 4*vq];
      h16x4 hx = {(_Float16)v4.x, (_Float16)v4.y, (_Float16)v4.z, (_Float16)v4.w};
      *(h16x4*)&Xh[psw(c, 4*vq)] = hx;
    }
    __syncthreads();

    // ---- S phase: A = K rows (m = v), B = Q rows (n = u)
    const int vr = (wv << 4) + l15;
    const s16x8 kh0 = *(const s16x8*)&KH[psw(vr, l4*8)];
    const s16x8 kh1 = *(const s16x8*)&KH[psw(vr, 32 + l4*8)];
    const s16x8 kl0 = *(const s16x8*)&KL[psw(vr, l4*8)];
    const s16x8 kl1 = *(const s16x8*)&KL[psw(vr, 32 + l4*8)];
    float P[5][4];
    #pragma unroll
    for (int t = 0; t < 5; ++t) {
      const int qrow = (t < 4) ? (t*16 + l15) : (64 + (l15 & 3));
      const s16x8 qh0 = *(const s16x8*)&QH[psw(qrow, l4*8)];
      const s16x8 qh1 = *(const s16x8*)&QH[psw(qrow, 32 + l4*8)];
      const s16x8 ql0 = *(const s16x8*)&QL[psw(qrow, l4*8)];
      const s16x8 ql1 = *(const s16x8*)&QL[psw(qrow, 32 + l4*8)];
      f32x4 s = {};
      s = __builtin_amdgcn_mfma_f32_16x16x32_bf16(kh0, qh0, s, 0, 0, 0);
      s = __builtin_amdgcn_mfma_f32_16x16x32_bf16(kh1, qh1, s, 0, 0, 0);
      s = __builtin_amdgcn_mfma_f32_16x16x32_bf16(kl0, qh0, s, 0, 0, 0);
      s = __builtin_amdgcn_mfma_f32_16x16x32_bf16(kl1, qh1, s, 0, 0, 0);
      s = __builtin_amdgcn_mfma_f32_16x16x32_bf16(kh0, ql0, s, 0, 0, 0);
      s = __builtin_amdgcn_mfma_f32_16x16x32_bf16(kh1, ql1, s, 0, 0, 0);
      const float ri = rinv[(t < 4) ? (t*16 + l15) : (64 + l15)];   // 0 for pad/OOB
      #pragma unroll
      for (int r = 0; r < 4; ++r) P[t][r] = __expf(s[r]) * ri;
    }
    // write P to fp16 plane: core rows + halo rows
    #pragma unroll
    for (int t = 0; t < 4; ++t) {
      h16x4 hp = {(_Float16)P[t][0], (_Float16)P[t][1], (_Float16)P[t][2], (_Float16)P[t][3]};
      *(h16x4*)&Ph[psw(t*16 + l15, vq4)] = hp;
    }
    if (l15 < 4) {
      h16x4 hp = {(_Float16)P[4][0], (_Float16)P[4][1], (_Float16)P[4][2], (_Float16)P[4][3]};
      *(h16x4*)&Ph[psw(64 + l15, vq4)] = hp;
    }
    __syncthreads();

    // ---- xT phase: A = P rows (m = u), B = x rows (n = c)
    {
      const int ur = (wv << 4) + l15;
      const h16x8 pa0 = *(const h16x8*)&Ph[psw(ur, l4*8)];
      const h16x8 pa1 = *(const h16x8*)&Ph[psw(ur, 32 + l4*8)];
      #pragma unroll
      for (int t = 0; t < 4; ++t) {
        const int crow = t*16 + l15;
        const h16x8 xb0 = *(const h16x8*)&Xh[psw(crow, l4*8)];
        const h16x8 xb1 = *(const h16x8*)&Xh[psw(crow, 32 + l4*8)];
        xacc[t] = __builtin_amdgcn_mfma_f32_16x16x32_f16(pa0, xb0, xacc[t], 0, 0, 0);
        xacc[t] = __builtin_amdgcn_mfma_f32_16x16x32_f16(pa1, xb1, xacc[t], 0, 0, 0);
      }
    }

    // ---- banded V: d=0 from f32 regs, d=+-1,+-2 neighbors from fp16 plane
    {
      const float4 cs4 = *(const float4*)&csrow[v0 + vq4];
      const float ci[4] = {1.f/cs4.x, 1.f/cs4.y, 1.f/cs4.z, 1.f/cs4.w};
      #pragma unroll
      for (int t = 0; t < 4; ++t) {
        float w[4] = {P[t][0], P[t][1], P[t][2], P[t][3]};
        #pragma unroll
        for (int d = -2; d <= 2; ++d) {
          if (d == 0) continue;
          const int q = t*16 + l15 + d;
          const int rr = (q < 0) ? (66 + q) : ((q > 63) ? (q + 2) : q);
          const h16x4 pn = *(const h16x4*)&Ph[psw(rr, vq4)];
          w[0] += (float)pn[0]; w[1] += (float)pn[1];
          w[2] += (float)pn[2]; w[3] += (float)pn[3];
        }
        #pragma unroll
        for (int r = 0; r < 4; ++r)
          vsum[t] = fmaf(P[t][r] * ci[r], w[r], vsum[t]);
      }
    }
  }

  // V reduce: over l4 (shfl bits 4,5), then across waves via LDS
  #pragma unroll
  for (int t = 0; t < 4; ++t) {
    float v = vsum[t];
    v += __shfl_xor(v, 16); v += __shfl_xor(v, 32);
    vsum[t] = v;
  }
  if (l4 == 0) {
    #pragma unroll
    for (int t = 0; t < 4; ++t) Vw[(wv << 6) + (t << 4) + l15] = vsum[t];
  }
  __syncthreads();
  if (tid < 64) {
    float v = Vw[tid] + Vw[64+tid] + Vw[128+tid] + Vw[192+tid];
    Vt[tid] = tanhf(5.f * v * rsrow[u0 + tid]);
  }
  __syncthreads();

  // epilogue: lane holds xT[u = wv*16 + l4*4 + r][c = t*16 + l15]
  const int ubu = (wv << 4) + (l4 << 2);
  float tv[4];
  #pragma unroll
  for (int r = 0; r < 4; ++r) tv[r] = Vt[ubu + r];
  #pragma unroll
  for (int t = 0; t < 4; ++t) {
    const int c = (t << 4) + l15;
    const size_t base = rowoff + (size_t)c*HW_ + u0 + ubu;
    const float4 xb4 = *(const float4*)&xblend[base];
    float4 o4;
    o4.x = xb4.x * (1.f - tv[0]) + xacc[t][0] * tv[0];
    o4.y = xb4.y * (1.f - tv[1]) + xacc[t][1] * tv[1];
    o4.z = xb4.z * (1.f - tv[2]) + xacc[t][2] * tv[2];
    o4.w = xb4.w * (1.f - tv[3]) + xacc[t][3] * tv[3];
    *(float4*)&outp[base] = o4;
  }
}

// ---------------------------------------------------------------------------
extern "C" void kernel_launch(void* const* d_in, const int* in_sizes, int n_in,
                              void* d_out, int out_size, void* d_ws, size_t ws_size,
                              hipStream_t stream) {
  const float* x_left  = (const float*)d_in[0];
  const float* x_right = (const float*)d_in[1];
  const float* catL    = (const float*)d_in[2];
  const float* catR    = (const float*)d_in[3];
  const float* bq_w    = (const float*)d_in[4];
  const float* bq_b    = (const float*)d_in[5];
  const float* bs_w    = (const float*)d_in[6];
  const float* bs_b    = (const float*)d_in[7];
  const float* rb_w1   = (const float*)d_in[8];
  const float* rb_b1   = (const float*)d_in[9];
  const float* rb_w2   = (const float*)d_in[10];
  const float* rb_b2   = (const float*)d_in[11];
  const float* gamma   = (const float*)d_in[12];
  const float* beta    = (const float*)d_in[13];

  float* ws = (float*)d_ws;
  size_t off = 0;
  float* WfQ = ws + off; off += WFQ_SZ;
  float* WfK = ws + off; off += WFQ_SZ;
  unsigned short* Wb   = (unsigned short*)(ws + off); off += WB_SZ;
  unsigned short* W2bQ = (unsigned short*)(ws + off); off += W2B_SZ;
  unsigned short* W2bK = (unsigned short*)(ws + off); off += W2B_SZ;
  float* ab  = ws + off; off += AB_SZ;
  float* bfQ = ws + off; off += BF_SZ;
  float* bfK = ws + off; off += BF_SZ;
  unsigned short* t1   = (unsigned short*)(ws + off); off += T1_SZ;
  unsigned short* catb = (unsigned short*)(ws + off); off += CATB_SZ;
  float* Qb  = ws + off; off += QK_SZ;
  float* Kb  = ws + off; off += QK_SZ;
  float* rsb = ws + off; off += RS_SZ;
  float* csb = ws + off; off += RS_SZ;
  float* csp = ws + off; off += CSP_SZ;

  wtrans_kernel<<<576, 256, 0, stream>>>(rb_w1, rb_w2, bq_w, bs_w, Wb, WfQ, WfK);
  bnstats_kernel<<<512, 256, 0, stream>>>(catL, catR, gamma, beta, ab);
  prep2_kernel<<<160, 256, 0, stream>>>(bq_w, bs_w, bq_b, bs_b, rb_b2,
                                        WfQ, WfK, W2bQ, W2bK, bfQ, bfK);

  dim3 agrid(HW_/64, 1, 8);
  dim3 cgrid(5, 80, 8);
  // left -> Q
  bnapply_kernel<<<agrid, 256, 0, stream>>>(catL, ab, catb);
  conv1_mfma<<<cgrid, 256, 0, stream>>>(catb, Wb, rb_b1, t1);
  conv2_mfma<<<cgrid, 256, 0, stream>>>(t1, catb, W2bQ, bfQ, Qb);
  // right -> K
  bnapply_kernel<<<agrid, 256, 0, stream>>>(catR, ab + 512, catb);
  conv1_mfma<<<cgrid, 256, 0, stream>>>(catb, Wb, rb_b1, t1);
  conv2_mfma<<<cgrid, 256, 0, stream>>>(t1, catb, W2bK, bfK, Kb);

  rowmean_kernel<<<B_*C0_*H_, 64, 0, stream>>>(Qb);
  rowmean_kernel<<<B_*C0_*H_, 64, 0, stream>>>(Kb);

  stats_kernel<<<dim3(5, NROWS_), 256, 0, stream>>>(Qb, Kb, rsb, csp);
  csreduce_kernel<<<(int)((RS_SZ + 255)/256), 256, 0, stream>>>(csp, csb);

  float* outL = (float*)d_out;
  float* outR = outL + QK_SZ;
  attn_kernel<<<dim3(5, NROWS_), 256, 0, stream>>>(Qb, Kb, rsb, csb, x_right, x_left, outL);
  attn_kernel<<<dim3(5, NROWS_), 256, 0, stream>>>(Kb, Qb, csb, rsb, x_left, x_right, outR);
}

// Round 8
// 651.246 us; speedup vs baseline: 8.2942x; 1.0833x over previous
//
#include <hip/hip_runtime.h>

#define B_    2
#define C0_   64
#define C4_   256
#define H_    160
#define W_    320
#define G_    4
#define HW_   (H_*W_)
#define NROWS_ (B_*H_)      // 320
#define EPS_  1e-5f

typedef float f32x4 __attribute__((ext_vector_type(4)));
typedef short s16x8 __attribute__((ext_vector_type(8)));
typedef _Float16 h16x8 __attribute__((ext_vector_type(8)));
typedef _Float16 h16x4 __attribute__((ext_vector_type(4)));

// workspace sizes (in floats)
#define WFQ_SZ  36864       // f32 [g][tap9][o16][ic64]
#define WB_SZ   73728       // bf16 conv1 weights (147456 shorts)
#define W2B_SZ  20480       // bf16 fused conv2 weights (40960 shorts)
#define AB_SZ   1024
#define BF_SZ   64
#define PB_SZ   8192        // bnstats partials: 4096 float2
#define T1_SZ   13107200    // bf16 t1 [b][g][h][w][ic64]
#define CATB_SZ 13107200    // bf16 catb, same layout (one side at a time)
#define QK_SZ   ((size_t)B_*C0_*HW_)   // 6553600
#define RS_SZ   ((size_t)NROWS_*W_)    // 102400
#define CSP_SZ  ((size_t)NROWS_*5*W_)  // 512000

__device__ __forceinline__ unsigned f2bf1(float x) {
  unsigned u = __float_as_uint(x);
  return (u + 0x7FFFu + ((u >> 16) & 1u)) >> 16;
}
__device__ __forceinline__ unsigned packbf(float lo, float hi) {
  return f2bf1(lo) | (f2bf1(hi) << 16);
}
// swizzled short-index into a [row][64] 2B plane: XOR 16B-chunk by (row&7)
__device__ __forceinline__ int psw(int r, int c) {
  return (r << 6) + (((c >> 3) ^ (r & 7)) << 3) + (c & 7);
}

// ---------------------------------------------------------------------------
// wtrans: Wb bf16 [g][tap][oc][ic]; WfQ/WfK f32 [g][tap][o16][ic] (proj-folded)
__global__ __launch_bounds__(256) void wtrans_kernel(
    const float* __restrict__ w1, const float* __restrict__ w2,
    const float* __restrict__ bq, const float* __restrict__ bs,
    unsigned short* __restrict__ Wb, float* __restrict__ WfQ, float* __restrict__ WfK) {
  int idx = blockIdx.x * 256 + threadIdx.x;
  if (idx < 147456) {
    int ic = idx & 63, oc = (idx >> 6) & 63, tap = (idx >> 12) % 9, g = idx / 36864;
    float v = w1[((size_t)(g*64 + oc) * 64 + ic) * 9 + tap];
    Wb[idx] = (unsigned short)f2bf1(v);
  }
  if (idx < 36864) {
    int ic = idx & 63, o = (idx >> 6) & 15, tap = (idx >> 10) % 9, g = idx / 9216;
    const float* w2p = w2 + ((size_t)(g*64) * 64 + ic) * 9 + tap;   // + oc*576
    const float* bqp = bq + (size_t)(g*16 + o) * 64;
    const float* bsp = bs + (size_t)(g*16 + o) * 64;
    float sq = 0.f, sk = 0.f;
    for (int oc = 0; oc < 64; ++oc) {
      float wv = w2p[(size_t)oc * 576];
      sq = fmaf(bqp[oc], wv, sq);
      sk = fmaf(bsp[oc], wv, sk);
    }
    WfQ[idx] = sq;
    WfK[idx] = sk;
  }
}

// ---------------------------------------------------------------------------
// bnstats stage 1: per (side, channel, hw-chunk) partial sum/sumsq, float4 loads.
// grid.x = 4096: sc = bid>>3 (side*256+c), ck = bid&7 (chunk of HW/8=6400 floats)
__global__ __launch_bounds__(256) void bnstats1_kernel(
    const float* __restrict__ catL, const float* __restrict__ catR,
    float2* __restrict__ pb) {
  const int bid = blockIdx.x;
  const int sc = bid >> 3, ck = bid & 7;
  const int side = sc >> 8, c = sc & 255;
  const float* base = (side ? catR : catL) + (size_t)c * HW_ + ck * (HW_/8);
  float s = 0.f, s2 = 0.f;
  for (int i = threadIdx.x; i < 1600; i += 256) {   // 1600 float4 = 6400 floats
    const float4 v0 = *(const float4*)&base[4*i];
    const float4 v1 = *(const float4*)&base[(size_t)C4_*HW_ + 4*i];
    s  += (v0.x + v0.y) + (v0.z + v0.w) + (v1.x + v1.y) + (v1.z + v1.w);
    float t0 = fmaf(v0.x, v0.x, v0.y*v0.y) + fmaf(v0.z, v0.z, v0.w*v0.w);
    float t1 = fmaf(v1.x, v1.x, v1.y*v1.y) + fmaf(v1.z, v1.z, v1.w*v1.w);
    s2 += t0 + t1;
  }
  #pragma unroll
  for (int o = 32; o; o >>= 1) { s += __shfl_down(s, o); s2 += __shfl_down(s2, o); }
  __shared__ float rs[4], rs2[4];
  const int wid = threadIdx.x >> 6;
  if ((threadIdx.x & 63) == 0) { rs[wid] = s; rs2[wid] = s2; }
  __syncthreads();
  if (threadIdx.x == 0)
    pb[bid] = make_float2(rs[0]+rs[1]+rs[2]+rs[3], rs2[0]+rs2[1]+rs2[2]+rs2[3]);
}

// bnstats stage 2: fold 8 partials per (side,c) -> scale a, shift b
__global__ __launch_bounds__(256) void bnstats2_kernel(
    const float2* __restrict__ pb, const float* __restrict__ gamma,
    const float* __restrict__ beta, float* __restrict__ ab) {
  const int sc = blockIdx.x * 256 + threadIdx.x;
  if (sc >= 512) return;
  const int side = sc >> 8, c = sc & 255;
  float s = 0.f, s2 = 0.f;
  #pragma unroll
  for (int k = 0; k < 8; ++k) {
    const float2 p = pb[sc*8 + k];
    s += p.x; s2 += p.y;
  }
  const float inv_n = 1.f / (float)(2*HW_);
  const float mu  = s * inv_n;
  const float var = s2 * inv_n - mu*mu;
  const float a = gamma[c] * rsqrtf(var + EPS_);
  ab[side*512 + c]       = a;
  ab[side*512 + 256 + c] = beta[c] - mu*a;
}

// ---------------------------------------------------------------------------
// bnapply: catb[b][g][px][ic64] = bf16( a*cat + shift ). One side per launch.
__global__ __launch_bounds__(256) void bnapply_kernel(
    const float* __restrict__ cat, const float* __restrict__ abs_,
    unsigned short* __restrict__ catb) {
  const int z = blockIdx.z;
  const int b = z >> 2, g = z & 3;
  const int tid = threadIdx.x;
  const int px = blockIdx.x * 64 + (tid & 63);
  const int ic0 = (tid >> 6) * 16;
  const float* src = cat + ((size_t)b*C4_ + g*64 + ic0) * HW_ + px;
  const float* abp = abs_ + g*64 + ic0;
  unsigned short* dst = catb + (((size_t)(b*4 + g)*HW_ + px) << 6) + ic0;
  unsigned pk[8];
  #pragma unroll
  for (int j = 0; j < 8; ++j) {
    const float2 a2 = *(const float2*)&abp[2*j];
    const float2 s2 = *(const float2*)&abp[256 + 2*j];
    float v0 = fmaf(a2.x, src[(size_t)(2*j)*HW_],   s2.x);
    float v1 = fmaf(a2.y, src[(size_t)(2*j+1)*HW_], s2.y);
    pk[j] = packbf(v0, v1);
  }
  *(uint4*)&dst[0] = *(uint4*)&pk[0];
  *(uint4*)&dst[8] = *(uint4*)&pk[4];
}

// ---------------------------------------------------------------------------
// prep2: W2bQ/K bf16 [g][tap10][o][ic] (tap9 = plain proj weight; residual data
// comes from catb which already carries full BN); bf[o] = proj_bias + sum_c w*b2_c
__global__ __launch_bounds__(256) void prep2_kernel(
    const float* __restrict__ bq, const float* __restrict__ bs,
    const float* __restrict__ bqb, const float* __restrict__ bsb,
    const float* __restrict__ b2,
    const float* __restrict__ WfQ, const float* __restrict__ WfK,
    unsigned short* __restrict__ W2bQ, unsigned short* __restrict__ W2bK,
    float* __restrict__ bfQ, float* __restrict__ bfK) {
  int idx = blockIdx.x*256 + threadIdx.x;
  if (idx < 40960) {
    int ic = idx & 63, o = (idx >> 6) & 15, tap = (idx >> 10) % 10, g = idx / 10240;
    float vq, vk;
    if (tap < 9) {
      int src = ((g*9 + tap)*16 + o)*64 + ic;
      vq = WfQ[src]; vk = WfK[src];
    } else {
      vq = bq[(size_t)(g*16 + o)*64 + ic];
      vk = bs[(size_t)(g*16 + o)*64 + ic];
    }
    W2bQ[idx] = (unsigned short)f2bf1(vq);
    W2bK[idx] = (unsigned short)f2bf1(vk);
  }
  if (idx < 128) {
    int side = idx >> 6, co = idx & 63, g = co >> 4, o = co & 15;
    const float* w = side ? bs : bq;
    float s = (side ? bsb : bqb)[co];
    for (int c2 = 0; c2 < 64; ++c2) {
      int ch = g*64 + c2;
      s = fmaf(w[(size_t)(g*16 + o)*64 + c2], b2[ch], s);
    }
    (side ? bfK : bfQ)[co] = s;
  }
}

// ---------------------------------------------------------------------------
// conv1 MFMA: t1[b][g][h][w][oc64](bf16) = leaky(gconv3x3(catb) + b1)
__global__ __launch_bounds__(256) void conv1_mfma(
    const unsigned short* __restrict__ catb,
    const unsigned short* __restrict__ Wb, const float* __restrict__ bias,
    unsigned short* __restrict__ t1) {
  const int b = blockIdx.z >> 2, g = blockIdx.z & 3;
  const int h0 = blockIdx.y * 2, w0 = blockIdx.x * 64;
  const int tid = threadIdx.x;
  const int lane = tid & 63, wv = tid >> 6;
  const int m0 = wv * 16;
  const int m = lane & 15, kg = lane >> 4;
  __shared__ short Xs[4*66*72];   // [r4][c66][icpad72]

  const unsigned short* catbg = catb + (((size_t)(b*4 + g)*H_) << 6) * W_;
  for (int u = tid; u < 264*8; u += 256) {
    int rc = u >> 3, j = u & 7;
    int r = rc / 66, c = rc - r*66;
    int gh = h0 - 1 + r, gw = w0 - 1 + c;
    s16x8 v = {};
    if (gh >= 0 && gh < H_ && gw >= 0 && gw < W_)
      v = *(const s16x8*)&catbg[(((size_t)gh*W_ + gw) << 6) + j*8];
    *(s16x8*)&Xs[rc*72 + j*8] = v;
  }

  s16x8 afrag[18];
  #pragma unroll
  for (int s = 0; s < 18; ++s) {
    const int tap = s >> 1, ic0 = (s & 1)*32 + kg*8;
    afrag[s] = *(const s16x8*)&Wb[(((size_t)g*9 + tap)*64 + m0 + m)*64 + ic0];
  }
  __syncthreads();

  f32x4 acc[8] = {};
  #pragma unroll
  for (int s = 0; s < 18; ++s) {
    const int tap = s >> 1, dh = tap / 3, dw = tap - dh*3;
    const int ic0 = (s & 1)*32 + kg*8;
    #pragma unroll
    for (int t = 0; t < 8; ++t) {
      const int px = t*16 + m;
      const int r = px >> 6, wl = px & 63;
      const s16x8 bfrag = *(const s16x8*)&Xs[((r + dh)*66 + wl + dw)*72 + ic0];
      acc[t] = __builtin_amdgcn_mfma_f32_16x16x32_bf16(afrag[s], bfrag, acc[t], 0, 0, 0);
    }
  }

  const int ocq = m0 + kg*4;
  const float4 b4 = *(const float4*)&bias[g*64 + ocq];
  const float bb[4] = {b4.x, b4.y, b4.z, b4.w};
  #pragma unroll
  for (int t = 0; t < 8; ++t) {
    const int px = t*16 + m;
    const int h = h0 + (px >> 6), w = w0 + (px & 63);
    float v[4];
    #pragma unroll
    for (int r = 0; r < 4; ++r) {
      float x = acc[t][r] + bb[r];
      v[r] = (x >= 0.f) ? x : 0.1f * x;
    }
    const size_t base = ((((size_t)(b*4 + g)*H_ + h)*W_ + w) << 6) + ocq;
    uint2 pk; pk.x = packbf(v[0], v[1]); pk.y = packbf(v[2], v[3]);
    *(uint2*)&t1[base] = pk;
  }
}

// ---------------------------------------------------------------------------
// conv2 MFMA + folded 1x1 proj + residual-as-K (residual data = catb)
__global__ __launch_bounds__(256) void conv2_mfma(
    const unsigned short* __restrict__ t1, const unsigned short* __restrict__ catb,
    const unsigned short* __restrict__ W2b,
    const float* __restrict__ bf, float* __restrict__ qout) {
  const int b = blockIdx.z >> 2, g = blockIdx.z & 3;
  const int h0 = blockIdx.y * 2, w0 = blockIdx.x * 64;
  const int tid = threadIdx.x;
  const int lane = tid & 63, wv = tid >> 6;
  const int m = lane & 15, kg = lane >> 4;
  __shared__ short Ys[4*66*72];    // t1 tile [r][c][icpad]
  __shared__ short Rs[128*72];     // residual [px][icpad] = catb core tile

  const unsigned short* t1g = t1 + (((size_t)(b*4 + g)*H_) << 6) * W_;
  const unsigned short* catbg = catb + (((size_t)(b*4 + g)*H_) << 6) * W_;
  for (int u = tid; u < 264*8; u += 256) {
    int rc = u >> 3, j = u & 7;
    int r = rc / 66, c = rc - r*66;
    int gh = h0 - 1 + r, gw = w0 - 1 + c;
    s16x8 v = {};
    if (gh >= 0 && gh < H_ && gw >= 0 && gw < W_)
      v = *(const s16x8*)&t1g[(((size_t)gh*W_ + gw) << 6) + j*8];
    *(s16x8*)&Ys[(rc*72) + j*8] = v;
  }
  for (int u = tid; u < 128*8; u += 256) {
    int px = u >> 3, j = u & 7;
    int gh = h0 + (px >> 6), gw = w0 + (px & 63);
    *(s16x8*)&Rs[px*72 + j*8] =
        *(const s16x8*)&catbg[(((size_t)gh*W_ + gw) << 6) + j*8];
  }

  s16x8 afrag[20];
  #pragma unroll
  for (int s = 0; s < 20; ++s) {
    const int tap = (s < 18) ? (s >> 1) : 9;
    const int ic0 = (s < 18) ? ((s & 1)*32 + kg*8) : ((s - 18)*32 + kg*8);
    afrag[s] = *(const s16x8*)&W2b[(((size_t)g*10 + tap)*16 + m)*64 + ic0];
  }
  __syncthreads();

  f32x4 acc[2] = {};
  #pragma unroll
  for (int s = 0; s < 18; ++s) {
    const int tap = s >> 1, dh = tap / 3, dw = tap - dh*3;
    const int ic0 = (s & 1)*32 + kg*8;
    #pragma unroll
    for (int t = 0; t < 2; ++t) {
      const int px = (wv*2 + t)*16 + m;
      const int r = px >> 6, wl = px & 63;
      const s16x8 bfrag = *(const s16x8*)&Ys[((r + dh)*66 + wl + dw)*72 + ic0];
      acc[t] = __builtin_amdgcn_mfma_f32_16x16x32_bf16(afrag[s], bfrag, acc[t], 0, 0, 0);
    }
  }
  #pragma unroll
  for (int s = 18; s < 20; ++s) {
    const int ic0 = (s - 18)*32 + kg*8;
    #pragma unroll
    for (int t = 0; t < 2; ++t) {
      const int px = (wv*2 + t)*16 + m;
      const s16x8 bfrag = *(const s16x8*)&Rs[px*72 + ic0];
      acc[t] = __builtin_amdgcn_mfma_f32_16x16x32_bf16(afrag[s], bfrag, acc[t], 0, 0, 0);
    }
  }

  const int ocq = kg*4;
  const float4 q4 = *(const float4*)&bf[g*16 + ocq];
  const float qb[4] = {q4.x, q4.y, q4.z, q4.w};
  #pragma unroll
  for (int t = 0; t < 2; ++t) {
    const int px = (wv*2 + t)*16 + m;
    const int h = h0 + (px >> 6), w = w0 + (px & 63);
    #pragma unroll
    for (int r = 0; r < 4; ++r) {
      const int oc = g*16 + ocq + r;
      qout[((size_t)(b*64 + oc)*H_ + h)*W_ + w] = acc[t][r] + qb[r];
    }
  }
}

// ---------------------------------------------------------------------------
__global__ __launch_bounds__(64) void rowmean_kernel(float* __restrict__ q) {
  float* p = q + (size_t)blockIdx.x * W_;
  const int lane = threadIdx.x;
  float v[5]; float s = 0.f;
  #pragma unroll
  for (int k = 0; k < 5; ++k) { v[k] = p[lane + 64*k]; s += v[k]; }
  #pragma unroll
  for (int o = 32; o; o >>= 1) s += __shfl_xor(s, o);
  const float m = s * (1.f/320.f);
  #pragma unroll
  for (int k = 0; k < 5; ++k) p[lane + 64*k] = v[k] - m;
}

// ---------------------------------------------------------------------------
// stats via split-bf16 MFMA: rsum + cspart of exp(S). S = KhiQhi+KloQhi+KhiQlo.
__global__ __launch_bounds__(256, 4) void stats_kernel(
    const float* __restrict__ Qp, const float* __restrict__ Kp,
    float* __restrict__ rsum, float* __restrict__ cspart) {
  const int ub = blockIdx.x, row = blockIdx.y;
  const int b = row / H_, h = row - b*H_;
  const int u0 = ub * 64;
  const int tid = threadIdx.x;
  const int lane = tid & 63, wv = tid >> 6;
  const int l15 = lane & 15, l4 = lane >> 4;
  __shared__ unsigned short QH[64*64], QL[64*64], KH[64*64], KL[64*64];
  __shared__ float rsw[256];
  const size_t rowoff = (size_t)b*C0_*HW_ + (size_t)h*W_;

  for (int i = tid; i < 1024; i += 256) {
    int uq = i >> 6, c = i & 63;
    float4 v4 = *(const float4*)&Qp[rowoff + (size_t)c*HW_ + u0 + 4*uq];
    float q[4] = {v4.x, v4.y, v4.z, v4.w};
    #pragma unroll
    for (int j = 0; j < 4; ++j) {
      int r = 4*uq + j;
      unsigned hh = f2bf1(q[j]);
      QH[psw(r, c)] = (unsigned short)hh;
      QL[psw(r, c)] = (unsigned short)f2bf1(q[j] - __uint_as_float(hh << 16));
    }
  }
  float rp[4] = {};
  for (int vb = 0; vb < 5; ++vb) {
    __syncthreads();
    for (int i = tid; i < 1024; i += 256) {
      int vq = i >> 6, c = i & 63;
      float4 v4 = *(const float4*)&Kp[rowoff + (size_t)c*HW_ + vb*64 + 4*vq];
      float k[4] = {v4.x, v4.y, v4.z, v4.w};
      #pragma unroll
      for (int j = 0; j < 4; ++j) {
        int r = 4*vq + j;
        unsigned hh = f2bf1(k[j]);
        KH[psw(r, c)] = (unsigned short)hh;
        KL[psw(r, c)] = (unsigned short)f2bf1(k[j] - __uint_as_float(hh << 16));
      }
    }
    __syncthreads();
    const int vr = (wv << 4) + l15;
    const s16x8 kh0 = *(const s16x8*)&KH[psw(vr, l4*8)];
    const s16x8 kh1 = *(const s16x8*)&KH[psw(vr, 32 + l4*8)];
    const s16x8 kl0 = *(const s16x8*)&KL[psw(vr, l4*8)];
    const s16x8 kl1 = *(const s16x8*)&KL[psw(vr, 32 + l4*8)];
    float cp[4] = {};
    #pragma unroll
    for (int t = 0; t < 4; ++t) {
      const int qrow = t*16 + l15;
      const s16x8 qh0 = *(const s16x8*)&QH[psw(qrow, l4*8)];
      const s16x8 qh1 = *(const s16x8*)&QH[psw(qrow, 32 + l4*8)];
      const s16x8 ql0 = *(const s16x8*)&QL[psw(qrow, l4*8)];
      const s16x8 ql1 = *(const s16x8*)&QL[psw(qrow, 32 + l4*8)];
      f32x4 s = {};
      s = __builtin_amdgcn_mfma_f32_16x16x32_bf16(kh0, qh0, s, 0, 0, 0);
      s = __builtin_amdgcn_mfma_f32_16x16x32_bf16(kh1, qh1, s, 0, 0, 0);
      s = __builtin_amdgcn_mfma_f32_16x16x32_bf16(kl0, qh0, s, 0, 0, 0);
      s = __builtin_amdgcn_mfma_f32_16x16x32_bf16(kl1, qh1, s, 0, 0, 0);
      s = __builtin_amdgcn_mfma_f32_16x16x32_bf16(kh0, ql0, s, 0, 0, 0);
      s = __builtin_amdgcn_mfma_f32_16x16x32_bf16(kh1, ql1, s, 0, 0, 0);
      float e0 = __expf(s[0]), e1 = __expf(s[1]), e2 = __expf(s[2]), e3 = __expf(s[3]);
      rp[t] += e0 + e1 + e2 + e3;
      cp[0] += e0; cp[1] += e1; cp[2] += e2; cp[3] += e3;
    }
    #pragma unroll
    for (int r = 0; r < 4; ++r) {
      float v = cp[r];
      v += __shfl_xor(v, 1); v += __shfl_xor(v, 2);
      v += __shfl_xor(v, 4); v += __shfl_xor(v, 8);
      cp[r] = v;
    }
    if (l15 == 0) {
      f32x4 cw = {cp[0], cp[1], cp[2], cp[3]};
      *(f32x4*)&cspart[((size_t)row*5 + ub)*W_ + vb*64 + (wv << 4) + (l4 << 2)] = cw;
    }
  }
  #pragma unroll
  for (int t = 0; t < 4; ++t) {
    float v = rp[t];
    v += __shfl_xor(v, 16); v += __shfl_xor(v, 32);
    rp[t] = v;
  }
  if (l4 == 0) {
    #pragma unroll
    for (int t = 0; t < 4; ++t) rsw[(wv << 6) + (t << 4) + l15] = rp[t];
  }
  __syncthreads();
  if (tid < 64)
    rsum[(size_t)row*W_ + u0 + tid] = rsw[tid] + rsw[64+tid] + rsw[128+tid] + rsw[192+tid];
}

__global__ __launch_bounds__(256) void csreduce_kernel(
    const float* __restrict__ csp, float* __restrict__ csum) {
  int idx = blockIdx.x*256 + threadIdx.x;
  if (idx >= (int)RS_SZ) return;
  int row = idx / W_, v = idx - row*W_;
  float s = 0.f;
  #pragma unroll
  for (int ub = 0; ub < 5; ++ub) s += csp[((size_t)row*5 + ub)*W_ + v];
  csum[idx] = s;
}

// ---------------------------------------------------------------------------
__device__ __forceinline__ int halo_u(int k, int u0) {
  if (k < 64) return u0 + k;
  return (k == 64) ? (u0-2) : (k == 65) ? (u0-1) : (k == 66) ? (u0+64) : (u0+65);
}

// attn: split-bf16 MFMA S -> P (fp16 plane + f32 regs) -> fp16 MFMA xT + banded V
__global__ __launch_bounds__(256, 3) void attn_kernel(
    const float* __restrict__ Qp, const float* __restrict__ Kp,
    const float* __restrict__ rsump, const float* __restrict__ csump,
    const float* __restrict__ xmul, const float* __restrict__ xblend,
    float* __restrict__ outp) {
  const int ub = blockIdx.x;        // 0..4
  const int row = blockIdx.y;       // 0..319
  const int b = row / H_, h = row - b*H_;
  const int u0 = ub * 64;
  const int tid = threadIdx.x;
  const int lane = tid & 63, wv = tid >> 6;
  const int l15 = lane & 15, l4 = lane >> 4;

  __shared__ unsigned short QH[68*64], QL[68*64];   // Q split [u 0..67][c]
  __shared__ unsigned short KH[64*64], KL[64*64];   // K split [v][c]
  __shared__ _Float16 Xh[64*64];                    // x fp16 [c][v]
  __shared__ _Float16 Ph[68*64];                    // P fp16 [u 0..67][v]
  __shared__ float rinv[80];                        // 68..79 = 0
  __shared__ float Vw[256], Vt[64];

  const size_t rowoff = (size_t)b*C0_*HW_ + (size_t)h*W_;
  const float* rsrow = rsump + (size_t)row*W_;
  const float* csrow = csump + (size_t)row*W_;

  if (tid < 80) rinv[tid] = 0.f;
  if (tid < 68) {
    const int u = halo_u(tid, u0);
    rinv[tid] = (u >= 0 && u < W_) ? (1.f / rsrow[u]) : 0.f;
  }
  // stage Q transposed+split (rows 0..63 core, 64..67 halo)
  for (int i = tid; i < 17*64; i += 256) {
    int uq = i >> 6, c = i & 63;
    float q[4];
    if (uq < 16) {
      float4 v4 = *(const float4*)&Qp[rowoff + (size_t)c*HW_ + u0 + 4*uq];
      q[0] = v4.x; q[1] = v4.y; q[2] = v4.z; q[3] = v4.w;
    } else {
      #pragma unroll
      for (int j = 0; j < 4; ++j) {
        int u = halo_u(64 + j, u0);
        q[j] = (u >= 0 && u < W_) ? Qp[rowoff + (size_t)c*HW_ + u] : 0.f;
      }
    }
    #pragma unroll
    for (int j = 0; j < 4; ++j) {
      int r = 4*uq + j;
      unsigned hh = f2bf1(q[j]);
      QH[psw(r, c)] = (unsigned short)hh;
      QL[psw(r, c)] = (unsigned short)f2bf1(q[j] - __uint_as_float(hh << 16));
    }
  }

  f32x4 xacc[4] = {};
  float vsum[4] = {};
  const int vq4 = (wv << 4) + (l4 << 2);   // this lane's v base (4 consecutive)

  for (int vb = 0; vb < 5; ++vb) {
    const int v0 = vb * 64;
    __syncthreads();
    // stage K split [v][c]
    for (int i = tid; i < 1024; i += 256) {
      int vq = i >> 6, c = i & 63;
      float4 v4 = *(const float4*)&Kp[rowoff + (size_t)c*HW_ + v0 + 4*vq];
      float k[4] = {v4.x, v4.y, v4.z, v4.w};
      #pragma unroll
      for (int j = 0; j < 4; ++j) {
        int r = 4*vq + j;
        unsigned hh = f2bf1(k[j]);
        KH[psw(r, c)] = (unsigned short)hh;
        KL[psw(r, c)] = (unsigned short)f2bf1(k[j] - __uint_as_float(hh << 16));
      }
    }
    // stage x fp16 [c][v]
    for (int i = tid; i < 1024; i += 256) {
      int c = i >> 4, vq = i & 15;
      float4 v4 = *(const float4*)&xmul[rowoff + (size_t)c*HW_ + v0 + 4*vq];
      h16x4 hx = {(_Float16)v4.x, (_Float16)v4.y, (_Float16)v4.z, (_Float16)v4.w};
      *(h16x4*)&Xh[psw(c, 4*vq)] = hx;
    }
    __syncthreads();

    // ---- S phase: A = K rows (m = v), B = Q rows (n = u)
    const int vr = (wv << 4) + l15;
    const s16x8 kh0 = *(const s16x8*)&KH[psw(vr, l4*8)];
    const s16x8 kh1 = *(const s16x8*)&KH[psw(vr, 32 + l4*8)];
    const s16x8 kl0 = *(const s16x8*)&KL[psw(vr, l4*8)];
    const s16x8 kl1 = *(const s16x8*)&KL[psw(vr, 32 + l4*8)];
    float P[5][4];
    #pragma unroll
    for (int t = 0; t < 5; ++t) {
      const int qrow = (t < 4) ? (t*16 + l15) : (64 + (l15 & 3));
      const s16x8 qh0 = *(const s16x8*)&QH[psw(qrow, l4*8)];
      const s16x8 qh1 = *(const s16x8*)&QH[psw(qrow, 32 + l4*8)];
      const s16x8 ql0 = *(const s16x8*)&QL[psw(qrow, l4*8)];
      const s16x8 ql1 = *(const s16x8*)&QL[psw(qrow, 32 + l4*8)];
      f32x4 s = {};
      s = __builtin_amdgcn_mfma_f32_16x16x32_bf16(kh0, qh0, s, 0, 0, 0);
      s = __builtin_amdgcn_mfma_f32_16x16x32_bf16(kh1, qh1, s, 0, 0, 0);
      s = __builtin_amdgcn_mfma_f32_16x16x32_bf16(kl0, qh0, s, 0, 0, 0);
      s = __builtin_amdgcn_mfma_f32_16x16x32_bf16(kl1, qh1, s, 0, 0, 0);
      s = __builtin_amdgcn_mfma_f32_16x16x32_bf16(kh0, ql0, s, 0, 0, 0);
      s = __builtin_amdgcn_mfma_f32_16x16x32_bf16(kh1, ql1, s, 0, 0, 0);
      const float ri = rinv[(t < 4) ? (t*16 + l15) : (64 + l15)];   // 0 for pad/OOB
      #pragma unroll
      for (int r = 0; r < 4; ++r) P[t][r] = __expf(s[r]) * ri;
    }
    // write P to fp16 plane: core rows + halo rows
    #pragma unroll
    for (int t = 0; t < 4; ++t) {
      h16x4 hp = {(_Float16)P[t][0], (_Float16)P[t][1], (_Float16)P[t][2], (_Float16)P[t][3]};
      *(h16x4*)&Ph[psw(t*16 + l15, vq4)] = hp;
    }
    if (l15 < 4) {
      h16x4 hp = {(_Float16)P[4][0], (_Float16)P[4][1], (_Float16)P[4][2], (_Float16)P[4][3]};
      *(h16x4*)&Ph[psw(64 + l15, vq4)] = hp;
    }
    __syncthreads();

    // ---- xT phase: A = P rows (m = u), B = x rows (n = c)
    {
      const int ur = (wv << 4) + l15;
      const h16x8 pa0 = *(const h16x8*)&Ph[psw(ur, l4*8)];
      const h16x8 pa1 = *(const h16x8*)&Ph[psw(ur, 32 + l4*8)];
      #pragma unroll
      for (int t = 0; t < 4; ++t) {
        const int crow = t*16 + l15;
        const h16x8 xb0 = *(const h16x8*)&Xh[psw(crow, l4*8)];
        const h16x8 xb1 = *(const h16x8*)&Xh[psw(crow, 32 + l4*8)];
        xacc[t] = __builtin_amdgcn_mfma_f32_16x16x32_f16(pa0, xb0, xacc[t], 0, 0, 0);
        xacc[t] = __builtin_amdgcn_mfma_f32_16x16x32_f16(pa1, xb1, xacc[t], 0, 0, 0);
      }
    }

    // ---- banded V: d=0 from f32 regs, d=+-1,+-2 neighbors from fp16 plane
    {
      const float4 cs4 = *(const float4*)&csrow[v0 + vq4];
      const float ci[4] = {1.f/cs4.x, 1.f/cs4.y, 1.f/cs4.z, 1.f/cs4.w};
      #pragma unroll
      for (int t = 0; t < 4; ++t) {
        float w[4] = {P[t][0], P[t][1], P[t][2], P[t][3]};
        #pragma unroll
        for (int d = -2; d <= 2; ++d) {
          if (d == 0) continue;
          const int q = t*16 + l15 + d;
          const int rr = (q < 0) ? (66 + q) : ((q > 63) ? (q + 2) : q);
          const h16x4 pn = *(const h16x4*)&Ph[psw(rr, vq4)];
          w[0] += (float)pn[0]; w[1] += (float)pn[1];
          w[2] += (float)pn[2]; w[3] += (float)pn[3];
        }
        #pragma unroll
        for (int r = 0; r < 4; ++r)
          vsum[t] = fmaf(P[t][r] * ci[r], w[r], vsum[t]);
      }
    }
  }

  // V reduce: over l4 (shfl bits 4,5), then across waves via LDS
  #pragma unroll
  for (int t = 0; t < 4; ++t) {
    float v = vsum[t];
    v += __shfl_xor(v, 16); v += __shfl_xor(v, 32);
    vsum[t] = v;
  }
  if (l4 == 0) {
    #pragma unroll
    for (int t = 0; t < 4; ++t) Vw[(wv << 6) + (t << 4) + l15] = vsum[t];
  }
  __syncthreads();
  if (tid < 64) {
    float v = Vw[tid] + Vw[64+tid] + Vw[128+tid] + Vw[192+tid];
    Vt[tid] = tanhf(5.f * v * rsrow[u0 + tid]);
  }
  __syncthreads();

  // epilogue: lane holds xT[u = wv*16 + l4*4 + r][c = t*16 + l15]
  const int ubu = (wv << 4) + (l4 << 2);
  float tv[4];
  #pragma unroll
  for (int r = 0; r < 4; ++r) tv[r] = Vt[ubu + r];
  #pragma unroll
  for (int t = 0; t < 4; ++t) {
    const int c = (t << 4) + l15;
    const size_t base = rowoff + (size_t)c*HW_ + u0 + ubu;
    const float4 xb4 = *(const float4*)&xblend[base];
    float4 o4;
    o4.x = xb4.x * (1.f - tv[0]) + xacc[t][0] * tv[0];
    o4.y = xb4.y * (1.f - tv[1]) + xacc[t][1] * tv[1];
    o4.z = xb4.z * (1.f - tv[2]) + xacc[t][2] * tv[2];
    o4.w = xb4.w * (1.f - tv[3]) + xacc[t][3] * tv[3];
    *(float4*)&outp[base] = o4;
  }
}

// ---------------------------------------------------------------------------
extern "C" void kernel_launch(void* const* d_in, const int* in_sizes, int n_in,
                              void* d_out, int out_size, void* d_ws, size_t ws_size,
                              hipStream_t stream) {
  const float* x_left  = (const float*)d_in[0];
  const float* x_right = (const float*)d_in[1];
  const float* catL    = (const float*)d_in[2];
  const float* catR    = (const float*)d_in[3];
  const float* bq_w    = (const float*)d_in[4];
  const float* bq_b    = (const float*)d_in[5];
  const float* bs_w    = (const float*)d_in[6];
  const float* bs_b    = (const float*)d_in[7];
  const float* rb_w1   = (const float*)d_in[8];
  const float* rb_b1   = (const float*)d_in[9];
  const float* rb_w2   = (const float*)d_in[10];
  const float* rb_b2   = (const float*)d_in[11];
  const float* gamma   = (const float*)d_in[12];
  const float* beta    = (const float*)d_in[13];

  float* ws = (float*)d_ws;
  size_t off = 0;
  float* WfQ = ws + off; off += WFQ_SZ;
  float* WfK = ws + off; off += WFQ_SZ;
  unsigned short* Wb   = (unsigned short*)(ws + off); off += WB_SZ;
  unsigned short* W2bQ = (unsigned short*)(ws + off); off += W2B_SZ;
  unsigned short* W2bK = (unsigned short*)(ws + off); off += W2B_SZ;
  float* ab  = ws + off; off += AB_SZ;
  float* bfQ = ws + off; off += BF_SZ;
  float* bfK = ws + off; off += BF_SZ;
  float2* pb = (float2*)(ws + off); off += PB_SZ;
  unsigned short* t1   = (unsigned short*)(ws + off); off += T1_SZ;
  unsigned short* catb = (unsigned short*)(ws + off); off += CATB_SZ;
  float* Qb  = ws + off; off += QK_SZ;
  float* Kb  = ws + off; off += QK_SZ;
  float* rsb = ws + off; off += RS_SZ;
  float* csb = ws + off; off += RS_SZ;
  float* csp = ws + off; off += CSP_SZ;

  wtrans_kernel<<<576, 256, 0, stream>>>(rb_w1, rb_w2, bq_w, bs_w, Wb, WfQ, WfK);
  bnstats1_kernel<<<4096, 256, 0, stream>>>(catL, catR, pb);
  bnstats2_kernel<<<2, 256, 0, stream>>>(pb, gamma, beta, ab);
  prep2_kernel<<<160, 256, 0, stream>>>(bq_w, bs_w, bq_b, bs_b, rb_b2,
                                        WfQ, WfK, W2bQ, W2bK, bfQ, bfK);

  dim3 agrid(HW_/64, 1, 8);
  dim3 cgrid(5, 80, 8);
  // left -> Q
  bnapply_kernel<<<agrid, 256, 0, stream>>>(catL, ab, catb);
  conv1_mfma<<<cgrid, 256, 0, stream>>>(catb, Wb, rb_b1, t1);
  conv2_mfma<<<cgrid, 256, 0, stream>>>(t1, catb, W2bQ, bfQ, Qb);
  // right -> K
  bnapply_kernel<<<agrid, 256, 0, stream>>>(catR, ab + 512, catb);
  conv1_mfma<<<cgrid, 256, 0, stream>>>(catb, Wb, rb_b1, t1);
  conv2_mfma<<<cgrid, 256, 0, stream>>>(t1, catb, W2bK, bfK, Kb);

  rowmean_kernel<<<B_*C0_*H_, 64, 0, stream>>>(Qb);
  rowmean_kernel<<<B_*C0_*H_, 64, 0, stream>>>(Kb);

  stats_kernel<<<dim3(5, NROWS_), 256, 0, stream>>>(Qb, Kb, rsb, csp);
  csreduce_kernel<<<(int)((RS_SZ + 255)/256), 256, 0, stream>>>(csp, csb);

  float* outL = (float*)d_out;
  float* outR = outL + QK_SZ;
  attn_kernel<<<dim3(5, NROWS_), 256, 0, stream>>>(Qb, Kb, rsb, csb, x_right, x_left, outL);
  attn_kernel<<<dim3(5, NROWS_), 256, 0, stream>>>(Kb, Qb, csb, rsb, x_left, x_right, outR);
}